// Round 15
// baseline (1290.033 us; speedup 1.0000x reference)
//
#include <hip/hip_runtime.h>

#define BN_SCALE 0.9999950000374997f  // 1/sqrt(1+1e-5)

// ---- DPP full-wave reductions (validated in fps/knn since R2/R4) ----
template <int CTRL>
__device__ __forceinline__ float dpp_fmax_step(float v) {
  int xi = __builtin_bit_cast(int, v);
  int ti = __builtin_amdgcn_update_dpp(xi, xi, CTRL, 0xf, 0xf, false);  // invalid lanes -> old(=v)
  return fmaxf(v, __builtin_bit_cast(float, ti));
}
template <int CTRL>
__device__ __forceinline__ int dpp_imin_step(int v) {
  int t = __builtin_amdgcn_update_dpp(v, v, CTRL, 0xf, 0xf, false);    // invalid lanes -> old(=v)
  return (t < v) ? t : v;
}
template <int CTRL>
__device__ __forceinline__ float dpp_fadd_step(float v) {
  // bound_ctrl=true: invalid lanes contribute 0 (required for sums)
  int ti = __builtin_amdgcn_update_dpp(0, __builtin_bit_cast(int, v), CTRL, 0xf, 0xf, true);
  return v + __builtin_bit_cast(float, ti);
}
__device__ __forceinline__ float wave_fmax(float v) {
  v = dpp_fmax_step<0x111>(v);
  v = dpp_fmax_step<0x112>(v);
  v = dpp_fmax_step<0x114>(v);
  v = dpp_fmax_step<0x118>(v);
  v = dpp_fmax_step<0x142>(v);
  v = dpp_fmax_step<0x143>(v);
  return __builtin_bit_cast(float, __builtin_amdgcn_readlane(__builtin_bit_cast(int, v), 63));
}
__device__ __forceinline__ int wave_imin(int v) {
  v = dpp_imin_step<0x111>(v);
  v = dpp_imin_step<0x112>(v);
  v = dpp_imin_step<0x114>(v);
  v = dpp_imin_step<0x118>(v);
  v = dpp_imin_step<0x142>(v);
  v = dpp_imin_step<0x143>(v);
  return __builtin_amdgcn_readlane(v, 63);
}
__device__ __forceinline__ float wave_fadd(float v) {
  v = dpp_fadd_step<0x111>(v);
  v = dpp_fadd_step<0x112>(v);
  v = dpp_fadd_step<0x114>(v);
  v = dpp_fadd_step<0x118>(v);
  v = dpp_fadd_step<0x142>(v);
  v = dpp_fadd_step<0x143>(v);
  return __builtin_bit_cast(float, __builtin_amdgcn_readlane(__builtin_bit_cast(int, v), 63));
}

// ---------------- knn4 body (R14 version: float4 dot + tournament selection) ----------------
template <int R, bool SQPRE>
__device__ __forceinline__ void knn4_body(const float* __restrict__ Q, int qStrideB,
                                          const float* __restrict__ Xc, int cStrideB,
                                          int C, int M, int N, int k, int* __restrict__ idxOut,
                                          const float* __restrict__ sqPre,
                                          int b, int q0, char* smem) {
  constexpr int NR = 4 * R;
  float (*negd)[R * 256] = (float (*)[R * 256])smem;
  int tid = threadIdx.x;
  const float* qb = Q + (long)b * qStrideB + q0;
  const float* cb = Xc + (long)b * cStrideB;
  if constexpr (R % 4 == 0) {
    constexpr int H = R / 4;
    float d0[R], d1[R], d2[R], d3[R], sq[R];
    #pragma unroll
    for (int i = 0; i < R; ++i) { d0[i] = d1[i] = d2[i] = d3[i] = sq[i] = 0.f; }
    for (int c = 0; c < C; ++c) {
      float4 q4 = *(const float4*)(qb + (long)c * M);  // uniform -> scalar load
      const float4* pc4 = (const float4*)(cb + (long)c * N);
      #pragma unroll
      for (int h = 0; h < H; ++h) {
        float4 xv = pc4[tid + 256 * h];                // 16B/lane coalesced
        if (!SQPRE) {
          sq[4 * h + 0] = fmaf(xv.x, xv.x, sq[4 * h + 0]);
          sq[4 * h + 1] = fmaf(xv.y, xv.y, sq[4 * h + 1]);
          sq[4 * h + 2] = fmaf(xv.z, xv.z, sq[4 * h + 2]);
          sq[4 * h + 3] = fmaf(xv.w, xv.w, sq[4 * h + 3]);
        }
        d0[4 * h + 0] = fmaf(q4.x, xv.x, d0[4 * h + 0]);
        d0[4 * h + 1] = fmaf(q4.x, xv.y, d0[4 * h + 1]);
        d0[4 * h + 2] = fmaf(q4.x, xv.z, d0[4 * h + 2]);
        d0[4 * h + 3] = fmaf(q4.x, xv.w, d0[4 * h + 3]);
        d1[4 * h + 0] = fmaf(q4.y, xv.x, d1[4 * h + 0]);
        d1[4 * h + 1] = fmaf(q4.y, xv.y, d1[4 * h + 1]);
        d1[4 * h + 2] = fmaf(q4.y, xv.z, d1[4 * h + 2]);
        d1[4 * h + 3] = fmaf(q4.y, xv.w, d1[4 * h + 3]);
        d2[4 * h + 0] = fmaf(q4.z, xv.x, d2[4 * h + 0]);
        d2[4 * h + 1] = fmaf(q4.z, xv.y, d2[4 * h + 1]);
        d2[4 * h + 2] = fmaf(q4.z, xv.z, d2[4 * h + 2]);
        d2[4 * h + 3] = fmaf(q4.z, xv.w, d2[4 * h + 3]);
        d3[4 * h + 0] = fmaf(q4.w, xv.x, d3[4 * h + 0]);
        d3[4 * h + 1] = fmaf(q4.w, xv.y, d3[4 * h + 1]);
        d3[4 * h + 2] = fmaf(q4.w, xv.z, d3[4 * h + 2]);
        d3[4 * h + 3] = fmaf(q4.w, xv.w, d3[4 * h + 3]);
      }
    }
    #pragma unroll
    for (int h = 0; h < H; ++h) {
      float4 s4;
      if (SQPRE) {
        s4 = ((const float4*)(sqPre + (long)b * N))[tid + 256 * h];
      } else {
        s4 = make_float4(sq[4 * h], sq[4 * h + 1], sq[4 * h + 2], sq[4 * h + 3]);
      }
      ((float4*)negd[0])[tid + 256 * h] =
          make_float4(2.f * d0[4 * h] - s4.x, 2.f * d0[4 * h + 1] - s4.y,
                      2.f * d0[4 * h + 2] - s4.z, 2.f * d0[4 * h + 3] - s4.w);
      ((float4*)negd[1])[tid + 256 * h] =
          make_float4(2.f * d1[4 * h] - s4.x, 2.f * d1[4 * h + 1] - s4.y,
                      2.f * d1[4 * h + 2] - s4.z, 2.f * d1[4 * h + 3] - s4.w);
      ((float4*)negd[2])[tid + 256 * h] =
          make_float4(2.f * d2[4 * h] - s4.x, 2.f * d2[4 * h + 1] - s4.y,
                      2.f * d2[4 * h + 2] - s4.z, 2.f * d2[4 * h + 3] - s4.w);
      ((float4*)negd[3])[tid + 256 * h] =
          make_float4(2.f * d3[4 * h] - s4.x, 2.f * d3[4 * h + 1] - s4.y,
                      2.f * d3[4 * h + 2] - s4.z, 2.f * d3[4 * h + 3] - s4.w);
    }
  } else {
    float d0[R], d1[R], d2[R], d3[R], sq[R];
    #pragma unroll
    for (int i = 0; i < R; ++i) { d0[i] = d1[i] = d2[i] = d3[i] = sq[i] = 0.f; }
    for (int c = 0; c < C; ++c) {
      float4 q4 = *(const float4*)(qb + (long)c * M);
      const float* pc = cb + (long)c * N;
      #pragma unroll
      for (int i = 0; i < R; ++i) {
        float xv = pc[tid + 256 * i];
        sq[i] = fmaf(xv, xv, sq[i]);
        d0[i] = fmaf(q4.x, xv, d0[i]);
        d1[i] = fmaf(q4.y, xv, d1[i]);
        d2[i] = fmaf(q4.z, xv, d2[i]);
        d3[i] = fmaf(q4.w, xv, d3[i]);
      }
    }
    #pragma unroll
    for (int i = 0; i < R; ++i) {
      int m = tid + 256 * i;
      negd[0][m] = 2.f * d0[i] - sq[i];
      negd[1][m] = 2.f * d1[i] - sq[i];
      negd[2][m] = 2.f * d2[i] - sq[i];
      negd[3][m] = 2.f * d3[i] - sq[i];
    }
  }
  __syncthreads();
  int lane = tid & 63, w = tid >> 6;
  const float* row = negd[w];
  int* outp = idxOut + ((long)b * M + (q0 + w)) * k;
  float v[NR];
  #pragma unroll
  for (int i = 0; i < NR; ++i) v[i] = row[lane + 64 * i];
  constexpr int G = NR / 4;
  for (int kk = 0; kk < k; ++kk) {
    float bv[G]; int br[G];
    #pragma unroll
    for (int g = 0; g < G; ++g) {
      float v0 = v[4 * g]; int r0 = 4 * g;
      #pragma unroll
      for (int j = 1; j < 4; ++j) {
        bool c = v[4 * g + j] > v0;
        v0 = c ? v[4 * g + j] : v0;
        r0 = c ? (4 * g + j) : r0;
      }
      bv[g] = v0; br[g] = r0;
    }
    #pragma unroll
    for (int s = G >> 1; s >= 1; s >>= 1) {
      #pragma unroll
      for (int i = 0; i < s; ++i) {
        bool c = bv[2 * i] >= bv[2 * i + 1];
        bv[i] = c ? bv[2 * i] : bv[2 * i + 1];
        br[i] = c ? br[2 * i] : br[2 * i + 1];
      }
    }
    float best = bv[0]; int ib = br[0];
    int bi = (best > -INFINITY) ? (lane + (ib << 6)) : N;
    float gmax = wave_fmax(best);
    int cand = (best == gmax) ? bi : 0x7FFFFFFF;
    int big = wave_imin(cand);
    if (lane == 0) outp[kk] = big;
    int ri = big >> 6;
    bool mine = (lane == (big & 63));
    #pragma unroll
    for (int i = 0; i < NR; ++i)
      if (i == ri) v[i] = mine ? -INFINITY : v[i];
  }
}

template <int R>
__global__ void knn4_kernel(const float* __restrict__ Q, int qStrideB,
                            const float* __restrict__ Xc, int cStrideB,
                            int C, int M, int N, int k, int* __restrict__ idxOut) {
  __shared__ __align__(16) char smem[R * 256 * 4 * 4];
  knn4_body<R, false>(Q, qStrideB, Xc, cStrideB, C, M, N, k, idxOut, nullptr,
                      blockIdx.y, blockIdx.x * 4, smem);
}

// ---------------- gemmPS body ----------------
__device__ __forceinline__ void gemmPS_body(const float* __restrict__ X, int xStrideB, int C, int Np,
                                            const float* __restrict__ W, int ldw, int O,
                                            float* __restrict__ PtT, float* __restrict__ StT,
                                            int b, int n0, int o0, char* smem) {
  float (*Wp)[65] = (float (*)[65])smem;
  float (*Ws)[65] = (float (*)[65])(smem + 4160);
  float (*Xt)[65] = (float (*)[65])(smem + 8320);
  int tid = threadIdx.x;
  int to = tid % 16, tn = tid / 16;
  float accP[4][4] = {}, accS[4][4] = {};
  for (int c0 = 0; c0 < C; c0 += 16) {
    for (int e = tid; e < 16 * 64; e += 256) {
      int oo = e / 16, kk = e % 16;
      int c = c0 + kk, o = o0 + oo;
      bool ok = (c < C && o < O);
      Wp[kk][oo] = ok ? W[(long)o * ldw + c] : 0.f;
      Ws[kk][oo] = ok ? W[(long)o * ldw + C + c] : 0.f;
    }
    for (int e = tid; e < 16 * 64; e += 256) {
      int kk = e / 64, nn = e % 64;
      int c = c0 + kk, n = n0 + nn;
      Xt[kk][nn] = (c < C && n < Np) ? X[(long)b * xStrideB + (long)c * Np + n] : 0.f;
    }
    __syncthreads();
    for (int kk = 0; kk < 16; ++kk) {
      float xv[4], wp[4], ws[4];
      for (int i = 0; i < 4; ++i) xv[i] = Xt[kk][tn + 16 * i];
      for (int j = 0; j < 4; ++j) { wp[j] = Wp[kk][to + 16 * j]; ws[j] = Ws[kk][to + 16 * j]; }
      for (int i = 0; i < 4; ++i)
        for (int j = 0; j < 4; ++j) {
          accP[i][j] = fmaf(xv[i], wp[j], accP[i][j]);
          accS[i][j] = fmaf(xv[i], ws[j], accS[i][j]);
        }
    }
    __syncthreads();
  }
  for (int i = 0; i < 4; ++i) {
    int n = n0 + tn + 16 * i;
    if (n >= Np) continue;
    for (int j = 0; j < 4; ++j) {
      int o = o0 + to + 16 * j;
      if (o < O) {
        long off = ((long)b * Np + n) * O + o;
        PtT[off] = accP[i][j];
        StT[off] = accS[i][j];
      }
    }
  }
}

// ---------------- ecfinish body (O=64 flat-256 variant) ----------------
__device__ __forceinline__ void ecfinish_body64(const float* __restrict__ Pt, const float* __restrict__ St,
                                                const int* __restrict__ idx, int k, int O, int Np,
                                                const float* __restrict__ g, const float* __restrict__ bb,
                                                float* __restrict__ outp, long oStrideB,
                                                float* __restrict__ sqOut,
                                                int b, int blk) {
  int tid = threadIdx.x;
  int o = tid & 63;
  int n = blk * 4 + (tid >> 6);
  const float* PtB = Pt + (long)b * Np * O;
  const float* StB = St + (long)b * Np * O;
  const int* ip = idx + ((long)b * Np + n) * k;
  float mx = -INFINITY, mn = INFINITY;
  for (int kk = 0; kk < k; ++kk) {
    float v = PtB[(long)ip[kk] * O + o];
    mx = fmaxf(mx, v); mn = fminf(mn, v);
  }
  float ctrP = PtB[(long)n * O + o];
  float ctrS = StB[(long)n * O + o];
  float gs = g[o] * BN_SCALE;
  float m = (gs >= 0.f) ? mx : mn;
  float h = (ctrS - ctrP + m) * gs + bb[o];
  float out = h >= 0.f ? h : 0.2f * h;
  outp[(long)b * oStrideB + (long)o * Np + n] = out;
  if (sqOut) {
    int obits = __builtin_bit_cast(int, out);
    float acc = 0.f;
    #pragma unroll
    for (int c = 0; c < 64; ++c) {
      float hv = __builtin_bit_cast(float, __builtin_amdgcn_readlane(obits, c));
      acc = fmaf(hv, hv, acc);
    }
    if (o == 0) sqOut[(long)b * Np + n] = acc;
  }
}

__global__ void ecfinish_kernel(const float* __restrict__ Pt, const float* __restrict__ St,
                                const int* __restrict__ idx, int k, int O, int Np,
                                const float* __restrict__ g, const float* __restrict__ bb,
                                float* __restrict__ outp, long oStrideB) {
  int b = blockIdx.y;
  int n = blockIdx.x * blockDim.y + threadIdx.y;
  int o = threadIdx.x;
  const float* PtB = Pt + (long)b * Np * O;
  const float* StB = St + (long)b * Np * O;
  const int* ip = idx + ((long)b * Np + n) * k;
  float mx = -INFINITY, mn = INFINITY;
  for (int kk = 0; kk < k; ++kk) {
    float v = PtB[(long)ip[kk] * O + o];
    mx = fmaxf(mx, v); mn = fminf(mn, v);
  }
  float ctrP = PtB[(long)n * O + o];
  float ctrS = StB[(long)n * O + o];
  float gs = g[o] * BN_SCALE;
  float m = (gs >= 0.f) ? mx : mn;
  float h = (ctrS - ctrP + m) * gs + bb[o];
  outp[(long)b * oStrideB + (long)o * Np + n] = h >= 0.f ? h : 0.2f * h;
}

// ---------------- gemm_colmax body (R14->R15: 128-row tiles, 8x4 acc) ----------------
// Per kk-step: 12 LDS reads / 32 FMA (73% dense vs 50%). Per-(n,o) fmaf chain ascending
// c unchanged -> bit-identical accs; colmax = pure fmax (exact assoc/comm) -> partials
// bit-identical under regrouping. nNT halves (16 for A, 4 for B); head uses new counts.
__device__ __forceinline__ void gemm_colmax_body(const float* __restrict__ X, int xStrideB, int C, int Np,
                                                 const float* __restrict__ W, int ldw, int O,
                                                 const float* __restrict__ g, const float* __restrict__ bb,
                                                 float* __restrict__ partial,
                                                 int b, int n0, int o0, int nt, int nNT, char* smem) {
  float (*Wt)[65] = (float (*)[65])smem;            // 4160 B
  float (*Xt)[129] = (float (*)[129])(smem + 4160); // 8256 B
  int tid = threadIdx.x;
  int to = tid % 16, tn = tid / 16;
  float acc[8][4] = {};
  for (int c0 = 0; c0 < C; c0 += 16) {
    for (int e = tid; e < 16 * 64; e += 256) {
      int oo = e / 16, kk = e % 16;
      int c = c0 + kk, o = o0 + oo;
      Wt[kk][oo] = (c < C && o < O) ? W[(long)o * ldw + c] : 0.f;
    }
    for (int e = tid; e < 16 * 128; e += 256) {
      int kk = e / 128, nn = e % 128;
      int c = c0 + kk, n = n0 + nn;
      Xt[kk][nn] = (c < C && n < Np) ? X[(long)b * xStrideB + (long)c * Np + n] : 0.f;
    }
    __syncthreads();
    for (int kk = 0; kk < 16; ++kk) {
      float xv[8], wv[4];
      #pragma unroll
      for (int i = 0; i < 8; ++i) xv[i] = Xt[kk][tn + 16 * i];
      #pragma unroll
      for (int j = 0; j < 4; ++j) wv[j] = Wt[kk][to + 16 * j];
      #pragma unroll
      for (int i = 0; i < 8; ++i)
        #pragma unroll
        for (int j = 0; j < 4; ++j) acc[i][j] = fmaf(xv[i], wv[j], acc[i][j]);
    }
    __syncthreads();
  }
  float vm[4];
  #pragma unroll
  for (int j = 0; j < 4; ++j) {
    int o = o0 + to + 16 * j;
    float gs = g[o] * BN_SCALE, bo = bb[o];
    float m = -INFINITY;
    #pragma unroll
    for (int i = 0; i < 8; ++i) {
      float h = acc[i][j] * gs + bo;
      h = h >= 0.f ? h : 0.2f * h;
      m = fmaxf(m, h);
    }
    vm[j] = m;
  }
  #pragma unroll
  for (int j = 0; j < 4; ++j) Wt[tn][to + 16 * j] = vm[j];   // reuse Wt for reduce
  __syncthreads();
  for (int s = 8; s > 0; s >>= 1) {
    if (tn < s)
      for (int j = 0; j < 4; ++j)
        Wt[tn][to + 16 * j] = fmaxf(Wt[tn][to + 16 * j], Wt[tn + s][to + 16 * j]);
    __syncthreads();
  }
  if (tn == 0)
    for (int j = 0; j < 4; ++j) {
      int o = o0 + to + 16 * j;
      partial[((long)b * nNT + nt) * O + o] = Wt[0][to + 16 * j];
    }
}

__global__ void gemm_colmax_kernel(const float* __restrict__ X, int xStrideB, int C, int Np,
                                   const float* __restrict__ W, int ldw, int O,
                                   const float* __restrict__ g, const float* __restrict__ bb,
                                   float* __restrict__ partial) {
  __shared__ __align__(16) char smem[4160 + 8256];
  gemm_colmax_body(X, xStrideB, C, Np, W, ldw, O, g, bb, partial,
                   blockIdx.z, blockIdx.x * 128, blockIdx.y * 64, blockIdx.x, gridDim.x, smem);
}

// ---------------- xmfill body ----------------
__device__ __forceinline__ void xmfill_body(const float* __restrict__ xt1, int N,
                                            const int* __restrict__ fpsI,
                                            const int* __restrict__ idxA, int k, int M,
                                            float* __restrict__ xm, int xe) {
  long t = (long)xe * 256 + threadIdx.x;
  int i = (int)(t % M);
  int c = (int)((t / M) % 128);
  int b = (int)(t / ((long)128 * M));
  const float* xb = xt1 + (long)b * 128 * N + (long)c * N;
  float* xmB = xm + (long)b * 256 * M;
  xmB[(long)c * M + i] = xb[fpsI[(long)b * M + i]];
  const int* ip = idxA + ((long)b * M + i) * k;
  float best = -INFINITY;
  for (int kk = 0; kk < k; ++kk) best = fmaxf(best, xb[ip[kk]]);
  xmB[(long)(128 + c) * M + i] = best;
}

// ---------------- FPS body, RANGE-split (unchanged) ----------------
template <int FIRST, int LAST>
__device__ __forceinline__ void fps_body_rg(const float* __restrict__ xyz, int N, int M,
                                            int it0, int it1,
                                            int* __restrict__ fpsIdx, float* __restrict__ node1,
                                            float* __restrict__ distSv, int* __restrict__ lastSv,
                                            int b, char* smem) {
  #pragma clang fp contract(off)
  float4* sp4 = (float4*)smem;                 // 2048 pts: slot (n&7)*256 + (n>>3)
  int*    fidx = (int*)(smem + 32768);
  float4* wvc  = (float4*)(smem + 32768 + 2048);
  int*    wis  = (int*)(smem + 32768 + 2048 + 128);
  int tid = threadIdx.x;
  int lane = tid & 63, w = tid >> 6;
  const float* xb = xyz + (long)b * 3 * N;
  for (int n = tid; n < N; n += 256) {
    sp4[((n & 7) << 8) | (n >> 3)] = make_float4(xb[n], xb[N + n], xb[2 * N + n], 0.f);
  }
  if (!FIRST) {
    for (int e = tid; e < it0; e += 256) fidx[e] = fpsIdx[(long)b * M + e];
  }
  __syncthreads();
  float4 pt[8];
  #pragma unroll
  for (int i = 0; i < 8; ++i) pt[i] = sp4[(i << 8) | tid];
  float dist[8];
  int last;
  float lx, ly, lz;
  if (FIRST) {
    #pragma unroll
    for (int i = 0; i < 8; ++i) dist[i] = 1e10f;
    last = 0;
    float4 l0 = sp4[0];
    lx = l0.x; ly = l0.y; lz = l0.z;
  } else {
    #pragma unroll
    for (int i = 0; i < 8; ++i) dist[i] = distSv[(long)b * 2048 + i * 256 + tid];
    last = lastSv[b];
    float4 lp = sp4[((last & 7) << 8) | (last >> 3)];
    lx = lp.x; ly = lp.y; lz = lp.z;
  }
  int base = tid * 8;
  for (int it = it0; it < it1; ++it) {
    int p = it & 1;
    if (tid == 0) fidx[it] = last;
    float best = -INFINITY; int bi = N;
    #pragma unroll
    for (int i = 0; i < 8; ++i) {
      float dx = pt[i].x - lx, dy = pt[i].y - ly, dz = pt[i].z - lz;
      float dx2 = dx * dx, dy2 = dy * dy, dz2 = dz * dz;
      float d = (dx2 + dy2) + dz2;
      float dn = dist[i];
      if (d < dn) dn = d;
      dist[i] = dn;
      if (dn > best) { best = dn; bi = base + i; }
    }
    float cx = pt[0].x, cy = pt[0].y, cz = pt[0].z;
    #pragma unroll
    for (int i = 1; i < 8; ++i) {
      bool c = (bi == base + i);
      cx = c ? pt[i].x : cx; cy = c ? pt[i].y : cy; cz = c ? pt[i].z : cz;
    }
    float gmax = wave_fmax(best);
    int cand = (best == gmax) ? bi : 0x7FFFFFFF;
    int wbi = wave_imin(cand);
    if (bi == wbi) { wvc[p * 4 + w] = make_float4(gmax, cx, cy, cz); wis[p * 4 + w] = wbi; }
    __syncthreads();
    float4 c0 = wvc[p * 4 + 0], c1 = wvc[p * 4 + 1], c2 = wvc[p * 4 + 2], c3 = wvc[p * 4 + 3];
    int i0 = wis[p * 4 + 0], i1 = wis[p * 4 + 1], i2 = wis[p * 4 + 2], i3 = wis[p * 4 + 3];
    float bv = c0.x; int bbi = i0; lx = c0.y; ly = c0.z; lz = c0.w;
    { bool c = (c1.x > bv) || (c1.x == bv && i1 < bbi);
      bv = c ? c1.x : bv; bbi = c ? i1 : bbi; lx = c ? c1.y : lx; ly = c ? c1.z : ly; lz = c ? c1.w : lz; }
    { bool c = (c2.x > bv) || (c2.x == bv && i2 < bbi);
      bv = c ? c2.x : bv; bbi = c ? i2 : bbi; lx = c ? c2.y : lx; ly = c ? c2.z : ly; lz = c ? c2.w : lz; }
    { bool c = (c3.x > bv) || (c3.x == bv && i3 < bbi);
      bv = c ? c3.x : bv; bbi = c ? i3 : bbi; lx = c ? c3.y : lx; ly = c ? c3.z : ly; lz = c ? c3.w : lz; }
    last = bbi;
    // parity: slot p rewritten only in iter it+2, after barrier it+1 -> safe with 1 barrier
  }
  if (!LAST) {
    for (int e = tid; e < it1; e += 256) {
      if (e >= it0) fpsIdx[(long)b * M + e] = fidx[e];
    }
    #pragma unroll
    for (int i = 0; i < 8; ++i) distSv[(long)b * 2048 + i * 256 + tid] = dist[i];
    if (tid == 0) lastSv[b] = last;
  } else {
    for (int e = tid; e < M; e += 256) fpsIdx[(long)b * M + e] = fidx[e];
    for (int e = tid; e < 3 * M; e += 256) {
      int c = e / M, i = e % M;
      int src = fidx[i];
      float4 ptc = sp4[((src & 7) << 8) | (src >> 3)];
      node1[(long)b * 3 * M + e] = (c == 0) ? ptc.x : (c == 1) ? ptc.y : ptc.z;
    }
  }
}

// ---------------- fused {fps-range + knn + gemmPS}, 1D grid, fps first ----------------
template <int FIRST, int LAST, bool SQP>
__global__ void knnfpsgemm_kernel(const float* __restrict__ Q, int qStrideB,
                                  const float* __restrict__ Xc, int cStrideB,
                                  int C, int Mq, int N, int k, int* __restrict__ idxOut,
                                  const float* __restrict__ W, int ldw, int O,
                                  float* __restrict__ Pt, float* __restrict__ St,
                                  const float* __restrict__ xyz, int Mf, int it0, int it1,
                                  int* __restrict__ fpsIdx, float* __restrict__ node1,
                                  float* __restrict__ distSv, int* __restrict__ lastSv,
                                  const float* __restrict__ sqPre,
                                  int nQblk, int nGblk, int nB) {
  __shared__ __align__(16) char smem[32768 + 2048 + 128 + 32];
  int bid = blockIdx.x;
  if (bid < nB) {
    __builtin_amdgcn_s_setprio(1);
    fps_body_rg<FIRST, LAST>(xyz, N, Mf, it0, it1, fpsIdx, node1, distSv, lastSv, bid, smem);
    __builtin_amdgcn_s_setprio(0);
  } else if (bid < nB + nB * nQblk) {
    int e = bid - nB;
    knn4_body<8, SQP>(Q, qStrideB, Xc, cStrideB, C, Mq, N, k, idxOut, sqPre,
                      e / nQblk, (e % nQblk) * 4, smem);
  } else {
    int e = bid - nB - nB * nQblk;
    gemmPS_body(Xc, cStrideB, C, N, W, ldw, O, Pt, St,
                e / nGblk, (e % nGblk) * 64, 0, smem);
  }
}

// ---------------- fused {ecfinish1 (+sq emit) + fps mid-range}, fps blocks first --------
__global__ void ecfps_kernel(const float* __restrict__ Pt, const float* __restrict__ St,
                             const int* __restrict__ idx, int k, int O, int Np,
                             const float* __restrict__ g, const float* __restrict__ bb,
                             float* __restrict__ outp, long oStrideB,
                             float* __restrict__ sqOut,
                             const float* __restrict__ xyz, int N, int Mf, int it0, int it1,
                             int* __restrict__ fpsIdx, float* __restrict__ node1,
                             float* __restrict__ distSv, int* __restrict__ lastSv,
                             int nEperB, int nB) {
  __shared__ __align__(16) char smem[32768 + 2048 + 128 + 32];
  int bid = blockIdx.x;
  if (bid < nB) {
    __builtin_amdgcn_s_setprio(1);
    fps_body_rg<0, 0>(xyz, N, Mf, it0, it1, fpsIdx, node1, distSv, lastSv, bid, smem);
    __builtin_amdgcn_s_setprio(0);
  } else {
    int e = bid - nB;
    ecfinish_body64(Pt, St, idx, k, O, Np, g, bb, outp, oStrideB, sqOut,
                    e / nEperB, e % nEperB);
  }
}

// ---------------- fused {ecfinish2 + agg-knn}, striped (agg every 5th bid) ----------------
__global__ void ecfagg_kernel(const float* __restrict__ Pt, const float* __restrict__ St,
                              const int* __restrict__ idxS2, int k2, int O2, int Np2,
                              const float* __restrict__ g2, const float* __restrict__ b2,
                              float* __restrict__ out2, long oStrideB2,
                              const float* __restrict__ Qn, int qStrideB,
                              const float* __restrict__ Xc, int cStrideB,
                              int Cq, int Mq, int Nc, int kq, int* __restrict__ idxAgg,
                              int nQblk, int nEperB) {
  __shared__ __align__(16) char smem[32768];
  int bid = blockIdx.x;
  if (bid % 5 == 0) {
    int a = bid / 5;                       // [0, 1024)
    knn4_body<8, false>(Qn, qStrideB, Xc, cStrideB, Cq, Mq, Nc, kq, idxAgg, nullptr,
                        a / nQblk, (a % nQblk) * 4, smem);
  } else {
    int e = bid - bid / 5 - 1;             // [0, 4096) sequential
    ecfinish_body64(Pt, St, idxS2, k2, O2, Np2, g2, b2, out2, oStrideB2, nullptr,
                    e / nEperB, e % nEperB);
  }
}

// ---------------- fused {gemm_colmaxA + xmfill}, striped 1:1 ----------------
__global__ void colmaxxm_kernel(const float* __restrict__ X, int xStrideB, int C, int Np,
                                const float* __restrict__ W, int ldw, int O,
                                const float* __restrict__ g, const float* __restrict__ bb,
                                float* __restrict__ partial, int nNT, int nOT,
                                const float* __restrict__ xt1, int N,
                                const int* __restrict__ fpsI, const int* __restrict__ idxA,
                                int kq, int M, float* __restrict__ xm) {
  __shared__ __align__(16) char smem[4160 + 8256];
  int bid = blockIdx.x;
  if (bid % 2 == 0) {
    xmfill_body(xt1, N, fpsI, idxA, kq, M, xm, bid / 2);       // [0, 2048)
  } else {
    int e = bid / 2;                                            // [0, 2048)
    int per = nNT * nOT;
    int b = e / per, r = e % per;
    int nt = r % nNT, ot = r / nNT;
    gemm_colmax_body(X, xStrideB, C, Np, W, ldw, O, g, bb, partial,
                     b, nt * 128, ot * 64, nt, nNT, smem);
  }
}

// ---------------- fused {knn<2> + gemmPS} for stages 3/4 ----------------
__global__ void knngemm_kernel(const float* __restrict__ Xin, int xStrideB,
                               int C, int Mq, int N, int k, int* __restrict__ idxOut,
                               const float* __restrict__ W, int ldw, int O,
                               float* __restrict__ Pt, float* __restrict__ St,
                               int nQblk, int nGn, int nGo, int nB) {
  __shared__ __align__(16) char smem[3 * 4160];
  int bid = blockIdx.x;
  if (bid < nB * nQblk) {
    knn4_body<2, false>(Xin, xStrideB, Xin, xStrideB, C, Mq, N, k, idxOut, nullptr,
                        bid / nQblk, (bid % nQblk) * 4, smem);
  } else {
    int e = bid - nB * nQblk;
    int per = nGn * nGo;
    int b = e / per, r = e % per;
    int nt = r % nGn, ot = r / nGn;
    gemmPS_body(Xin, xStrideB, C, N, W, ldw, O, Pt, St, b, nt * 64, ot * 64, smem);
  }
}

// ---------------- head: fused colmax_finish + 3-layer MLP (wave-cooperative) ----------------
__global__ void head_kernel(const float* __restrict__ partA, int NTa,
                            const float* __restrict__ partB, int NTb,
                            const float* __restrict__ Wl1, const float* __restrict__ g6, const float* __restrict__ b6,
                            const float* __restrict__ Wl2, const float* __restrict__ bl2,
                            const float* __restrict__ g7, const float* __restrict__ b7,
                            const float* __restrict__ Wl3, const float* __restrict__ bl3,
                            float* __restrict__ logits) {
  __shared__ float v[2048];
  __shared__ float h1[512];
  __shared__ float h2[256];
  int b = blockIdx.x, tid = threadIdx.x;
  int lane = tid & 63, w = tid >> 6;
  for (int o = tid; o < 1024; o += 256) {
    float m = -INFINITY;
    for (int t = 0; t < NTa; ++t) m = fmaxf(m, partA[((long)b * NTa + t) * 1024 + o]);
    v[o] = m;
    float m2 = -INFINITY;
    for (int t = 0; t < NTb; ++t) m2 = fmaxf(m2, partB[((long)b * NTb + t) * 1024 + o]);
    v[1024 + o] = m2;
  }
  __syncthreads();
  for (int o = w; o < 512; o += 4) {
    const float4* wr = (const float4*)(Wl1 + (long)o * 2048);
    const float4* vp = (const float4*)v;
    float s = 0.f;
    #pragma unroll
    for (int j = 0; j < 8; ++j) {
      float4 w4 = wr[lane + 64 * j];
      float4 v4 = vp[lane + 64 * j];
      s = fmaf(w4.x, v4.x, s); s = fmaf(w4.y, v4.y, s);
      s = fmaf(w4.z, v4.z, s); s = fmaf(w4.w, v4.w, s);
    }
    float t = wave_fadd(s);
    if (lane == 0) {
      float h = t * (g6[o] * BN_SCALE) + b6[o];
      h1[o] = h >= 0.f ? h : 0.2f * h;
    }
  }
  __syncthreads();
  for (int o = w; o < 256; o += 4) {
    const float4* wr = (const float4*)(Wl2 + (long)o * 512);
    const float4* hp = (const float4*)h1;
    float s = 0.f;
    #pragma unroll
    for (int j = 0; j < 2; ++j) {
      float4 w4 = wr[lane + 64 * j];
      float4 v4 = hp[lane + 64 * j];
      s = fmaf(w4.x, v4.x, s); s = fmaf(w4.y, v4.y, s);
      s = fmaf(w4.z, v4.z, s); s = fmaf(w4.w, v4.w, s);
    }
    float t = wave_fadd(s);
    if (lane == 0) {
      float sb = t + bl2[o];
      float h = sb * (g7[o] * BN_SCALE) + b7[o];
      h2[o] = h >= 0.f ? h : 0.2f * h;
    }
  }
  __syncthreads();
  for (int o = w; o < 40; o += 4) {
    const float4* wr = (const float4*)(Wl3 + (long)o * 256);
    const float4* hp = (const float4*)h2;
    float4 w4 = wr[lane];
    float4 v4 = hp[lane];
    float s = fmaf(w4.x, v4.x, 0.f);
    s = fmaf(w4.y, v4.y, s); s = fmaf(w4.z, v4.z, s); s = fmaf(w4.w, v4.w, s);
    float t = wave_fadd(s);
    if (lane == 0) logits[(long)b * 40 + o] = t + bl3[o];
  }
}

extern "C" void kernel_launch(void* const* d_in, const int* in_sizes, int n_in,
                              void* d_out, int out_size, void* d_ws, size_t ws_size,
                              hipStream_t stream) {
  const float* x   = (const float*)d_in[0];
  const float* W1  = (const float*)d_in[1];
  const float* g1  = (const float*)d_in[2];
  const float* b1  = (const float*)d_in[3];
  const float* W2  = (const float*)d_in[4];
  const float* g2  = (const float*)d_in[5];
  const float* b2  = (const float*)d_in[6];
  const float* W2m = (const float*)d_in[7];
  const float* g2m = (const float*)d_in[8];
  const float* b2m = (const float*)d_in[9];
  const float* W3  = (const float*)d_in[10];
  const float* g3  = (const float*)d_in[11];
  const float* b3  = (const float*)d_in[12];
  const float* W4  = (const float*)d_in[13];
  const float* g4  = (const float*)d_in[14];
  const float* b4  = (const float*)d_in[15];
  const float* W5  = (const float*)d_in[16];
  const float* g5  = (const float*)d_in[17];
  const float* b5  = (const float*)d_in[18];
  const float* Wl1 = (const float*)d_in[19];
  const float* g6  = (const float*)d_in[20];
  const float* b6  = (const float*)d_in[21];
  const float* Wl2 = (const float*)d_in[22];
  const float* bl2 = (const float*)d_in[23];
  const float* g7  = (const float*)d_in[24];
  const float* b7  = (const float*)d_in[25];
  const float* Wl3 = (const float*)d_in[26];
  const float* bl3 = (const float*)d_in[27];
  float* outF = (float*)d_out;

  const int B = 8, N = 2048, K = 20, M = 512, K2 = 10;

  float* ws    = (float*)d_ws;
  float* xt1   = ws;                               // (B,128,N)
  float* xm    = xt1 + (size_t)B * 128 * N;        // (B,256,M)
  float* xc    = xm  + (size_t)B * 256 * M;        // (B,512,M)
  float* Pt    = xc  + (size_t)B * 512 * M;        // max(B*N*64, B*M*256)
  float* St    = Pt  + (size_t)B * N * 64;
  float* partA = St  + (size_t)B * N * 64;         // (B,16,1024)
  float* partB = partA + (size_t)B * 16 * 1024;    // (B,4,1024)
  int*   idxK  = (int*)(partB + (size_t)B * 4 * 1024);  // (B,N,K)
  int*   fpsI  = idxK + (size_t)B * N * K;         // (B,M)
  float* fpsDist = (float*)(fpsI + (size_t)B * M); // (B,2048) fps checkpoint dists
  int*   fpsLast = (int*)(fpsDist + (size_t)B * 2048);  // (B)
  int*   idxAgg  = fpsLast + 64;                   // (B,M,K) aggregate-knn indices
  float* sqS2    = (float*)(idxAgg + (size_t)B * M * K); // (B,N) stage-2 candidate norms

  float* logits = outF;        // (B,40)
  float* node1  = outF + 320;  // (B,3,M)

  dim3 t256(256);
  const int nQblk = N / 4;     // 512 knn query-blocks per batch (N-point knn)
  const int nGblk = N / 64;    // 32 gemmPS n-tiles per batch (stage 1/2)
  const int nFused = B + B * nQblk + B * nGblk;
  const int nQa = M / 4;       // 128 agg/stage3/4 knn query-blocks per batch
  const int IT1 = 208, IT2 = 304;   // fps phase boundaries (R15 rebalance: big kernels host more)

  // ---- stage 1 FUSED: fps [0,208) + knn(xyz) + gemmPS1 (all depend only on x)
  knnfpsgemm_kernel<1, 0, false><<<dim3(nFused), t256, 0, stream>>>(
      x, 3 * N, x, 3 * N, 3, N, N, K, idxK,
      W1, 6, 64, Pt, St,
      x, M, 0, IT1, fpsI, node1, fpsDist, fpsLast, nullptr, nQblk, nGblk, B);

  // ---- ecfinish1 (+sq emit for stage-2 knn) FUSED with fps [208,304)
  ecfps_kernel<<<dim3(B + B * (N / 4)), t256, 0, stream>>>(
      Pt, St, idxK, K, 64, N, g1, b1, xt1, (long)128 * N, sqS2,
      x, N, M, IT1, IT2, fpsI, node1, fpsDist, fpsLast, N / 4, B);

  // ---- stage 2 FUSED: fps [304,512) + knn(x1, precomputed sq) + gemmPS2
  knnfpsgemm_kernel<0, 1, true><<<dim3(nFused), t256, 0, stream>>>(
      xt1, 128 * N, xt1, 128 * N, 64, N, N, K, idxK,
      W2, 128, 64, Pt, St,
      x, M, IT2, M, fpsI, node1, fpsDist, fpsLast, sqS2, nQblk, nGblk, B);

  // ---- FUSED: ecfinish2 (gather-bound) + aggregate-knn (VALU-latency-bound), striped
  ecfagg_kernel<<<dim3(B * nQa + B * (N / 4)), t256, 0, stream>>>(
      Pt, St, idxK, K, 64, N, g2, b2, xt1 + (size_t)64 * N, (long)128 * N,
      node1, 3 * M, x, 3 * N, 3, M, N, K, idxAgg, nQa, N / 4);

  // ---- FUSED: gemm_colmaxA (128-row tiles) + xmfill, striped 1:1
  colmaxxm_kernel<<<dim3(2 * (B * 128 * M) / 256), t256, 0, stream>>>(
      xt1, 128 * N, 128, N, W2m, 128, 1024, g2m, b2m, partA, 16, 16,
      xt1, N, fpsI, idxAgg, K, M, xm);

  // ---- stage 3 FUSED: knn(xm) + gemmPS3
  knngemm_kernel<<<dim3(B * nQa + B * (M / 64) * (256 / 64)), t256, 0, stream>>>(
      xm, 256 * M, 256, M, M, K2, idxK, W3, 512, 256, Pt, St, nQa, M / 64, 256 / 64, B);
  ecfinish_kernel<<<dim3(M, B), dim3(256, 1), 0, stream>>>(Pt, St, idxK, K2, 256, M, g3, b3, xc, (long)512 * M);

  // ---- stage 4 FUSED: knn(x3) + gemmPS4
  knngemm_kernel<<<dim3(B * nQa + B * (M / 64) * (256 / 64)), t256, 0, stream>>>(
      xc, 512 * M, 256, M, M, K2, idxK, W4, 512, 256, Pt, St, nQa, M / 64, 256 / 64, B);
  ecfinish_kernel<<<dim3(M, B), dim3(256, 1), 0, stream>>>(Pt, St, idxK, K2, 256, M, g4, b4,
                                                           xc + (size_t)256 * M, (long)512 * M);

  // ---- vs partials (128-row tiles: M/128 = 4 n-tiles)
  gemm_colmax_kernel<<<dim3(M / 128, 1024 / 64, B), t256, 0, stream>>>(xc, 512 * M, 512, M, W5, 512, 1024,
                                                                       g5, b5, partB);

  // ---- head (fused colmax_finish + MLP; NTa=16, NTb=4 after retiling)
  head_kernel<<<dim3(B), t256, 0, stream>>>(partA, 16, partB, 4,
                                            Wl1, g6, b6, Wl2, bl2, g7, b7, Wl3, bl3, logits);
}

// Round 16
// 1189.367 us; speedup vs baseline: 1.0846x; 1.0846x over previous
//
#include <hip/hip_runtime.h>

#define BN_SCALE 0.9999950000374997f  // 1/sqrt(1+1e-5)

// ---- DPP full-wave reductions (validated in fps/knn since R2/R4) ----
template <int CTRL>
__device__ __forceinline__ float dpp_fmax_step(float v) {
  int xi = __builtin_bit_cast(int, v);
  int ti = __builtin_amdgcn_update_dpp(xi, xi, CTRL, 0xf, 0xf, false);  // invalid lanes -> old(=v)
  return fmaxf(v, __builtin_bit_cast(float, ti));
}
template <int CTRL>
__device__ __forceinline__ int dpp_imin_step(int v) {
  int t = __builtin_amdgcn_update_dpp(v, v, CTRL, 0xf, 0xf, false);    // invalid lanes -> old(=v)
  return (t < v) ? t : v;
}
template <int CTRL>
__device__ __forceinline__ float dpp_fadd_step(float v) {
  // bound_ctrl=true: invalid lanes contribute 0 (required for sums)
  int ti = __builtin_amdgcn_update_dpp(0, __builtin_bit_cast(int, v), CTRL, 0xf, 0xf, true);
  return v + __builtin_bit_cast(float, ti);
}
__device__ __forceinline__ float wave_fmax(float v) {
  v = dpp_fmax_step<0x111>(v);
  v = dpp_fmax_step<0x112>(v);
  v = dpp_fmax_step<0x114>(v);
  v = dpp_fmax_step<0x118>(v);
  v = dpp_fmax_step<0x142>(v);
  v = dpp_fmax_step<0x143>(v);
  return __builtin_bit_cast(float, __builtin_amdgcn_readlane(__builtin_bit_cast(int, v), 63));
}
__device__ __forceinline__ int wave_imin(int v) {
  v = dpp_imin_step<0x111>(v);
  v = dpp_imin_step<0x112>(v);
  v = dpp_imin_step<0x114>(v);
  v = dpp_imin_step<0x118>(v);
  v = dpp_imin_step<0x142>(v);
  v = dpp_imin_step<0x143>(v);
  return __builtin_amdgcn_readlane(v, 63);
}
__device__ __forceinline__ float wave_fadd(float v) {
  v = dpp_fadd_step<0x111>(v);
  v = dpp_fadd_step<0x112>(v);
  v = dpp_fadd_step<0x114>(v);
  v = dpp_fadd_step<0x118>(v);
  v = dpp_fadd_step<0x142>(v);
  v = dpp_fadd_step<0x143>(v);
  return __builtin_bit_cast(float, __builtin_amdgcn_readlane(__builtin_bit_cast(int, v), 63));
}

// ---------------- knn4 body (R14 version: float4 dot + tournament selection) ----------------
template <int R, bool SQPRE>
__device__ __forceinline__ void knn4_body(const float* __restrict__ Q, int qStrideB,
                                          const float* __restrict__ Xc, int cStrideB,
                                          int C, int M, int N, int k, int* __restrict__ idxOut,
                                          const float* __restrict__ sqPre,
                                          int b, int q0, char* smem) {
  constexpr int NR = 4 * R;
  float (*negd)[R * 256] = (float (*)[R * 256])smem;
  int tid = threadIdx.x;
  const float* qb = Q + (long)b * qStrideB + q0;
  const float* cb = Xc + (long)b * cStrideB;
  if constexpr (R % 4 == 0) {
    constexpr int H = R / 4;
    float d0[R], d1[R], d2[R], d3[R], sq[R];
    #pragma unroll
    for (int i = 0; i < R; ++i) { d0[i] = d1[i] = d2[i] = d3[i] = sq[i] = 0.f; }
    for (int c = 0; c < C; ++c) {
      float4 q4 = *(const float4*)(qb + (long)c * M);  // uniform -> scalar load
      const float4* pc4 = (const float4*)(cb + (long)c * N);
      #pragma unroll
      for (int h = 0; h < H; ++h) {
        float4 xv = pc4[tid + 256 * h];                // 16B/lane coalesced
        if (!SQPRE) {
          sq[4 * h + 0] = fmaf(xv.x, xv.x, sq[4 * h + 0]);
          sq[4 * h + 1] = fmaf(xv.y, xv.y, sq[4 * h + 1]);
          sq[4 * h + 2] = fmaf(xv.z, xv.z, sq[4 * h + 2]);
          sq[4 * h + 3] = fmaf(xv.w, xv.w, sq[4 * h + 3]);
        }
        d0[4 * h + 0] = fmaf(q4.x, xv.x, d0[4 * h + 0]);
        d0[4 * h + 1] = fmaf(q4.x, xv.y, d0[4 * h + 1]);
        d0[4 * h + 2] = fmaf(q4.x, xv.z, d0[4 * h + 2]);
        d0[4 * h + 3] = fmaf(q4.x, xv.w, d0[4 * h + 3]);
        d1[4 * h + 0] = fmaf(q4.y, xv.x, d1[4 * h + 0]);
        d1[4 * h + 1] = fmaf(q4.y, xv.y, d1[4 * h + 1]);
        d1[4 * h + 2] = fmaf(q4.y, xv.z, d1[4 * h + 2]);
        d1[4 * h + 3] = fmaf(q4.y, xv.w, d1[4 * h + 3]);
        d2[4 * h + 0] = fmaf(q4.z, xv.x, d2[4 * h + 0]);
        d2[4 * h + 1] = fmaf(q4.z, xv.y, d2[4 * h + 1]);
        d2[4 * h + 2] = fmaf(q4.z, xv.z, d2[4 * h + 2]);
        d2[4 * h + 3] = fmaf(q4.z, xv.w, d2[4 * h + 3]);
        d3[4 * h + 0] = fmaf(q4.w, xv.x, d3[4 * h + 0]);
        d3[4 * h + 1] = fmaf(q4.w, xv.y, d3[4 * h + 1]);
        d3[4 * h + 2] = fmaf(q4.w, xv.z, d3[4 * h + 2]);
        d3[4 * h + 3] = fmaf(q4.w, xv.w, d3[4 * h + 3]);
      }
    }
    #pragma unroll
    for (int h = 0; h < H; ++h) {
      float4 s4;
      if (SQPRE) {
        s4 = ((const float4*)(sqPre + (long)b * N))[tid + 256 * h];
      } else {
        s4 = make_float4(sq[4 * h], sq[4 * h + 1], sq[4 * h + 2], sq[4 * h + 3]);
      }
      ((float4*)negd[0])[tid + 256 * h] =
          make_float4(2.f * d0[4 * h] - s4.x, 2.f * d0[4 * h + 1] - s4.y,
                      2.f * d0[4 * h + 2] - s4.z, 2.f * d0[4 * h + 3] - s4.w);
      ((float4*)negd[1])[tid + 256 * h] =
          make_float4(2.f * d1[4 * h] - s4.x, 2.f * d1[4 * h + 1] - s4.y,
                      2.f * d1[4 * h + 2] - s4.z, 2.f * d1[4 * h + 3] - s4.w);
      ((float4*)negd[2])[tid + 256 * h] =
          make_float4(2.f * d2[4 * h] - s4.x, 2.f * d2[4 * h + 1] - s4.y,
                      2.f * d2[4 * h + 2] - s4.z, 2.f * d2[4 * h + 3] - s4.w);
      ((float4*)negd[3])[tid + 256 * h] =
          make_float4(2.f * d3[4 * h] - s4.x, 2.f * d3[4 * h + 1] - s4.y,
                      2.f * d3[4 * h + 2] - s4.z, 2.f * d3[4 * h + 3] - s4.w);
    }
  } else {
    float d0[R], d1[R], d2[R], d3[R], sq[R];
    #pragma unroll
    for (int i = 0; i < R; ++i) { d0[i] = d1[i] = d2[i] = d3[i] = sq[i] = 0.f; }
    for (int c = 0; c < C; ++c) {
      float4 q4 = *(const float4*)(qb + (long)c * M);
      const float* pc = cb + (long)c * N;
      #pragma unroll
      for (int i = 0; i < R; ++i) {
        float xv = pc[tid + 256 * i];
        sq[i] = fmaf(xv, xv, sq[i]);
        d0[i] = fmaf(q4.x, xv, d0[i]);
        d1[i] = fmaf(q4.y, xv, d1[i]);
        d2[i] = fmaf(q4.z, xv, d2[i]);
        d3[i] = fmaf(q4.w, xv, d3[i]);
      }
    }
    #pragma unroll
    for (int i = 0; i < R; ++i) {
      int m = tid + 256 * i;
      negd[0][m] = 2.f * d0[i] - sq[i];
      negd[1][m] = 2.f * d1[i] - sq[i];
      negd[2][m] = 2.f * d2[i] - sq[i];
      negd[3][m] = 2.f * d3[i] - sq[i];
    }
  }
  __syncthreads();
  int lane = tid & 63, w = tid >> 6;
  const float* row = negd[w];
  int* outp = idxOut + ((long)b * M + (q0 + w)) * k;
  float v[NR];
  #pragma unroll
  for (int i = 0; i < NR; ++i) v[i] = row[lane + 64 * i];
  constexpr int G = NR / 4;
  for (int kk = 0; kk < k; ++kk) {
    float bv[G]; int br[G];
    #pragma unroll
    for (int g = 0; g < G; ++g) {
      float v0 = v[4 * g]; int r0 = 4 * g;
      #pragma unroll
      for (int j = 1; j < 4; ++j) {
        bool c = v[4 * g + j] > v0;
        v0 = c ? v[4 * g + j] : v0;
        r0 = c ? (4 * g + j) : r0;
      }
      bv[g] = v0; br[g] = r0;
    }
    #pragma unroll
    for (int s = G >> 1; s >= 1; s >>= 1) {
      #pragma unroll
      for (int i = 0; i < s; ++i) {
        bool c = bv[2 * i] >= bv[2 * i + 1];
        bv[i] = c ? bv[2 * i] : bv[2 * i + 1];
        br[i] = c ? br[2 * i] : br[2 * i + 1];
      }
    }
    float best = bv[0]; int ib = br[0];
    int bi = (best > -INFINITY) ? (lane + (ib << 6)) : N;
    float gmax = wave_fmax(best);
    int cand = (best == gmax) ? bi : 0x7FFFFFFF;
    int big = wave_imin(cand);
    if (lane == 0) outp[kk] = big;
    int ri = big >> 6;
    bool mine = (lane == (big & 63));
    #pragma unroll
    for (int i = 0; i < NR; ++i)
      if (i == ri) v[i] = mine ? -INFINITY : v[i];
  }
}

template <int R>
__global__ void knn4_kernel(const float* __restrict__ Q, int qStrideB,
                            const float* __restrict__ Xc, int cStrideB,
                            int C, int M, int N, int k, int* __restrict__ idxOut) {
  __shared__ __align__(16) char smem[R * 256 * 4 * 4];
  knn4_body<R, false>(Q, qStrideB, Xc, cStrideB, C, M, N, k, idxOut, nullptr,
                      blockIdx.y, blockIdx.x * 4, smem);
}

// ---------------- gemmPS body ----------------
__device__ __forceinline__ void gemmPS_body(const float* __restrict__ X, int xStrideB, int C, int Np,
                                            const float* __restrict__ W, int ldw, int O,
                                            float* __restrict__ PtT, float* __restrict__ StT,
                                            int b, int n0, int o0, char* smem) {
  float (*Wp)[65] = (float (*)[65])smem;
  float (*Ws)[65] = (float (*)[65])(smem + 4160);
  float (*Xt)[65] = (float (*)[65])(smem + 8320);
  int tid = threadIdx.x;
  int to = tid % 16, tn = tid / 16;
  float accP[4][4] = {}, accS[4][4] = {};
  for (int c0 = 0; c0 < C; c0 += 16) {
    for (int e = tid; e < 16 * 64; e += 256) {
      int oo = e / 16, kk = e % 16;
      int c = c0 + kk, o = o0 + oo;
      bool ok = (c < C && o < O);
      Wp[kk][oo] = ok ? W[(long)o * ldw + c] : 0.f;
      Ws[kk][oo] = ok ? W[(long)o * ldw + C + c] : 0.f;
    }
    for (int e = tid; e < 16 * 64; e += 256) {
      int kk = e / 64, nn = e % 64;
      int c = c0 + kk, n = n0 + nn;
      Xt[kk][nn] = (c < C && n < Np) ? X[(long)b * xStrideB + (long)c * Np + n] : 0.f;
    }
    __syncthreads();
    for (int kk = 0; kk < 16; ++kk) {
      float xv[4], wp[4], ws[4];
      for (int i = 0; i < 4; ++i) xv[i] = Xt[kk][tn + 16 * i];
      for (int j = 0; j < 4; ++j) { wp[j] = Wp[kk][to + 16 * j]; ws[j] = Ws[kk][to + 16 * j]; }
      for (int i = 0; i < 4; ++i)
        for (int j = 0; j < 4; ++j) {
          accP[i][j] = fmaf(xv[i], wp[j], accP[i][j]);
          accS[i][j] = fmaf(xv[i], ws[j], accS[i][j]);
        }
    }
    __syncthreads();
  }
  for (int i = 0; i < 4; ++i) {
    int n = n0 + tn + 16 * i;
    if (n >= Np) continue;
    for (int j = 0; j < 4; ++j) {
      int o = o0 + to + 16 * j;
      if (o < O) {
        long off = ((long)b * Np + n) * O + o;
        PtT[off] = accP[i][j];
        StT[off] = accS[i][j];
      }
    }
  }
}

// ---------------- ecfinish body (O=64 flat-256 variant) ----------------
__device__ __forceinline__ void ecfinish_body64(const float* __restrict__ Pt, const float* __restrict__ St,
                                                const int* __restrict__ idx, int k, int O, int Np,
                                                const float* __restrict__ g, const float* __restrict__ bb,
                                                float* __restrict__ outp, long oStrideB,
                                                float* __restrict__ sqOut,
                                                int b, int blk) {
  int tid = threadIdx.x;
  int o = tid & 63;
  int n = blk * 4 + (tid >> 6);
  const float* PtB = Pt + (long)b * Np * O;
  const float* StB = St + (long)b * Np * O;
  const int* ip = idx + ((long)b * Np + n) * k;
  float mx = -INFINITY, mn = INFINITY;
  for (int kk = 0; kk < k; ++kk) {
    float v = PtB[(long)ip[kk] * O + o];
    mx = fmaxf(mx, v); mn = fminf(mn, v);
  }
  float ctrP = PtB[(long)n * O + o];
  float ctrS = StB[(long)n * O + o];
  float gs = g[o] * BN_SCALE;
  float m = (gs >= 0.f) ? mx : mn;
  float h = (ctrS - ctrP + m) * gs + bb[o];
  float out = h >= 0.f ? h : 0.2f * h;
  outp[(long)b * oStrideB + (long)o * Np + n] = out;
  if (sqOut) {
    int obits = __builtin_bit_cast(int, out);
    float acc = 0.f;
    #pragma unroll
    for (int c = 0; c < 64; ++c) {
      float hv = __builtin_bit_cast(float, __builtin_amdgcn_readlane(obits, c));
      acc = fmaf(hv, hv, acc);
    }
    if (o == 0) sqOut[(long)b * Np + n] = acc;
  }
}

__global__ void ecfinish_kernel(const float* __restrict__ Pt, const float* __restrict__ St,
                                const int* __restrict__ idx, int k, int O, int Np,
                                const float* __restrict__ g, const float* __restrict__ bb,
                                float* __restrict__ outp, long oStrideB) {
  int b = blockIdx.y;
  int n = blockIdx.x * blockDim.y + threadIdx.y;
  int o = threadIdx.x;
  const float* PtB = Pt + (long)b * Np * O;
  const float* StB = St + (long)b * Np * O;
  const int* ip = idx + ((long)b * Np + n) * k;
  float mx = -INFINITY, mn = INFINITY;
  for (int kk = 0; kk < k; ++kk) {
    float v = PtB[(long)ip[kk] * O + o];
    mx = fmaxf(mx, v); mn = fminf(mn, v);
  }
  float ctrP = PtB[(long)n * O + o];
  float ctrS = StB[(long)n * O + o];
  float gs = g[o] * BN_SCALE;
  float m = (gs >= 0.f) ? mx : mn;
  float h = (ctrS - ctrP + m) * gs + bb[o];
  outp[(long)b * oStrideB + (long)o * Np + n] = h >= 0.f ? h : 0.2f * h;
}

// ---------------- gemm_colmax body (R14 64-tile version — R15 128-tile REVERTED:
// the 8x4-acc retile raised VGPR in the fused colmaxxm kernel, cutting xmfill's
// occupancy 8->5 blocks/CU; xmfill is gather-latency-bound -> -106us total) --------
__device__ __forceinline__ void gemm_colmax_body(const float* __restrict__ X, int xStrideB, int C, int Np,
                                                 const float* __restrict__ W, int ldw, int O,
                                                 const float* __restrict__ g, const float* __restrict__ bb,
                                                 float* __restrict__ partial,
                                                 int b, int n0, int o0, int nt, int nNT, char* smem) {
  float (*Wt)[65] = (float (*)[65])smem;
  float (*Xt)[65] = (float (*)[65])(smem + 4160);
  int tid = threadIdx.x;
  int to = tid % 16, tn = tid / 16;
  float acc[4][4] = {};
  for (int c0 = 0; c0 < C; c0 += 16) {
    for (int e = tid; e < 16 * 64; e += 256) {
      int oo = e / 16, kk = e % 16;
      int c = c0 + kk, o = o0 + oo;
      Wt[kk][oo] = (c < C && o < O) ? W[(long)o * ldw + c] : 0.f;
    }
    for (int e = tid; e < 16 * 64; e += 256) {
      int kk = e / 64, nn = e % 64;
      int c = c0 + kk, n = n0 + nn;
      Xt[kk][nn] = (c < C && n < Np) ? X[(long)b * xStrideB + (long)c * Np + n] : 0.f;
    }
    __syncthreads();
    for (int kk = 0; kk < 16; ++kk) {
      float xv[4], wv[4];
      for (int i = 0; i < 4; ++i) xv[i] = Xt[kk][tn + 16 * i];
      for (int j = 0; j < 4; ++j) wv[j] = Wt[kk][to + 16 * j];
      for (int i = 0; i < 4; ++i)
        for (int j = 0; j < 4; ++j) acc[i][j] = fmaf(xv[i], wv[j], acc[i][j]);
    }
    __syncthreads();
  }
  float vm[4];
  for (int j = 0; j < 4; ++j) {
    int o = o0 + to + 16 * j;
    float gs = g[o] * BN_SCALE, bo = bb[o];
    float m = -INFINITY;
    for (int i = 0; i < 4; ++i) {
      float h = acc[i][j] * gs + bo;
      h = h >= 0.f ? h : 0.2f * h;
      m = fmaxf(m, h);
    }
    vm[j] = m;
  }
  for (int j = 0; j < 4; ++j) Xt[tn][to + 16 * j] = vm[j];
  __syncthreads();
  for (int s = 8; s > 0; s >>= 1) {
    if (tn < s)
      for (int j = 0; j < 4; ++j)
        Xt[tn][to + 16 * j] = fmaxf(Xt[tn][to + 16 * j], Xt[tn + s][to + 16 * j]);
    __syncthreads();
  }
  if (tn == 0)
    for (int j = 0; j < 4; ++j) {
      int o = o0 + to + 16 * j;
      partial[((long)b * nNT + nt) * O + o] = Xt[0][to + 16 * j];
    }
}

__global__ void gemm_colmax_kernel(const float* __restrict__ X, int xStrideB, int C, int Np,
                                   const float* __restrict__ W, int ldw, int O,
                                   const float* __restrict__ g, const float* __restrict__ bb,
                                   float* __restrict__ partial) {
  __shared__ __align__(16) char smem[2 * 4160];
  gemm_colmax_body(X, xStrideB, C, Np, W, ldw, O, g, bb, partial,
                   blockIdx.z, blockIdx.x * 64, blockIdx.y * 64, blockIdx.x, gridDim.x, smem);
}

// ---------------- xmfill body ----------------
__device__ __forceinline__ void xmfill_body(const float* __restrict__ xt1, int N,
                                            const int* __restrict__ fpsI,
                                            const int* __restrict__ idxA, int k, int M,
                                            float* __restrict__ xm, int xe) {
  long t = (long)xe * 256 + threadIdx.x;
  int i = (int)(t % M);
  int c = (int)((t / M) % 128);
  int b = (int)(t / ((long)128 * M));
  const float* xb = xt1 + (long)b * 128 * N + (long)c * N;
  float* xmB = xm + (long)b * 256 * M;
  xmB[(long)c * M + i] = xb[fpsI[(long)b * M + i]];
  const int* ip = idxA + ((long)b * M + i) * k;
  float best = -INFINITY;
  for (int kk = 0; kk < k; ++kk) best = fmaxf(best, xb[ip[kk]]);
  xmB[(long)(128 + c) * M + i] = best;
}

// ---------------- FPS body, RANGE-split (unchanged) ----------------
template <int FIRST, int LAST>
__device__ __forceinline__ void fps_body_rg(const float* __restrict__ xyz, int N, int M,
                                            int it0, int it1,
                                            int* __restrict__ fpsIdx, float* __restrict__ node1,
                                            float* __restrict__ distSv, int* __restrict__ lastSv,
                                            int b, char* smem) {
  #pragma clang fp contract(off)
  float4* sp4 = (float4*)smem;                 // 2048 pts: slot (n&7)*256 + (n>>3)
  int*    fidx = (int*)(smem + 32768);
  float4* wvc  = (float4*)(smem + 32768 + 2048);
  int*    wis  = (int*)(smem + 32768 + 2048 + 128);
  int tid = threadIdx.x;
  int lane = tid & 63, w = tid >> 6;
  const float* xb = xyz + (long)b * 3 * N;
  for (int n = tid; n < N; n += 256) {
    sp4[((n & 7) << 8) | (n >> 3)] = make_float4(xb[n], xb[N + n], xb[2 * N + n], 0.f);
  }
  if (!FIRST) {
    for (int e = tid; e < it0; e += 256) fidx[e] = fpsIdx[(long)b * M + e];
  }
  __syncthreads();
  float4 pt[8];
  #pragma unroll
  for (int i = 0; i < 8; ++i) pt[i] = sp4[(i << 8) | tid];
  float dist[8];
  int last;
  float lx, ly, lz;
  if (FIRST) {
    #pragma unroll
    for (int i = 0; i < 8; ++i) dist[i] = 1e10f;
    last = 0;
    float4 l0 = sp4[0];
    lx = l0.x; ly = l0.y; lz = l0.z;
  } else {
    #pragma unroll
    for (int i = 0; i < 8; ++i) dist[i] = distSv[(long)b * 2048 + i * 256 + tid];
    last = lastSv[b];
    float4 lp = sp4[((last & 7) << 8) | (last >> 3)];
    lx = lp.x; ly = lp.y; lz = lp.z;
  }
  int base = tid * 8;
  for (int it = it0; it < it1; ++it) {
    int p = it & 1;
    if (tid == 0) fidx[it] = last;
    float best = -INFINITY; int bi = N;
    #pragma unroll
    for (int i = 0; i < 8; ++i) {
      float dx = pt[i].x - lx, dy = pt[i].y - ly, dz = pt[i].z - lz;
      float dx2 = dx * dx, dy2 = dy * dy, dz2 = dz * dz;
      float d = (dx2 + dy2) + dz2;
      float dn = dist[i];
      if (d < dn) dn = d;
      dist[i] = dn;
      if (dn > best) { best = dn; bi = base + i; }
    }
    float cx = pt[0].x, cy = pt[0].y, cz = pt[0].z;
    #pragma unroll
    for (int i = 1; i < 8; ++i) {
      bool c = (bi == base + i);
      cx = c ? pt[i].x : cx; cy = c ? pt[i].y : cy; cz = c ? pt[i].z : cz;
    }
    float gmax = wave_fmax(best);
    int cand = (best == gmax) ? bi : 0x7FFFFFFF;
    int wbi = wave_imin(cand);
    if (bi == wbi) { wvc[p * 4 + w] = make_float4(gmax, cx, cy, cz); wis[p * 4 + w] = wbi; }
    __syncthreads();
    float4 c0 = wvc[p * 4 + 0], c1 = wvc[p * 4 + 1], c2 = wvc[p * 4 + 2], c3 = wvc[p * 4 + 3];
    int i0 = wis[p * 4 + 0], i1 = wis[p * 4 + 1], i2 = wis[p * 4 + 2], i3 = wis[p * 4 + 3];
    float bv = c0.x; int bbi = i0; lx = c0.y; ly = c0.z; lz = c0.w;
    { bool c = (c1.x > bv) || (c1.x == bv && i1 < bbi);
      bv = c ? c1.x : bv; bbi = c ? i1 : bbi; lx = c ? c1.y : lx; ly = c ? c1.z : ly; lz = c ? c1.w : lz; }
    { bool c = (c2.x > bv) || (c2.x == bv && i2 < bbi);
      bv = c ? c2.x : bv; bbi = c ? i2 : bbi; lx = c ? c2.y : lx; ly = c ? c2.z : ly; lz = c ? c2.w : lz; }
    { bool c = (c3.x > bv) || (c3.x == bv && i3 < bbi);
      bv = c ? c3.x : bv; bbi = c ? i3 : bbi; lx = c ? c3.y : lx; ly = c ? c3.z : ly; lz = c ? c3.w : lz; }
    last = bbi;
    // parity: slot p rewritten only in iter it+2, after barrier it+1 -> safe with 1 barrier
  }
  if (!LAST) {
    for (int e = tid; e < it1; e += 256) {
      if (e >= it0) fpsIdx[(long)b * M + e] = fidx[e];
    }
    #pragma unroll
    for (int i = 0; i < 8; ++i) distSv[(long)b * 2048 + i * 256 + tid] = dist[i];
    if (tid == 0) lastSv[b] = last;
  } else {
    for (int e = tid; e < M; e += 256) fpsIdx[(long)b * M + e] = fidx[e];
    for (int e = tid; e < 3 * M; e += 256) {
      int c = e / M, i = e % M;
      int src = fidx[i];
      float4 ptc = sp4[((src & 7) << 8) | (src >> 3)];
      node1[(long)b * 3 * M + e] = (c == 0) ? ptc.x : (c == 1) ? ptc.y : ptc.z;
    }
  }
}

// ---------------- fused {fps-range + knn + gemmPS}, 1D grid, fps first ----------------
template <int FIRST, int LAST, bool SQP>
__global__ void knnfpsgemm_kernel(const float* __restrict__ Q, int qStrideB,
                                  const float* __restrict__ Xc, int cStrideB,
                                  int C, int Mq, int N, int k, int* __restrict__ idxOut,
                                  const float* __restrict__ W, int ldw, int O,
                                  float* __restrict__ Pt, float* __restrict__ St,
                                  const float* __restrict__ xyz, int Mf, int it0, int it1,
                                  int* __restrict__ fpsIdx, float* __restrict__ node1,
                                  float* __restrict__ distSv, int* __restrict__ lastSv,
                                  const float* __restrict__ sqPre,
                                  int nQblk, int nGblk, int nB) {
  __shared__ __align__(16) char smem[32768 + 2048 + 128 + 32];
  int bid = blockIdx.x;
  if (bid < nB) {
    __builtin_amdgcn_s_setprio(1);
    fps_body_rg<FIRST, LAST>(xyz, N, Mf, it0, it1, fpsIdx, node1, distSv, lastSv, bid, smem);
    __builtin_amdgcn_s_setprio(0);
  } else if (bid < nB + nB * nQblk) {
    int e = bid - nB;
    knn4_body<8, SQP>(Q, qStrideB, Xc, cStrideB, C, Mq, N, k, idxOut, sqPre,
                      e / nQblk, (e % nQblk) * 4, smem);
  } else {
    int e = bid - nB - nB * nQblk;
    gemmPS_body(Xc, cStrideB, C, N, W, ldw, O, Pt, St,
                e / nGblk, (e % nGblk) * 64, 0, smem);
  }
}

// ---------------- fused {ecfinish1 (+sq emit) + fps mid-range}, fps blocks first --------
__global__ void ecfps_kernel(const float* __restrict__ Pt, const float* __restrict__ St,
                             const int* __restrict__ idx, int k, int O, int Np,
                             const float* __restrict__ g, const float* __restrict__ bb,
                             float* __restrict__ outp, long oStrideB,
                             float* __restrict__ sqOut,
                             const float* __restrict__ xyz, int N, int Mf, int it0, int it1,
                             int* __restrict__ fpsIdx, float* __restrict__ node1,
                             float* __restrict__ distSv, int* __restrict__ lastSv,
                             int nEperB, int nB) {
  __shared__ __align__(16) char smem[32768 + 2048 + 128 + 32];
  int bid = blockIdx.x;
  if (bid < nB) {
    __builtin_amdgcn_s_setprio(1);
    fps_body_rg<0, 0>(xyz, N, Mf, it0, it1, fpsIdx, node1, distSv, lastSv, bid, smem);
    __builtin_amdgcn_s_setprio(0);
  } else {
    int e = bid - nB;
    ecfinish_body64(Pt, St, idx, k, O, Np, g, bb, outp, oStrideB, sqOut,
                    e / nEperB, e % nEperB);
  }
}

// ---------------- fused {ecfinish2 + agg-knn}, striped (agg every 5th bid) ----------------
__global__ void ecfagg_kernel(const float* __restrict__ Pt, const float* __restrict__ St,
                              const int* __restrict__ idxS2, int k2, int O2, int Np2,
                              const float* __restrict__ g2, const float* __restrict__ b2,
                              float* __restrict__ out2, long oStrideB2,
                              const float* __restrict__ Qn, int qStrideB,
                              const float* __restrict__ Xc, int cStrideB,
                              int Cq, int Mq, int Nc, int kq, int* __restrict__ idxAgg,
                              int nQblk, int nEperB) {
  __shared__ __align__(16) char smem[32768];
  int bid = blockIdx.x;
  if (bid % 5 == 0) {
    int a = bid / 5;                       // [0, 1024)
    knn4_body<8, false>(Qn, qStrideB, Xc, cStrideB, Cq, Mq, Nc, kq, idxAgg, nullptr,
                        a / nQblk, (a % nQblk) * 4, smem);
  } else {
    int e = bid - bid / 5 - 1;             // [0, 4096) sequential
    ecfinish_body64(Pt, St, idxS2, k2, O2, Np2, g2, b2, out2, oStrideB2, nullptr,
                    e / nEperB, e % nEperB);
  }
}

// ---------------- fused {gemm_colmaxA + xmfill}, striped (xmfill every 3rd bid) ----------------
__global__ void colmaxxm_kernel(const float* __restrict__ X, int xStrideB, int C, int Np,
                                const float* __restrict__ W, int ldw, int O,
                                const float* __restrict__ g, const float* __restrict__ bb,
                                float* __restrict__ partial, int nNT, int nOT,
                                const float* __restrict__ xt1, int N,
                                const int* __restrict__ fpsI, const int* __restrict__ idxA,
                                int kq, int M, float* __restrict__ xm) {
  __shared__ __align__(16) char smem[2 * 4160];
  int bid = blockIdx.x;
  if (bid % 3 == 0) {
    xmfill_body(xt1, N, fpsI, idxA, kq, M, xm, bid / 3);       // [0, 2048)
  } else {
    int e = bid - bid / 3 - 1;                                  // [0, 4096)
    int per = nNT * nOT;
    int b = e / per, r = e % per;
    int nt = r % nNT, ot = r / nNT;
    gemm_colmax_body(X, xStrideB, C, Np, W, ldw, O, g, bb, partial,
                     b, nt * 64, ot * 64, nt, nNT, smem);
  }
}

// ---------------- fused {knn<2> + gemmPS} for stages 3/4 ----------------
__global__ void knngemm_kernel(const float* __restrict__ Xin, int xStrideB,
                               int C, int Mq, int N, int k, int* __restrict__ idxOut,
                               const float* __restrict__ W, int ldw, int O,
                               float* __restrict__ Pt, float* __restrict__ St,
                               int nQblk, int nGn, int nGo, int nB) {
  __shared__ __align__(16) char smem[3 * 4160];
  int bid = blockIdx.x;
  if (bid < nB * nQblk) {
    knn4_body<2, false>(Xin, xStrideB, Xin, xStrideB, C, Mq, N, k, idxOut, nullptr,
                        bid / nQblk, (bid % nQblk) * 4, smem);
  } else {
    int e = bid - nB * nQblk;
    int per = nGn * nGo;
    int b = e / per, r = e % per;
    int nt = r % nGn, ot = r / nGn;
    gemmPS_body(Xin, xStrideB, C, N, W, ldw, O, Pt, St, b, nt * 64, ot * 64, smem);
  }
}

// ---------------- head: fused colmax_finish + 3-layer MLP (wave-cooperative) ----------------
__global__ void head_kernel(const float* __restrict__ partA, int NTa,
                            const float* __restrict__ partB, int NTb,
                            const float* __restrict__ Wl1, const float* __restrict__ g6, const float* __restrict__ b6,
                            const float* __restrict__ Wl2, const float* __restrict__ bl2,
                            const float* __restrict__ g7, const float* __restrict__ b7,
                            const float* __restrict__ Wl3, const float* __restrict__ bl3,
                            float* __restrict__ logits) {
  __shared__ float v[2048];
  __shared__ float h1[512];
  __shared__ float h2[256];
  int b = blockIdx.x, tid = threadIdx.x;
  int lane = tid & 63, w = tid >> 6;
  for (int o = tid; o < 1024; o += 256) {
    float m = -INFINITY;
    for (int t = 0; t < NTa; ++t) m = fmaxf(m, partA[((long)b * NTa + t) * 1024 + o]);
    v[o] = m;
    float m2 = -INFINITY;
    for (int t = 0; t < NTb; ++t) m2 = fmaxf(m2, partB[((long)b * NTb + t) * 1024 + o]);
    v[1024 + o] = m2;
  }
  __syncthreads();
  for (int o = w; o < 512; o += 4) {
    const float4* wr = (const float4*)(Wl1 + (long)o * 2048);
    const float4* vp = (const float4*)v;
    float s = 0.f;
    #pragma unroll
    for (int j = 0; j < 8; ++j) {
      float4 w4 = wr[lane + 64 * j];
      float4 v4 = vp[lane + 64 * j];
      s = fmaf(w4.x, v4.x, s); s = fmaf(w4.y, v4.y, s);
      s = fmaf(w4.z, v4.z, s); s = fmaf(w4.w, v4.w, s);
    }
    float t = wave_fadd(s);
    if (lane == 0) {
      float h = t * (g6[o] * BN_SCALE) + b6[o];
      h1[o] = h >= 0.f ? h : 0.2f * h;
    }
  }
  __syncthreads();
  for (int o = w; o < 256; o += 4) {
    const float4* wr = (const float4*)(Wl2 + (long)o * 512);
    const float4* hp = (const float4*)h1;
    float s = 0.f;
    #pragma unroll
    for (int j = 0; j < 2; ++j) {
      float4 w4 = wr[lane + 64 * j];
      float4 v4 = hp[lane + 64 * j];
      s = fmaf(w4.x, v4.x, s); s = fmaf(w4.y, v4.y, s);
      s = fmaf(w4.z, v4.z, s); s = fmaf(w4.w, v4.w, s);
    }
    float t = wave_fadd(s);
    if (lane == 0) {
      float sb = t + bl2[o];
      float h = sb * (g7[o] * BN_SCALE) + b7[o];
      h2[o] = h >= 0.f ? h : 0.2f * h;
    }
  }
  __syncthreads();
  for (int o = w; o < 40; o += 4) {
    const float4* wr = (const float4*)(Wl3 + (long)o * 256);
    const float4* hp = (const float4*)h2;
    float4 w4 = wr[lane];
    float4 v4 = hp[lane];
    float s = fmaf(w4.x, v4.x, 0.f);
    s = fmaf(w4.y, v4.y, s); s = fmaf(w4.z, v4.z, s); s = fmaf(w4.w, v4.w, s);
    float t = wave_fadd(s);
    if (lane == 0) logits[(long)b * 40 + o] = t + bl3[o];
  }
}

extern "C" void kernel_launch(void* const* d_in, const int* in_sizes, int n_in,
                              void* d_out, int out_size, void* d_ws, size_t ws_size,
                              hipStream_t stream) {
  const float* x   = (const float*)d_in[0];
  const float* W1  = (const float*)d_in[1];
  const float* g1  = (const float*)d_in[2];
  const float* b1  = (const float*)d_in[3];
  const float* W2  = (const float*)d_in[4];
  const float* g2  = (const float*)d_in[5];
  const float* b2  = (const float*)d_in[6];
  const float* W2m = (const float*)d_in[7];
  const float* g2m = (const float*)d_in[8];
  const float* b2m = (const float*)d_in[9];
  const float* W3  = (const float*)d_in[10];
  const float* g3  = (const float*)d_in[11];
  const float* b3  = (const float*)d_in[12];
  const float* W4  = (const float*)d_in[13];
  const float* g4  = (const float*)d_in[14];
  const float* b4  = (const float*)d_in[15];
  const float* W5  = (const float*)d_in[16];
  const float* g5  = (const float*)d_in[17];
  const float* b5  = (const float*)d_in[18];
  const float* Wl1 = (const float*)d_in[19];
  const float* g6  = (const float*)d_in[20];
  const float* b6  = (const float*)d_in[21];
  const float* Wl2 = (const float*)d_in[22];
  const float* bl2 = (const float*)d_in[23];
  const float* g7  = (const float*)d_in[24];
  const float* b7  = (const float*)d_in[25];
  const float* Wl3 = (const float*)d_in[26];
  const float* bl3 = (const float*)d_in[27];
  float* outF = (float*)d_out;

  const int B = 8, N = 2048, K = 20, M = 512, K2 = 10;

  float* ws    = (float*)d_ws;
  float* xt1   = ws;                               // (B,128,N)
  float* xm    = xt1 + (size_t)B * 128 * N;        // (B,256,M)
  float* xc    = xm  + (size_t)B * 256 * M;        // (B,512,M)
  float* Pt    = xc  + (size_t)B * 512 * M;        // max(B*N*64, B*M*256)
  float* St    = Pt  + (size_t)B * N * 64;
  float* partA = St  + (size_t)B * N * 64;         // (B,32,1024)
  float* partB = partA + (size_t)B * 32 * 1024;    // (B,8,1024)
  int*   idxK  = (int*)(partB + (size_t)B * 8 * 1024);  // (B,N,K)
  int*   fpsI  = idxK + (size_t)B * N * K;         // (B,M)
  float* fpsDist = (float*)(fpsI + (size_t)B * M); // (B,2048) fps checkpoint dists
  int*   fpsLast = (int*)(fpsDist + (size_t)B * 2048);  // (B)
  int*   idxAgg  = fpsLast + 64;                   // (B,M,K) aggregate-knn indices
  float* sqS2    = (float*)(idxAgg + (size_t)B * M * K); // (B,N) stage-2 candidate norms

  float* logits = outF;        // (B,40)
  float* node1  = outF + 320;  // (B,3,M)

  dim3 t256(256);
  const int nQblk = N / 4;     // 512 knn query-blocks per batch (N-point knn)
  const int nGblk = N / 64;    // 32 gemmPS n-tiles per batch (stage 1/2)
  const int nFused = B + B * nQblk + B * nGblk;
  const int nQa = M / 4;       // 128 agg/stage3/4 knn query-blocks per batch
  const int IT1 = 208, IT2 = 304;   // fps phase boundaries (kept from R15; stage kernels host more)

  // ---- stage 1 FUSED: fps [0,208) + knn(xyz) + gemmPS1 (all depend only on x)
  knnfpsgemm_kernel<1, 0, false><<<dim3(nFused), t256, 0, stream>>>(
      x, 3 * N, x, 3 * N, 3, N, N, K, idxK,
      W1, 6, 64, Pt, St,
      x, M, 0, IT1, fpsI, node1, fpsDist, fpsLast, nullptr, nQblk, nGblk, B);

  // ---- ecfinish1 (+sq emit for stage-2 knn) FUSED with fps [208,304)
  ecfps_kernel<<<dim3(B + B * (N / 4)), t256, 0, stream>>>(
      Pt, St, idxK, K, 64, N, g1, b1, xt1, (long)128 * N, sqS2,
      x, N, M, IT1, IT2, fpsI, node1, fpsDist, fpsLast, N / 4, B);

  // ---- stage 2 FUSED: fps [304,512) + knn(x1, precomputed sq) + gemmPS2
  knnfpsgemm_kernel<0, 1, true><<<dim3(nFused), t256, 0, stream>>>(
      xt1, 128 * N, xt1, 128 * N, 64, N, N, K, idxK,
      W2, 128, 64, Pt, St,
      x, M, IT2, M, fpsI, node1, fpsDist, fpsLast, sqS2, nQblk, nGblk, B);

  // ---- FUSED: ecfinish2 (gather-bound) + aggregate-knn (VALU-latency-bound), striped
  ecfagg_kernel<<<dim3(B * nQa + B * (N / 4)), t256, 0, stream>>>(
      Pt, St, idxK, K, 64, N, g2, b2, xt1 + (size_t)64 * N, (long)128 * N,
      node1, 3 * M, x, 3 * N, 3, M, N, K, idxAgg, nQa, N / 4);

  // ---- FUSED: gemm_colmaxA (64-tile, R14) + xmfill, striped every-3rd
  colmaxxm_kernel<<<dim3((B * 128 * M) / 256 + B * 32 * 16), t256, 0, stream>>>(
      xt1, 128 * N, 128, N, W2m, 128, 1024, g2m, b2m, partA, 32, 16,
      xt1, N, fpsI, idxAgg, K, M, xm);

  // ---- stage 3 FUSED: knn(xm) + gemmPS3
  knngemm_kernel<<<dim3(B * nQa + B * (M / 64) * (256 / 64)), t256, 0, stream>>>(
      xm, 256 * M, 256, M, M, K2, idxK, W3, 512, 256, Pt, St, nQa, M / 64, 256 / 64, B);
  ecfinish_kernel<<<dim3(M, B), dim3(256, 1), 0, stream>>>(Pt, St, idxK, K2, 256, M, g3, b3, xc, (long)512 * M);

  // ---- stage 4 FUSED: knn(x3) + gemmPS4
  knngemm_kernel<<<dim3(B * nQa + B * (M / 64) * (256 / 64)), t256, 0, stream>>>(
      xc, 512 * M, 256, M, M, K2, idxK, W4, 512, 256, Pt, St, nQa, M / 64, 256 / 64, B);
  ecfinish_kernel<<<dim3(M, B), dim3(256, 1), 0, stream>>>(Pt, St, idxK, K2, 256, M, g4, b4,
                                                           xc + (size_t)256 * M, (long)512 * M);

  // ---- vs partials (64-tile, R14: M/64 = 8 n-tiles)
  gemm_colmax_kernel<<<dim3(M / 64, 1024 / 64, B), t256, 0, stream>>>(xc, 512 * M, 512, M, W5, 512, 1024,
                                                                      g5, b5, partB);

  // ---- head (fused colmax_finish + MLP; NTa=32, NTb=8)
  head_kernel<<<dim3(B), t256, 0, stream>>>(partA, N / 64, partB, M / 64,
                                            Wl1, g6, b6, Wl2, bl2, g7, b7, Wl3, bl3, logits);
}

// Round 17
// 1064.094 us; speedup vs baseline: 1.2123x; 1.1177x over previous
//
#include <hip/hip_runtime.h>

#define BN_SCALE 0.9999950000374997f  // 1/sqrt(1+1e-5)

// ---- DPP full-wave reductions (validated in fps/knn since R2/R4) ----
template <int CTRL>
__device__ __forceinline__ float dpp_fmax_step(float v) {
  int xi = __builtin_bit_cast(int, v);
  int ti = __builtin_amdgcn_update_dpp(xi, xi, CTRL, 0xf, 0xf, false);  // invalid lanes -> old(=v)
  return fmaxf(v, __builtin_bit_cast(float, ti));
}
template <int CTRL>
__device__ __forceinline__ int dpp_imin_step(int v) {
  int t = __builtin_amdgcn_update_dpp(v, v, CTRL, 0xf, 0xf, false);    // invalid lanes -> old(=v)
  return (t < v) ? t : v;
}
template <int CTRL>
__device__ __forceinline__ float dpp_fadd_step(float v) {
  // bound_ctrl=true: invalid lanes contribute 0 (required for sums)
  int ti = __builtin_amdgcn_update_dpp(0, __builtin_bit_cast(int, v), CTRL, 0xf, 0xf, true);
  return v + __builtin_bit_cast(float, ti);
}
__device__ __forceinline__ float wave_fmax(float v) {
  v = dpp_fmax_step<0x111>(v);
  v = dpp_fmax_step<0x112>(v);
  v = dpp_fmax_step<0x114>(v);
  v = dpp_fmax_step<0x118>(v);
  v = dpp_fmax_step<0x142>(v);
  v = dpp_fmax_step<0x143>(v);
  return __builtin_bit_cast(float, __builtin_amdgcn_readlane(__builtin_bit_cast(int, v), 63));
}
__device__ __forceinline__ int wave_imin(int v) {
  v = dpp_imin_step<0x111>(v);
  v = dpp_imin_step<0x112>(v);
  v = dpp_imin_step<0x114>(v);
  v = dpp_imin_step<0x118>(v);
  v = dpp_imin_step<0x142>(v);
  v = dpp_imin_step<0x143>(v);
  return __builtin_amdgcn_readlane(v, 63);
}
__device__ __forceinline__ float wave_fadd(float v) {
  v = dpp_fadd_step<0x111>(v);
  v = dpp_fadd_step<0x112>(v);
  v = dpp_fadd_step<0x114>(v);
  v = dpp_fadd_step<0x118>(v);
  v = dpp_fadd_step<0x142>(v);
  v = dpp_fadd_step<0x143>(v);
  return __builtin_bit_cast(float, __builtin_amdgcn_readlane(__builtin_bit_cast(int, v), 63));
}

// ---------------- knn4 body (R14 version: float4 dot + tournament selection) ----------------
template <int R, bool SQPRE>
__device__ __forceinline__ void knn4_body(const float* __restrict__ Q, int qStrideB,
                                          const float* __restrict__ Xc, int cStrideB,
                                          int C, int M, int N, int k, int* __restrict__ idxOut,
                                          const float* __restrict__ sqPre,
                                          int b, int q0, char* smem) {
  constexpr int NR = 4 * R;
  float (*negd)[R * 256] = (float (*)[R * 256])smem;
  int tid = threadIdx.x;
  const float* qb = Q + (long)b * qStrideB + q0;
  const float* cb = Xc + (long)b * cStrideB;
  if constexpr (R % 4 == 0) {
    constexpr int H = R / 4;
    float d0[R], d1[R], d2[R], d3[R], sq[R];
    #pragma unroll
    for (int i = 0; i < R; ++i) { d0[i] = d1[i] = d2[i] = d3[i] = sq[i] = 0.f; }
    for (int c = 0; c < C; ++c) {
      float4 q4 = *(const float4*)(qb + (long)c * M);  // uniform -> scalar load
      const float4* pc4 = (const float4*)(cb + (long)c * N);
      #pragma unroll
      for (int h = 0; h < H; ++h) {
        float4 xv = pc4[tid + 256 * h];                // 16B/lane coalesced
        if (!SQPRE) {
          sq[4 * h + 0] = fmaf(xv.x, xv.x, sq[4 * h + 0]);
          sq[4 * h + 1] = fmaf(xv.y, xv.y, sq[4 * h + 1]);
          sq[4 * h + 2] = fmaf(xv.z, xv.z, sq[4 * h + 2]);
          sq[4 * h + 3] = fmaf(xv.w, xv.w, sq[4 * h + 3]);
        }
        d0[4 * h + 0] = fmaf(q4.x, xv.x, d0[4 * h + 0]);
        d0[4 * h + 1] = fmaf(q4.x, xv.y, d0[4 * h + 1]);
        d0[4 * h + 2] = fmaf(q4.x, xv.z, d0[4 * h + 2]);
        d0[4 * h + 3] = fmaf(q4.x, xv.w, d0[4 * h + 3]);
        d1[4 * h + 0] = fmaf(q4.y, xv.x, d1[4 * h + 0]);
        d1[4 * h + 1] = fmaf(q4.y, xv.y, d1[4 * h + 1]);
        d1[4 * h + 2] = fmaf(q4.y, xv.z, d1[4 * h + 2]);
        d1[4 * h + 3] = fmaf(q4.y, xv.w, d1[4 * h + 3]);
        d2[4 * h + 0] = fmaf(q4.z, xv.x, d2[4 * h + 0]);
        d2[4 * h + 1] = fmaf(q4.z, xv.y, d2[4 * h + 1]);
        d2[4 * h + 2] = fmaf(q4.z, xv.z, d2[4 * h + 2]);
        d2[4 * h + 3] = fmaf(q4.z, xv.w, d2[4 * h + 3]);
        d3[4 * h + 0] = fmaf(q4.w, xv.x, d3[4 * h + 0]);
        d3[4 * h + 1] = fmaf(q4.w, xv.y, d3[4 * h + 1]);
        d3[4 * h + 2] = fmaf(q4.w, xv.z, d3[4 * h + 2]);
        d3[4 * h + 3] = fmaf(q4.w, xv.w, d3[4 * h + 3]);
      }
    }
    #pragma unroll
    for (int h = 0; h < H; ++h) {
      float4 s4;
      if (SQPRE) {
        s4 = ((const float4*)(sqPre + (long)b * N))[tid + 256 * h];
      } else {
        s4 = make_float4(sq[4 * h], sq[4 * h + 1], sq[4 * h + 2], sq[4 * h + 3]);
      }
      ((float4*)negd[0])[tid + 256 * h] =
          make_float4(2.f * d0[4 * h] - s4.x, 2.f * d0[4 * h + 1] - s4.y,
                      2.f * d0[4 * h + 2] - s4.z, 2.f * d0[4 * h + 3] - s4.w);
      ((float4*)negd[1])[tid + 256 * h] =
          make_float4(2.f * d1[4 * h] - s4.x, 2.f * d1[4 * h + 1] - s4.y,
                      2.f * d1[4 * h + 2] - s4.z, 2.f * d1[4 * h + 3] - s4.w);
      ((float4*)negd[2])[tid + 256 * h] =
          make_float4(2.f * d2[4 * h] - s4.x, 2.f * d2[4 * h + 1] - s4.y,
                      2.f * d2[4 * h + 2] - s4.z, 2.f * d2[4 * h + 3] - s4.w);
      ((float4*)negd[3])[tid + 256 * h] =
          make_float4(2.f * d3[4 * h] - s4.x, 2.f * d3[4 * h + 1] - s4.y,
                      2.f * d3[4 * h + 2] - s4.z, 2.f * d3[4 * h + 3] - s4.w);
    }
  } else {
    float d0[R], d1[R], d2[R], d3[R], sq[R];
    #pragma unroll
    for (int i = 0; i < R; ++i) { d0[i] = d1[i] = d2[i] = d3[i] = sq[i] = 0.f; }
    for (int c = 0; c < C; ++c) {
      float4 q4 = *(const float4*)(qb + (long)c * M);
      const float* pc = cb + (long)c * N;
      #pragma unroll
      for (int i = 0; i < R; ++i) {
        float xv = pc[tid + 256 * i];
        sq[i] = fmaf(xv, xv, sq[i]);
        d0[i] = fmaf(q4.x, xv, d0[i]);
        d1[i] = fmaf(q4.y, xv, d1[i]);
        d2[i] = fmaf(q4.z, xv, d2[i]);
        d3[i] = fmaf(q4.w, xv, d3[i]);
      }
    }
    #pragma unroll
    for (int i = 0; i < R; ++i) {
      int m = tid + 256 * i;
      negd[0][m] = 2.f * d0[i] - sq[i];
      negd[1][m] = 2.f * d1[i] - sq[i];
      negd[2][m] = 2.f * d2[i] - sq[i];
      negd[3][m] = 2.f * d3[i] - sq[i];
    }
  }
  __syncthreads();
  int lane = tid & 63, w = tid >> 6;
  const float* row = negd[w];
  int* outp = idxOut + ((long)b * M + (q0 + w)) * k;
  float v[NR];
  #pragma unroll
  for (int i = 0; i < NR; ++i) v[i] = row[lane + 64 * i];
  constexpr int G = NR / 4;
  for (int kk = 0; kk < k; ++kk) {
    float bv[G]; int br[G];
    #pragma unroll
    for (int g = 0; g < G; ++g) {
      float v0 = v[4 * g]; int r0 = 4 * g;
      #pragma unroll
      for (int j = 1; j < 4; ++j) {
        bool c = v[4 * g + j] > v0;
        v0 = c ? v[4 * g + j] : v0;
        r0 = c ? (4 * g + j) : r0;
      }
      bv[g] = v0; br[g] = r0;
    }
    #pragma unroll
    for (int s = G >> 1; s >= 1; s >>= 1) {
      #pragma unroll
      for (int i = 0; i < s; ++i) {
        bool c = bv[2 * i] >= bv[2 * i + 1];
        bv[i] = c ? bv[2 * i] : bv[2 * i + 1];
        br[i] = c ? br[2 * i] : br[2 * i + 1];
      }
    }
    float best = bv[0]; int ib = br[0];
    int bi = (best > -INFINITY) ? (lane + (ib << 6)) : N;
    float gmax = wave_fmax(best);
    int cand = (best == gmax) ? bi : 0x7FFFFFFF;
    int big = wave_imin(cand);
    if (lane == 0) outp[kk] = big;
    int ri = big >> 6;
    bool mine = (lane == (big & 63));
    #pragma unroll
    for (int i = 0; i < NR; ++i)
      if (i == ri) v[i] = mine ? -INFINITY : v[i];
  }
}

template <int R>
__global__ void knn4_kernel(const float* __restrict__ Q, int qStrideB,
                            const float* __restrict__ Xc, int cStrideB,
                            int C, int M, int N, int k, int* __restrict__ idxOut) {
  __shared__ __align__(16) char smem[R * 256 * 4 * 4];
  knn4_body<R, false>(Q, qStrideB, Xc, cStrideB, C, M, N, k, idxOut, nullptr,
                      blockIdx.y, blockIdx.x * 4, smem);
}

// ---------------- gemmPS body (R16->R17: contiguous sub-tiles, float4 LDS reads).
// Thread owns n=tn*4+i, o=to*4+j -> Xt/Wp/Ws operands are single ds_read_b128 each
// (rows padded to 68 floats for 16B alignment). Per-(n,o) fmaf chain ascending c
// unchanged -> Pt/St bit-identical; layout in memory unchanged; stores now float4.
__device__ __forceinline__ void gemmPS_body(const float* __restrict__ X, int xStrideB, int C, int Np,
                                            const float* __restrict__ W, int ldw, int O,
                                            float* __restrict__ PtT, float* __restrict__ StT,
                                            int b, int n0, int o0, char* smem) {
  float (*Wp)[68] = (float (*)[68])smem;             // 4352 B
  float (*Ws)[68] = (float (*)[68])(smem + 4352);    // 4352 B
  float (*Xt)[68] = (float (*)[68])(smem + 8704);    // 4352 B (13056 total)
  int tid = threadIdx.x;
  int to = tid % 16, tn = tid / 16;
  float accP[4][4] = {}, accS[4][4] = {};
  for (int c0 = 0; c0 < C; c0 += 16) {
    for (int e = tid; e < 16 * 64; e += 256) {
      int oo = e / 16, kk = e % 16;
      int c = c0 + kk, o = o0 + oo;
      bool ok = (c < C && o < O);
      Wp[kk][oo] = ok ? W[(long)o * ldw + c] : 0.f;
      Ws[kk][oo] = ok ? W[(long)o * ldw + C + c] : 0.f;
    }
    for (int e = tid; e < 16 * 64; e += 256) {
      int kk = e / 64, nn = e % 64;
      int c = c0 + kk, n = n0 + nn;
      Xt[kk][nn] = (c < C && n < Np) ? X[(long)b * xStrideB + (long)c * Np + n] : 0.f;
    }
    __syncthreads();
    for (int kk = 0; kk < 16; ++kk) {
      float4 xv = *(const float4*)&Xt[kk][tn * 4];
      float4 wp = *(const float4*)&Wp[kk][to * 4];
      float4 ws = *(const float4*)&Ws[kk][to * 4];
      float xs[4] = {xv.x, xv.y, xv.z, xv.w};
      float wps[4] = {wp.x, wp.y, wp.z, wp.w};
      float wss[4] = {ws.x, ws.y, ws.z, ws.w};
      #pragma unroll
      for (int i = 0; i < 4; ++i)
        #pragma unroll
        for (int j = 0; j < 4; ++j) {
          accP[i][j] = fmaf(xs[i], wps[j], accP[i][j]);
          accS[i][j] = fmaf(xs[i], wss[j], accS[i][j]);
        }
    }
    __syncthreads();
  }
  #pragma unroll
  for (int i = 0; i < 4; ++i) {
    int n = n0 + tn * 4 + i;
    if (n >= Np) continue;
    int o = o0 + to * 4;
    if (o + 3 < O) {
      long off = ((long)b * Np + n) * O + o;
      *(float4*)&PtT[off] = make_float4(accP[i][0], accP[i][1], accP[i][2], accP[i][3]);
      *(float4*)&StT[off] = make_float4(accS[i][0], accS[i][1], accS[i][2], accS[i][3]);
    } else {
      for (int j = 0; j < 4; ++j) {
        int oo = o + j;
        if (oo < O) {
          long off = ((long)b * Np + n) * O + oo;
          PtT[off] = accP[i][j];
          StT[off] = accS[i][j];
        }
      }
    }
  }
}

// ---------------- ecfinish body (O=64 flat-256 variant) ----------------
__device__ __forceinline__ void ecfinish_body64(const float* __restrict__ Pt, const float* __restrict__ St,
                                                const int* __restrict__ idx, int k, int O, int Np,
                                                const float* __restrict__ g, const float* __restrict__ bb,
                                                float* __restrict__ outp, long oStrideB,
                                                float* __restrict__ sqOut,
                                                int b, int blk) {
  int tid = threadIdx.x;
  int o = tid & 63;
  int n = blk * 4 + (tid >> 6);
  const float* PtB = Pt + (long)b * Np * O;
  const float* StB = St + (long)b * Np * O;
  const int* ip = idx + ((long)b * Np + n) * k;
  float mx = -INFINITY, mn = INFINITY;
  for (int kk = 0; kk < k; ++kk) {
    float v = PtB[(long)ip[kk] * O + o];
    mx = fmaxf(mx, v); mn = fminf(mn, v);
  }
  float ctrP = PtB[(long)n * O + o];
  float ctrS = StB[(long)n * O + o];
  float gs = g[o] * BN_SCALE;
  float m = (gs >= 0.f) ? mx : mn;
  float h = (ctrS - ctrP + m) * gs + bb[o];
  float out = h >= 0.f ? h : 0.2f * h;
  outp[(long)b * oStrideB + (long)o * Np + n] = out;
  if (sqOut) {
    int obits = __builtin_bit_cast(int, out);
    float acc = 0.f;
    #pragma unroll
    for (int c = 0; c < 64; ++c) {
      float hv = __builtin_bit_cast(float, __builtin_amdgcn_readlane(obits, c));
      acc = fmaf(hv, hv, acc);
    }
    if (o == 0) sqOut[(long)b * Np + n] = acc;
  }
}

__global__ void ecfinish_kernel(const float* __restrict__ Pt, const float* __restrict__ St,
                                const int* __restrict__ idx, int k, int O, int Np,
                                const float* __restrict__ g, const float* __restrict__ bb,
                                float* __restrict__ outp, long oStrideB) {
  int b = blockIdx.y;
  int n = blockIdx.x * blockDim.y + threadIdx.y;
  int o = threadIdx.x;
  const float* PtB = Pt + (long)b * Np * O;
  const float* StB = St + (long)b * Np * O;
  const int* ip = idx + ((long)b * Np + n) * k;
  float mx = -INFINITY, mn = INFINITY;
  for (int kk = 0; kk < k; ++kk) {
    float v = PtB[(long)ip[kk] * O + o];
    mx = fmaxf(mx, v); mn = fminf(mn, v);
  }
  float ctrP = PtB[(long)n * O + o];
  float ctrS = StB[(long)n * O + o];
  float gs = g[o] * BN_SCALE;
  float m = (gs >= 0.f) ? mx : mn;
  float h = (ctrS - ctrP + m) * gs + bb[o];
  outp[(long)b * oStrideB + (long)o * Np + n] = h >= 0.f ? h : 0.2f * h;
}

// ---------------- gemm_colmax body (R17: contiguous sub-tiles, float4 LDS reads).
// Same remap as gemmPS (n=tn*4+i, o=to*4+j). acc chains unchanged -> bit-identical;
// colmax fmax over all 64 n regrouped (contiguous vs strided) -> exact, bit-identical.
__device__ __forceinline__ void gemm_colmax_body(const float* __restrict__ X, int xStrideB, int C, int Np,
                                                 const float* __restrict__ W, int ldw, int O,
                                                 const float* __restrict__ g, const float* __restrict__ bb,
                                                 float* __restrict__ partial,
                                                 int b, int n0, int o0, int nt, int nNT, char* smem) {
  float (*Wt)[68] = (float (*)[68])smem;            // 4352 B
  float (*Xt)[68] = (float (*)[68])(smem + 4352);   // 4352 B (8704 total)
  int tid = threadIdx.x;
  int to = tid % 16, tn = tid / 16;
  float acc[4][4] = {};
  for (int c0 = 0; c0 < C; c0 += 16) {
    for (int e = tid; e < 16 * 64; e += 256) {
      int oo = e / 16, kk = e % 16;
      int c = c0 + kk, o = o0 + oo;
      Wt[kk][oo] = (c < C && o < O) ? W[(long)o * ldw + c] : 0.f;
    }
    for (int e = tid; e < 16 * 64; e += 256) {
      int kk = e / 64, nn = e % 64;
      int c = c0 + kk, n = n0 + nn;
      Xt[kk][nn] = (c < C && n < Np) ? X[(long)b * xStrideB + (long)c * Np + n] : 0.f;
    }
    __syncthreads();
    for (int kk = 0; kk < 16; ++kk) {
      float4 xv = *(const float4*)&Xt[kk][tn * 4];
      float4 wv = *(const float4*)&Wt[kk][to * 4];
      float xs[4] = {xv.x, xv.y, xv.z, xv.w};
      float wvs[4] = {wv.x, wv.y, wv.z, wv.w};
      #pragma unroll
      for (int i = 0; i < 4; ++i)
        #pragma unroll
        for (int j = 0; j < 4; ++j) acc[i][j] = fmaf(xs[i], wvs[j], acc[i][j]);
    }
    __syncthreads();
  }
  float vm[4];
  #pragma unroll
  for (int j = 0; j < 4; ++j) {
    int o = o0 + to * 4 + j;
    float gs = g[o] * BN_SCALE, bo = bb[o];
    float m = -INFINITY;
    #pragma unroll
    for (int i = 0; i < 4; ++i) {
      float h = acc[i][j] * gs + bo;
      h = h >= 0.f ? h : 0.2f * h;
      m = fmaxf(m, h);
    }
    vm[j] = m;
  }
  #pragma unroll
  for (int j = 0; j < 4; ++j) Xt[tn][to * 4 + j] = vm[j];
  __syncthreads();
  for (int s = 8; s > 0; s >>= 1) {
    if (tn < s)
      for (int j = 0; j < 4; ++j)
        Xt[tn][to * 4 + j] = fmaxf(Xt[tn][to * 4 + j], Xt[tn + s][to * 4 + j]);
    __syncthreads();
  }
  if (tn == 0)
    for (int j = 0; j < 4; ++j) {
      int o = o0 + to * 4 + j;
      partial[((long)b * nNT + nt) * O + o] = Xt[0][to * 4 + j];
    }
}

__global__ void gemm_colmax_kernel(const float* __restrict__ X, int xStrideB, int C, int Np,
                                   const float* __restrict__ W, int ldw, int O,
                                   const float* __restrict__ g, const float* __restrict__ bb,
                                   float* __restrict__ partial) {
  __shared__ __align__(16) char smem[8704];
  gemm_colmax_body(X, xStrideB, C, Np, W, ldw, O, g, bb, partial,
                   blockIdx.z, blockIdx.x * 64, blockIdx.y * 64, blockIdx.x, gridDim.x, smem);
}

// ---------------- xmfill body ----------------
__device__ __forceinline__ void xmfill_body(const float* __restrict__ xt1, int N,
                                            const int* __restrict__ fpsI,
                                            const int* __restrict__ idxA, int k, int M,
                                            float* __restrict__ xm, int xe) {
  long t = (long)xe * 256 + threadIdx.x;
  int i = (int)(t % M);
  int c = (int)((t / M) % 128);
  int b = (int)(t / ((long)128 * M));
  const float* xb = xt1 + (long)b * 128 * N + (long)c * N;
  float* xmB = xm + (long)b * 256 * M;
  xmB[(long)c * M + i] = xb[fpsI[(long)b * M + i]];
  const int* ip = idxA + ((long)b * M + i) * k;
  float best = -INFINITY;
  for (int kk = 0; kk < k; ++kk) best = fmaxf(best, xb[ip[kk]]);
  xmB[(long)(128 + c) * M + i] = best;
}

// ---------------- FPS body, RANGE-split (unchanged) ----------------
template <int FIRST, int LAST>
__device__ __forceinline__ void fps_body_rg(const float* __restrict__ xyz, int N, int M,
                                            int it0, int it1,
                                            int* __restrict__ fpsIdx, float* __restrict__ node1,
                                            float* __restrict__ distSv, int* __restrict__ lastSv,
                                            int b, char* smem) {
  #pragma clang fp contract(off)
  float4* sp4 = (float4*)smem;                 // 2048 pts: slot (n&7)*256 + (n>>3)
  int*    fidx = (int*)(smem + 32768);
  float4* wvc  = (float4*)(smem + 32768 + 2048);
  int*    wis  = (int*)(smem + 32768 + 2048 + 128);
  int tid = threadIdx.x;
  int lane = tid & 63, w = tid >> 6;
  const float* xb = xyz + (long)b * 3 * N;
  for (int n = tid; n < N; n += 256) {
    sp4[((n & 7) << 8) | (n >> 3)] = make_float4(xb[n], xb[N + n], xb[2 * N + n], 0.f);
  }
  if (!FIRST) {
    for (int e = tid; e < it0; e += 256) fidx[e] = fpsIdx[(long)b * M + e];
  }
  __syncthreads();
  float4 pt[8];
  #pragma unroll
  for (int i = 0; i < 8; ++i) pt[i] = sp4[(i << 8) | tid];
  float dist[8];
  int last;
  float lx, ly, lz;
  if (FIRST) {
    #pragma unroll
    for (int i = 0; i < 8; ++i) dist[i] = 1e10f;
    last = 0;
    float4 l0 = sp4[0];
    lx = l0.x; ly = l0.y; lz = l0.z;
  } else {
    #pragma unroll
    for (int i = 0; i < 8; ++i) dist[i] = distSv[(long)b * 2048 + i * 256 + tid];
    last = lastSv[b];
    float4 lp = sp4[((last & 7) << 8) | (last >> 3)];
    lx = lp.x; ly = lp.y; lz = lp.z;
  }
  int base = tid * 8;
  for (int it = it0; it < it1; ++it) {
    int p = it & 1;
    if (tid == 0) fidx[it] = last;
    float best = -INFINITY; int bi = N;
    #pragma unroll
    for (int i = 0; i < 8; ++i) {
      float dx = pt[i].x - lx, dy = pt[i].y - ly, dz = pt[i].z - lz;
      float dx2 = dx * dx, dy2 = dy * dy, dz2 = dz * dz;
      float d = (dx2 + dy2) + dz2;
      float dn = dist[i];
      if (d < dn) dn = d;
      dist[i] = dn;
      if (dn > best) { best = dn; bi = base + i; }
    }
    float cx = pt[0].x, cy = pt[0].y, cz = pt[0].z;
    #pragma unroll
    for (int i = 1; i < 8; ++i) {
      bool c = (bi == base + i);
      cx = c ? pt[i].x : cx; cy = c ? pt[i].y : cy; cz = c ? pt[i].z : cz;
    }
    float gmax = wave_fmax(best);
    int cand = (best == gmax) ? bi : 0x7FFFFFFF;
    int wbi = wave_imin(cand);
    if (bi == wbi) { wvc[p * 4 + w] = make_float4(gmax, cx, cy, cz); wis[p * 4 + w] = wbi; }
    __syncthreads();
    float4 c0 = wvc[p * 4 + 0], c1 = wvc[p * 4 + 1], c2 = wvc[p * 4 + 2], c3 = wvc[p * 4 + 3];
    int i0 = wis[p * 4 + 0], i1 = wis[p * 4 + 1], i2 = wis[p * 4 + 2], i3 = wis[p * 4 + 3];
    float bv = c0.x; int bbi = i0; lx = c0.y; ly = c0.z; lz = c0.w;
    { bool c = (c1.x > bv) || (c1.x == bv && i1 < bbi);
      bv = c ? c1.x : bv; bbi = c ? i1 : bbi; lx = c ? c1.y : lx; ly = c ? c1.z : ly; lz = c ? c1.w : lz; }
    { bool c = (c2.x > bv) || (c2.x == bv && i2 < bbi);
      bv = c ? c2.x : bv; bbi = c ? i2 : bbi; lx = c ? c2.y : lx; ly = c ? c2.z : ly; lz = c ? c2.w : lz; }
    { bool c = (c3.x > bv) || (c3.x == bv && i3 < bbi);
      bv = c ? c3.x : bv; bbi = c ? i3 : bbi; lx = c ? c3.y : lx; ly = c ? c3.z : ly; lz = c ? c3.w : lz; }
    last = bbi;
    // parity: slot p rewritten only in iter it+2, after barrier it+1 -> safe with 1 barrier
  }
  if (!LAST) {
    for (int e = tid; e < it1; e += 256) {
      if (e >= it0) fpsIdx[(long)b * M + e] = fidx[e];
    }
    #pragma unroll
    for (int i = 0; i < 8; ++i) distSv[(long)b * 2048 + i * 256 + tid] = dist[i];
    if (tid == 0) lastSv[b] = last;
  } else {
    for (int e = tid; e < M; e += 256) fpsIdx[(long)b * M + e] = fidx[e];
    for (int e = tid; e < 3 * M; e += 256) {
      int c = e / M, i = e % M;
      int src = fidx[i];
      float4 ptc = sp4[((src & 7) << 8) | (src >> 3)];
      node1[(long)b * 3 * M + e] = (c == 0) ? ptc.x : (c == 1) ? ptc.y : ptc.z;
    }
  }
}

// ---------------- fused {fps-range + knn + gemmPS}, 1D grid, fps first ----------------
template <int FIRST, int LAST, bool SQP>
__global__ void knnfpsgemm_kernel(const float* __restrict__ Q, int qStrideB,
                                  const float* __restrict__ Xc, int cStrideB,
                                  int C, int Mq, int N, int k, int* __restrict__ idxOut,
                                  const float* __restrict__ W, int ldw, int O,
                                  float* __restrict__ Pt, float* __restrict__ St,
                                  const float* __restrict__ xyz, int Mf, int it0, int it1,
                                  int* __restrict__ fpsIdx, float* __restrict__ node1,
                                  float* __restrict__ distSv, int* __restrict__ lastSv,
                                  const float* __restrict__ sqPre,
                                  int nQblk, int nGblk, int nB) {
  __shared__ __align__(16) char smem[32768 + 2048 + 128 + 32];
  int bid = blockIdx.x;
  if (bid < nB) {
    __builtin_amdgcn_s_setprio(1);
    fps_body_rg<FIRST, LAST>(xyz, N, Mf, it0, it1, fpsIdx, node1, distSv, lastSv, bid, smem);
    __builtin_amdgcn_s_setprio(0);
  } else if (bid < nB + nB * nQblk) {
    int e = bid - nB;
    knn4_body<8, SQP>(Q, qStrideB, Xc, cStrideB, C, Mq, N, k, idxOut, sqPre,
                      e / nQblk, (e % nQblk) * 4, smem);
  } else {
    int e = bid - nB - nB * nQblk;
    gemmPS_body(Xc, cStrideB, C, N, W, ldw, O, Pt, St,
                e / nGblk, (e % nGblk) * 64, 0, smem);
  }
}

// ---------------- fused {ecfinish1 (+sq emit) + fps mid-range}, fps blocks first --------
__global__ void ecfps_kernel(const float* __restrict__ Pt, const float* __restrict__ St,
                             const int* __restrict__ idx, int k, int O, int Np,
                             const float* __restrict__ g, const float* __restrict__ bb,
                             float* __restrict__ outp, long oStrideB,
                             float* __restrict__ sqOut,
                             const float* __restrict__ xyz, int N, int Mf, int it0, int it1,
                             int* __restrict__ fpsIdx, float* __restrict__ node1,
                             float* __restrict__ distSv, int* __restrict__ lastSv,
                             int nEperB, int nB) {
  __shared__ __align__(16) char smem[32768 + 2048 + 128 + 32];
  int bid = blockIdx.x;
  if (bid < nB) {
    __builtin_amdgcn_s_setprio(1);
    fps_body_rg<0, 0>(xyz, N, Mf, it0, it1, fpsIdx, node1, distSv, lastSv, bid, smem);
    __builtin_amdgcn_s_setprio(0);
  } else {
    int e = bid - nB;
    ecfinish_body64(Pt, St, idx, k, O, Np, g, bb, outp, oStrideB, sqOut,
                    e / nEperB, e % nEperB);
  }
}

// ---------------- fused {ecfinish2 + agg-knn}, striped (agg every 5th bid) ----------------
__global__ void ecfagg_kernel(const float* __restrict__ Pt, const float* __restrict__ St,
                              const int* __restrict__ idxS2, int k2, int O2, int Np2,
                              const float* __restrict__ g2, const float* __restrict__ b2,
                              float* __restrict__ out2, long oStrideB2,
                              const float* __restrict__ Qn, int qStrideB,
                              const float* __restrict__ Xc, int cStrideB,
                              int Cq, int Mq, int Nc, int kq, int* __restrict__ idxAgg,
                              int nQblk, int nEperB) {
  __shared__ __align__(16) char smem[32768];
  int bid = blockIdx.x;
  if (bid % 5 == 0) {
    int a = bid / 5;                       // [0, 1024)
    knn4_body<8, false>(Qn, qStrideB, Xc, cStrideB, Cq, Mq, Nc, kq, idxAgg, nullptr,
                        a / nQblk, (a % nQblk) * 4, smem);
  } else {
    int e = bid - bid / 5 - 1;             // [0, 4096) sequential
    ecfinish_body64(Pt, St, idxS2, k2, O2, Np2, g2, b2, out2, oStrideB2, nullptr,
                    e / nEperB, e % nEperB);
  }
}

// ---------------- fused {gemm_colmaxA + xmfill}, striped (xmfill every 3rd bid) ----------------
__global__ void colmaxxm_kernel(const float* __restrict__ X, int xStrideB, int C, int Np,
                                const float* __restrict__ W, int ldw, int O,
                                const float* __restrict__ g, const float* __restrict__ bb,
                                float* __restrict__ partial, int nNT, int nOT,
                                const float* __restrict__ xt1, int N,
                                const int* __restrict__ fpsI, const int* __restrict__ idxA,
                                int kq, int M, float* __restrict__ xm) {
  __shared__ __align__(16) char smem[8704];
  int bid = blockIdx.x;
  if (bid % 3 == 0) {
    xmfill_body(xt1, N, fpsI, idxA, kq, M, xm, bid / 3);       // [0, 2048)
  } else {
    int e = bid - bid / 3 - 1;                                  // [0, 4096)
    int per = nNT * nOT;
    int b = e / per, r = e % per;
    int nt = r % nNT, ot = r / nNT;
    gemm_colmax_body(X, xStrideB, C, Np, W, ldw, O, g, bb, partial,
                     b, nt * 64, ot * 64, nt, nNT, smem);
  }
}

// ---------------- fused {knn<2> + gemmPS} for stages 3/4 ----------------
__global__ void knngemm_kernel(const float* __restrict__ Xin, int xStrideB,
                               int C, int Mq, int N, int k, int* __restrict__ idxOut,
                               const float* __restrict__ W, int ldw, int O,
                               float* __restrict__ Pt, float* __restrict__ St,
                               int nQblk, int nGn, int nGo, int nB) {
  __shared__ __align__(16) char smem[13056];
  int bid = blockIdx.x;
  if (bid < nB * nQblk) {
    knn4_body<2, false>(Xin, xStrideB, Xin, xStrideB, C, Mq, N, k, idxOut, nullptr,
                        bid / nQblk, (bid % nQblk) * 4, smem);
  } else {
    int e = bid - nB * nQblk;
    int per = nGn * nGo;
    int b = e / per, r = e % per;
    int nt = r % nGn, ot = r / nGn;
    gemmPS_body(Xin, xStrideB, C, N, W, ldw, O, Pt, St, b, nt * 64, ot * 64, smem);
  }
}

// ---------------- head: fused colmax_finish + 3-layer MLP (wave-cooperative) ----------------
__global__ void head_kernel(const float* __restrict__ partA, int NTa,
                            const float* __restrict__ partB, int NTb,
                            const float* __restrict__ Wl1, const float* __restrict__ g6, const float* __restrict__ b6,
                            const float* __restrict__ Wl2, const float* __restrict__ bl2,
                            const float* __restrict__ g7, const float* __restrict__ b7,
                            const float* __restrict__ Wl3, const float* __restrict__ bl3,
                            float* __restrict__ logits) {
  __shared__ float v[2048];
  __shared__ float h1[512];
  __shared__ float h2[256];
  int b = blockIdx.x, tid = threadIdx.x;
  int lane = tid & 63, w = tid >> 6;
  for (int o = tid; o < 1024; o += 256) {
    float m = -INFINITY;
    for (int t = 0; t < NTa; ++t) m = fmaxf(m, partA[((long)b * NTa + t) * 1024 + o]);
    v[o] = m;
    float m2 = -INFINITY;
    for (int t = 0; t < NTb; ++t) m2 = fmaxf(m2, partB[((long)b * NTb + t) * 1024 + o]);
    v[1024 + o] = m2;
  }
  __syncthreads();
  for (int o = w; o < 512; o += 4) {
    const float4* wr = (const float4*)(Wl1 + (long)o * 2048);
    const float4* vp = (const float4*)v;
    float s = 0.f;
    #pragma unroll
    for (int j = 0; j < 8; ++j) {
      float4 w4 = wr[lane + 64 * j];
      float4 v4 = vp[lane + 64 * j];
      s = fmaf(w4.x, v4.x, s); s = fmaf(w4.y, v4.y, s);
      s = fmaf(w4.z, v4.z, s); s = fmaf(w4.w, v4.w, s);
    }
    float t = wave_fadd(s);
    if (lane == 0) {
      float h = t * (g6[o] * BN_SCALE) + b6[o];
      h1[o] = h >= 0.f ? h : 0.2f * h;
    }
  }
  __syncthreads();
  for (int o = w; o < 256; o += 4) {
    const float4* wr = (const float4*)(Wl2 + (long)o * 512);
    const float4* hp = (const float4*)h1;
    float s = 0.f;
    #pragma unroll
    for (int j = 0; j < 2; ++j) {
      float4 w4 = wr[lane + 64 * j];
      float4 v4 = hp[lane + 64 * j];
      s = fmaf(w4.x, v4.x, s); s = fmaf(w4.y, v4.y, s);
      s = fmaf(w4.z, v4.z, s); s = fmaf(w4.w, v4.w, s);
    }
    float t = wave_fadd(s);
    if (lane == 0) {
      float sb = t + bl2[o];
      float h = sb * (g7[o] * BN_SCALE) + b7[o];
      h2[o] = h >= 0.f ? h : 0.2f * h;
    }
  }
  __syncthreads();
  for (int o = w; o < 40; o += 4) {
    const float4* wr = (const float4*)(Wl3 + (long)o * 256);
    const float4* hp = (const float4*)h2;
    float4 w4 = wr[lane];
    float4 v4 = hp[lane];
    float s = fmaf(w4.x, v4.x, 0.f);
    s = fmaf(w4.y, v4.y, s); s = fmaf(w4.z, v4.z, s); s = fmaf(w4.w, v4.w, s);
    float t = wave_fadd(s);
    if (lane == 0) logits[(long)b * 40 + o] = t + bl3[o];
  }
}

extern "C" void kernel_launch(void* const* d_in, const int* in_sizes, int n_in,
                              void* d_out, int out_size, void* d_ws, size_t ws_size,
                              hipStream_t stream) {
  const float* x   = (const float*)d_in[0];
  const float* W1  = (const float*)d_in[1];
  const float* g1  = (const float*)d_in[2];
  const float* b1  = (const float*)d_in[3];
  const float* W2  = (const float*)d_in[4];
  const float* g2  = (const float*)d_in[5];
  const float* b2  = (const float*)d_in[6];
  const float* W2m = (const float*)d_in[7];
  const float* g2m = (const float*)d_in[8];
  const float* b2m = (const float*)d_in[9];
  const float* W3  = (const float*)d_in[10];
  const float* g3  = (const float*)d_in[11];
  const float* b3  = (const float*)d_in[12];
  const float* W4  = (const float*)d_in[13];
  const float* g4  = (const float*)d_in[14];
  const float* b4  = (const float*)d_in[15];
  const float* W5  = (const float*)d_in[16];
  const float* g5  = (const float*)d_in[17];
  const float* b5  = (const float*)d_in[18];
  const float* Wl1 = (const float*)d_in[19];
  const float* g6  = (const float*)d_in[20];
  const float* b6  = (const float*)d_in[21];
  const float* Wl2 = (const float*)d_in[22];
  const float* bl2 = (const float*)d_in[23];
  const float* g7  = (const float*)d_in[24];
  const float* b7  = (const float*)d_in[25];
  const float* Wl3 = (const float*)d_in[26];
  const float* bl3 = (const float*)d_in[27];
  float* outF = (float*)d_out;

  const int B = 8, N = 2048, K = 20, M = 512, K2 = 10;

  float* ws    = (float*)d_ws;
  float* xt1   = ws;                               // (B,128,N)
  float* xm    = xt1 + (size_t)B * 128 * N;        // (B,256,M)
  float* xc    = xm  + (size_t)B * 256 * M;        // (B,512,M)
  float* Pt    = xc  + (size_t)B * 512 * M;        // max(B*N*64, B*M*256)
  float* St    = Pt  + (size_t)B * N * 64;
  float* partA = St  + (size_t)B * N * 64;         // (B,32,1024)
  float* partB = partA + (size_t)B * 32 * 1024;    // (B,8,1024)
  int*   idxK  = (int*)(partB + (size_t)B * 8 * 1024);  // (B,N,K)
  int*   fpsI  = idxK + (size_t)B * N * K;         // (B,M)
  float* fpsDist = (float*)(fpsI + (size_t)B * M); // (B,2048) fps checkpoint dists
  int*   fpsLast = (int*)(fpsDist + (size_t)B * 2048);  // (B)
  int*   idxAgg  = fpsLast + 64;                   // (B,M,K) aggregate-knn indices
  float* sqS2    = (float*)(idxAgg + (size_t)B * M * K); // (B,N) stage-2 candidate norms

  float* logits = outF;        // (B,40)
  float* node1  = outF + 320;  // (B,3,M)

  dim3 t256(256);
  const int nQblk = N / 4;     // 512 knn query-blocks per batch (N-point knn)
  const int nGblk = N / 64;    // 32 gemmPS n-tiles per batch (stage 1/2)
  const int nFused = B + B * nQblk + B * nGblk;
  const int nQa = M / 4;       // 128 agg/stage3/4 knn query-blocks per batch
  const int IT1 = 208, IT2 = 304;   // fps phase boundaries

  // ---- stage 1 FUSED: fps [0,208) + knn(xyz) + gemmPS1 (all depend only on x)
  knnfpsgemm_kernel<1, 0, false><<<dim3(nFused), t256, 0, stream>>>(
      x, 3 * N, x, 3 * N, 3, N, N, K, idxK,
      W1, 6, 64, Pt, St,
      x, M, 0, IT1, fpsI, node1, fpsDist, fpsLast, nullptr, nQblk, nGblk, B);

  // ---- ecfinish1 (+sq emit for stage-2 knn) FUSED with fps [208,304)
  ecfps_kernel<<<dim3(B + B * (N / 4)), t256, 0, stream>>>(
      Pt, St, idxK, K, 64, N, g1, b1, xt1, (long)128 * N, sqS2,
      x, N, M, IT1, IT2, fpsI, node1, fpsDist, fpsLast, N / 4, B);

  // ---- stage 2 FUSED: fps [304,512) + knn(x1, precomputed sq) + gemmPS2
  knnfpsgemm_kernel<0, 1, true><<<dim3(nFused), t256, 0, stream>>>(
      xt1, 128 * N, xt1, 128 * N, 64, N, N, K, idxK,
      W2, 128, 64, Pt, St,
      x, M, IT2, M, fpsI, node1, fpsDist, fpsLast, sqS2, nQblk, nGblk, B);

  // ---- FUSED: ecfinish2 (gather-bound) + aggregate-knn (VALU-latency-bound), striped
  ecfagg_kernel<<<dim3(B * nQa + B * (N / 4)), t256, 0, stream>>>(
      Pt, St, idxK, K, 64, N, g2, b2, xt1 + (size_t)64 * N, (long)128 * N,
      node1, 3 * M, x, 3 * N, 3, M, N, K, idxAgg, nQa, N / 4);

  // ---- FUSED: gemm_colmaxA + xmfill, striped every-3rd
  colmaxxm_kernel<<<dim3((B * 128 * M) / 256 + B * 32 * 16), t256, 0, stream>>>(
      xt1, 128 * N, 128, N, W2m, 128, 1024, g2m, b2m, partA, 32, 16,
      xt1, N, fpsI, idxAgg, K, M, xm);

  // ---- stage 3 FUSED: knn(xm) + gemmPS3
  knngemm_kernel<<<dim3(B * nQa + B * (M / 64) * (256 / 64)), t256, 0, stream>>>(
      xm, 256 * M, 256, M, M, K2, idxK, W3, 512, 256, Pt, St, nQa, M / 64, 256 / 64, B);
  ecfinish_kernel<<<dim3(M, B), dim3(256, 1), 0, stream>>>(Pt, St, idxK, K2, 256, M, g3, b3, xc, (long)512 * M);

  // ---- stage 4 FUSED: knn(x3) + gemmPS4
  knngemm_kernel<<<dim3(B * nQa + B * (M / 64) * (256 / 64)), t256, 0, stream>>>(
      xc, 512 * M, 256, M, M, K2, idxK, W4, 512, 256, Pt, St, nQa, M / 64, 256 / 64, B);
  ecfinish_kernel<<<dim3(M, B), dim3(256, 1), 0, stream>>>(Pt, St, idxK, K2, 256, M, g4, b4,
                                                           xc + (size_t)256 * M, (long)512 * M);

  // ---- vs partials
  gemm_colmax_kernel<<<dim3(M / 64, 1024 / 64, B), t256, 0, stream>>>(xc, 512 * M, 512, M, W5, 512, 1024,
                                                                      g5, b5, partB);

  // ---- head (fused colmax_finish + MLP; NTa=32, NTb=8)
  head_kernel<<<dim3(B), t256, 0, stream>>>(partA, N / 64, partB, M / 64,
                                            Wl1, g6, b6, Wl2, bl2, g7, b7, Wl3, bl3, logits);
}

// Round 18
// 1057.131 us; speedup vs baseline: 1.2203x; 1.0066x over previous
//
#include <hip/hip_runtime.h>

#define BN_SCALE 0.9999950000374997f  // 1/sqrt(1+1e-5)

// ---- DPP full-wave reductions (validated in fps/knn since R2/R4) ----
template <int CTRL>
__device__ __forceinline__ float dpp_fmax_step(float v) {
  int xi = __builtin_bit_cast(int, v);
  int ti = __builtin_amdgcn_update_dpp(xi, xi, CTRL, 0xf, 0xf, false);  // invalid lanes -> old(=v)
  return fmaxf(v, __builtin_bit_cast(float, ti));
}
template <int CTRL>
__device__ __forceinline__ int dpp_imin_step(int v) {
  int t = __builtin_amdgcn_update_dpp(v, v, CTRL, 0xf, 0xf, false);    // invalid lanes -> old(=v)
  return (t < v) ? t : v;
}
template <int CTRL>
__device__ __forceinline__ float dpp_fadd_step(float v) {
  // bound_ctrl=true: invalid lanes contribute 0 (required for sums)
  int ti = __builtin_amdgcn_update_dpp(0, __builtin_bit_cast(int, v), CTRL, 0xf, 0xf, true);
  return v + __builtin_bit_cast(float, ti);
}
__device__ __forceinline__ float wave_fmax(float v) {
  v = dpp_fmax_step<0x111>(v);
  v = dpp_fmax_step<0x112>(v);
  v = dpp_fmax_step<0x114>(v);
  v = dpp_fmax_step<0x118>(v);
  v = dpp_fmax_step<0x142>(v);
  v = dpp_fmax_step<0x143>(v);
  return __builtin_bit_cast(float, __builtin_amdgcn_readlane(__builtin_bit_cast(int, v), 63));
}
__device__ __forceinline__ int wave_imin(int v) {
  v = dpp_imin_step<0x111>(v);
  v = dpp_imin_step<0x112>(v);
  v = dpp_imin_step<0x114>(v);
  v = dpp_imin_step<0x118>(v);
  v = dpp_imin_step<0x142>(v);
  v = dpp_imin_step<0x143>(v);
  return __builtin_amdgcn_readlane(v, 63);
}
__device__ __forceinline__ float wave_fadd(float v) {
  v = dpp_fadd_step<0x111>(v);
  v = dpp_fadd_step<0x112>(v);
  v = dpp_fadd_step<0x114>(v);
  v = dpp_fadd_step<0x118>(v);
  v = dpp_fadd_step<0x142>(v);
  v = dpp_fadd_step<0x143>(v);
  return __builtin_bit_cast(float, __builtin_amdgcn_readlane(__builtin_bit_cast(int, v), 63));
}

// ---------------- knn4 body ----------------
// R17->R18 selection: persistent per-lane group bests bv[G]/br[G]. Per round: copy +
// tournament tree (no full rescan) + refold ONLY the group holding the removed value
// (gi = ri>>2 is wave-uniform -> scalar branch). Untouched groups fold over identical
// values; refold uses the identical ascending strict-> fold -> indices bit-identical.
template <int R, bool SQPRE>
__device__ __forceinline__ void knn4_body(const float* __restrict__ Q, int qStrideB,
                                          const float* __restrict__ Xc, int cStrideB,
                                          int C, int M, int N, int k, int* __restrict__ idxOut,
                                          const float* __restrict__ sqPre,
                                          int b, int q0, char* smem) {
  constexpr int NR = 4 * R;
  float (*negd)[R * 256] = (float (*)[R * 256])smem;
  int tid = threadIdx.x;
  const float* qb = Q + (long)b * qStrideB + q0;
  const float* cb = Xc + (long)b * cStrideB;
  if constexpr (R % 4 == 0) {
    constexpr int H = R / 4;
    float d0[R], d1[R], d2[R], d3[R], sq[R];
    #pragma unroll
    for (int i = 0; i < R; ++i) { d0[i] = d1[i] = d2[i] = d3[i] = sq[i] = 0.f; }
    for (int c = 0; c < C; ++c) {
      float4 q4 = *(const float4*)(qb + (long)c * M);  // uniform -> scalar load
      const float4* pc4 = (const float4*)(cb + (long)c * N);
      #pragma unroll
      for (int h = 0; h < H; ++h) {
        float4 xv = pc4[tid + 256 * h];                // 16B/lane coalesced
        if (!SQPRE) {
          sq[4 * h + 0] = fmaf(xv.x, xv.x, sq[4 * h + 0]);
          sq[4 * h + 1] = fmaf(xv.y, xv.y, sq[4 * h + 1]);
          sq[4 * h + 2] = fmaf(xv.z, xv.z, sq[4 * h + 2]);
          sq[4 * h + 3] = fmaf(xv.w, xv.w, sq[4 * h + 3]);
        }
        d0[4 * h + 0] = fmaf(q4.x, xv.x, d0[4 * h + 0]);
        d0[4 * h + 1] = fmaf(q4.x, xv.y, d0[4 * h + 1]);
        d0[4 * h + 2] = fmaf(q4.x, xv.z, d0[4 * h + 2]);
        d0[4 * h + 3] = fmaf(q4.x, xv.w, d0[4 * h + 3]);
        d1[4 * h + 0] = fmaf(q4.y, xv.x, d1[4 * h + 0]);
        d1[4 * h + 1] = fmaf(q4.y, xv.y, d1[4 * h + 1]);
        d1[4 * h + 2] = fmaf(q4.y, xv.z, d1[4 * h + 2]);
        d1[4 * h + 3] = fmaf(q4.y, xv.w, d1[4 * h + 3]);
        d2[4 * h + 0] = fmaf(q4.z, xv.x, d2[4 * h + 0]);
        d2[4 * h + 1] = fmaf(q4.z, xv.y, d2[4 * h + 1]);
        d2[4 * h + 2] = fmaf(q4.z, xv.z, d2[4 * h + 2]);
        d2[4 * h + 3] = fmaf(q4.z, xv.w, d2[4 * h + 3]);
        d3[4 * h + 0] = fmaf(q4.w, xv.x, d3[4 * h + 0]);
        d3[4 * h + 1] = fmaf(q4.w, xv.y, d3[4 * h + 1]);
        d3[4 * h + 2] = fmaf(q4.w, xv.z, d3[4 * h + 2]);
        d3[4 * h + 3] = fmaf(q4.w, xv.w, d3[4 * h + 3]);
      }
    }
    #pragma unroll
    for (int h = 0; h < H; ++h) {
      float4 s4;
      if (SQPRE) {
        s4 = ((const float4*)(sqPre + (long)b * N))[tid + 256 * h];
      } else {
        s4 = make_float4(sq[4 * h], sq[4 * h + 1], sq[4 * h + 2], sq[4 * h + 3]);
      }
      ((float4*)negd[0])[tid + 256 * h] =
          make_float4(2.f * d0[4 * h] - s4.x, 2.f * d0[4 * h + 1] - s4.y,
                      2.f * d0[4 * h + 2] - s4.z, 2.f * d0[4 * h + 3] - s4.w);
      ((float4*)negd[1])[tid + 256 * h] =
          make_float4(2.f * d1[4 * h] - s4.x, 2.f * d1[4 * h + 1] - s4.y,
                      2.f * d1[4 * h + 2] - s4.z, 2.f * d1[4 * h + 3] - s4.w);
      ((float4*)negd[2])[tid + 256 * h] =
          make_float4(2.f * d2[4 * h] - s4.x, 2.f * d2[4 * h + 1] - s4.y,
                      2.f * d2[4 * h + 2] - s4.z, 2.f * d2[4 * h + 3] - s4.w);
      ((float4*)negd[3])[tid + 256 * h] =
          make_float4(2.f * d3[4 * h] - s4.x, 2.f * d3[4 * h + 1] - s4.y,
                      2.f * d3[4 * h + 2] - s4.z, 2.f * d3[4 * h + 3] - s4.w);
    }
  } else {
    float d0[R], d1[R], d2[R], d3[R], sq[R];
    #pragma unroll
    for (int i = 0; i < R; ++i) { d0[i] = d1[i] = d2[i] = d3[i] = sq[i] = 0.f; }
    for (int c = 0; c < C; ++c) {
      float4 q4 = *(const float4*)(qb + (long)c * M);
      const float* pc = cb + (long)c * N;
      #pragma unroll
      for (int i = 0; i < R; ++i) {
        float xv = pc[tid + 256 * i];
        sq[i] = fmaf(xv, xv, sq[i]);
        d0[i] = fmaf(q4.x, xv, d0[i]);
        d1[i] = fmaf(q4.y, xv, d1[i]);
        d2[i] = fmaf(q4.z, xv, d2[i]);
        d3[i] = fmaf(q4.w, xv, d3[i]);
      }
    }
    #pragma unroll
    for (int i = 0; i < R; ++i) {
      int m = tid + 256 * i;
      negd[0][m] = 2.f * d0[i] - sq[i];
      negd[1][m] = 2.f * d1[i] - sq[i];
      negd[2][m] = 2.f * d2[i] - sq[i];
      negd[3][m] = 2.f * d3[i] - sq[i];
    }
  }
  __syncthreads();
  int lane = tid & 63, w = tid >> 6;
  const float* row = negd[w];
  int* outp = idxOut + ((long)b * M + (q0 + w)) * k;
  float v[NR];
  #pragma unroll
  for (int i = 0; i < NR; ++i) v[i] = row[lane + 64 * i];
  constexpr int G = NR / 4;
  // initial full group fold (identical to the old per-round fold)
  float bv[G]; int br[G];
  #pragma unroll
  for (int g = 0; g < G; ++g) {
    float v0 = v[4 * g]; int r0 = 4 * g;
    #pragma unroll
    for (int j = 1; j < 4; ++j) {
      bool c = v[4 * g + j] > v0;
      v0 = c ? v[4 * g + j] : v0;
      r0 = c ? (4 * g + j) : r0;
    }
    bv[g] = v0; br[g] = r0;
  }
  for (int kk = 0; kk < k; ++kk) {
    // tournament tree over persistent group bests (non-destructive copy)
    float mv[G]; int mi[G];
    #pragma unroll
    for (int g = 0; g < G; ++g) { mv[g] = bv[g]; mi[g] = br[g]; }
    #pragma unroll
    for (int s = G >> 1; s >= 1; s >>= 1) {
      #pragma unroll
      for (int i = 0; i < s; ++i) {
        bool c = mv[2 * i] >= mv[2 * i + 1];
        mv[i] = c ? mv[2 * i] : mv[2 * i + 1];
        mi[i] = c ? mi[2 * i] : mi[2 * i + 1];
      }
    }
    float best = mv[0]; int ib = mi[0];
    int bi = (best > -INFINITY) ? (lane + (ib << 6)) : N;
    float gmax = wave_fmax(best);
    int cand = (best == gmax) ? bi : 0x7FFFFFFF;
    int big = wave_imin(cand);
    if (lane == 0) outp[kk] = big;
    int ri = big >> 6;                      // uniform
    bool mine = (lane == (big & 63));
    #pragma unroll
    for (int i = 0; i < NR; ++i)
      if (i == ri) v[i] = mine ? -INFINITY : v[i];
    // refold only the affected group (gi uniform -> scalar branch; exact same fold)
    int gi = ri >> 2;
    #pragma unroll
    for (int g = 0; g < G; ++g) {
      if (g == gi) {
        float v0 = v[4 * g]; int r0 = 4 * g;
        #pragma unroll
        for (int j = 1; j < 4; ++j) {
          bool c = v[4 * g + j] > v0;
          v0 = c ? v[4 * g + j] : v0;
          r0 = c ? (4 * g + j) : r0;
        }
        bv[g] = v0; br[g] = r0;
      }
    }
  }
}

template <int R>
__global__ void knn4_kernel(const float* __restrict__ Q, int qStrideB,
                            const float* __restrict__ Xc, int cStrideB,
                            int C, int M, int N, int k, int* __restrict__ idxOut) {
  __shared__ __align__(16) char smem[R * 256 * 4 * 4];
  knn4_body<R, false>(Q, qStrideB, Xc, cStrideB, C, M, N, k, idxOut, nullptr,
                      blockIdx.y, blockIdx.x * 4, smem);
}

// ---------------- gemmPS body (R17: contiguous sub-tiles, float4 LDS reads) ----------------
__device__ __forceinline__ void gemmPS_body(const float* __restrict__ X, int xStrideB, int C, int Np,
                                            const float* __restrict__ W, int ldw, int O,
                                            float* __restrict__ PtT, float* __restrict__ StT,
                                            int b, int n0, int o0, char* smem) {
  float (*Wp)[68] = (float (*)[68])smem;             // 4352 B
  float (*Ws)[68] = (float (*)[68])(smem + 4352);    // 4352 B
  float (*Xt)[68] = (float (*)[68])(smem + 8704);    // 4352 B (13056 total)
  int tid = threadIdx.x;
  int to = tid % 16, tn = tid / 16;
  float accP[4][4] = {}, accS[4][4] = {};
  for (int c0 = 0; c0 < C; c0 += 16) {
    for (int e = tid; e < 16 * 64; e += 256) {
      int oo = e / 16, kk = e % 16;
      int c = c0 + kk, o = o0 + oo;
      bool ok = (c < C && o < O);
      Wp[kk][oo] = ok ? W[(long)o * ldw + c] : 0.f;
      Ws[kk][oo] = ok ? W[(long)o * ldw + C + c] : 0.f;
    }
    for (int e = tid; e < 16 * 64; e += 256) {
      int kk = e / 64, nn = e % 64;
      int c = c0 + kk, n = n0 + nn;
      Xt[kk][nn] = (c < C && n < Np) ? X[(long)b * xStrideB + (long)c * Np + n] : 0.f;
    }
    __syncthreads();
    for (int kk = 0; kk < 16; ++kk) {
      float4 xv = *(const float4*)&Xt[kk][tn * 4];
      float4 wp = *(const float4*)&Wp[kk][to * 4];
      float4 ws = *(const float4*)&Ws[kk][to * 4];
      float xs[4] = {xv.x, xv.y, xv.z, xv.w};
      float wps[4] = {wp.x, wp.y, wp.z, wp.w};
      float wss[4] = {ws.x, ws.y, ws.z, ws.w};
      #pragma unroll
      for (int i = 0; i < 4; ++i)
        #pragma unroll
        for (int j = 0; j < 4; ++j) {
          accP[i][j] = fmaf(xs[i], wps[j], accP[i][j]);
          accS[i][j] = fmaf(xs[i], wss[j], accS[i][j]);
        }
    }
    __syncthreads();
  }
  #pragma unroll
  for (int i = 0; i < 4; ++i) {
    int n = n0 + tn * 4 + i;
    if (n >= Np) continue;
    int o = o0 + to * 4;
    if (o + 3 < O) {
      long off = ((long)b * Np + n) * O + o;
      *(float4*)&PtT[off] = make_float4(accP[i][0], accP[i][1], accP[i][2], accP[i][3]);
      *(float4*)&StT[off] = make_float4(accS[i][0], accS[i][1], accS[i][2], accS[i][3]);
    } else {
      for (int j = 0; j < 4; ++j) {
        int oo = o + j;
        if (oo < O) {
          long off = ((long)b * Np + n) * O + oo;
          PtT[off] = accP[i][j];
          StT[off] = accS[i][j];
        }
      }
    }
  }
}

// ---------------- ecfinish body (O=64 flat-256 variant) ----------------
__device__ __forceinline__ void ecfinish_body64(const float* __restrict__ Pt, const float* __restrict__ St,
                                                const int* __restrict__ idx, int k, int O, int Np,
                                                const float* __restrict__ g, const float* __restrict__ bb,
                                                float* __restrict__ outp, long oStrideB,
                                                float* __restrict__ sqOut,
                                                int b, int blk) {
  int tid = threadIdx.x;
  int o = tid & 63;
  int n = blk * 4 + (tid >> 6);
  const float* PtB = Pt + (long)b * Np * O;
  const float* StB = St + (long)b * Np * O;
  const int* ip = idx + ((long)b * Np + n) * k;
  float mx = -INFINITY, mn = INFINITY;
  for (int kk = 0; kk < k; ++kk) {
    float v = PtB[(long)ip[kk] * O + o];
    mx = fmaxf(mx, v); mn = fminf(mn, v);
  }
  float ctrP = PtB[(long)n * O + o];
  float ctrS = StB[(long)n * O + o];
  float gs = g[o] * BN_SCALE;
  float m = (gs >= 0.f) ? mx : mn;
  float h = (ctrS - ctrP + m) * gs + bb[o];
  float out = h >= 0.f ? h : 0.2f * h;
  outp[(long)b * oStrideB + (long)o * Np + n] = out;
  if (sqOut) {
    int obits = __builtin_bit_cast(int, out);
    float acc = 0.f;
    #pragma unroll
    for (int c = 0; c < 64; ++c) {
      float hv = __builtin_bit_cast(float, __builtin_amdgcn_readlane(obits, c));
      acc = fmaf(hv, hv, acc);
    }
    if (o == 0) sqOut[(long)b * Np + n] = acc;
  }
}

__global__ void ecfinish_kernel(const float* __restrict__ Pt, const float* __restrict__ St,
                                const int* __restrict__ idx, int k, int O, int Np,
                                const float* __restrict__ g, const float* __restrict__ bb,
                                float* __restrict__ outp, long oStrideB) {
  int b = blockIdx.y;
  int n = blockIdx.x * blockDim.y + threadIdx.y;
  int o = threadIdx.x;
  const float* PtB = Pt + (long)b * Np * O;
  const float* StB = St + (long)b * Np * O;
  const int* ip = idx + ((long)b * Np + n) * k;
  float mx = -INFINITY, mn = INFINITY;
  for (int kk = 0; kk < k; ++kk) {
    float v = PtB[(long)ip[kk] * O + o];
    mx = fmaxf(mx, v); mn = fminf(mn, v);
  }
  float ctrP = PtB[(long)n * O + o];
  float ctrS = StB[(long)n * O + o];
  float gs = g[o] * BN_SCALE;
  float m = (gs >= 0.f) ? mx : mn;
  float h = (ctrS - ctrP + m) * gs + bb[o];
  outp[(long)b * oStrideB + (long)o * Np + n] = h >= 0.f ? h : 0.2f * h;
}

// ---------------- gemm_colmax body (R17: contiguous sub-tiles, float4 LDS reads) --------
__device__ __forceinline__ void gemm_colmax_body(const float* __restrict__ X, int xStrideB, int C, int Np,
                                                 const float* __restrict__ W, int ldw, int O,
                                                 const float* __restrict__ g, const float* __restrict__ bb,
                                                 float* __restrict__ partial,
                                                 int b, int n0, int o0, int nt, int nNT, char* smem) {
  float (*Wt)[68] = (float (*)[68])smem;            // 4352 B
  float (*Xt)[68] = (float (*)[68])(smem + 4352);   // 4352 B (8704 total)
  int tid = threadIdx.x;
  int to = tid % 16, tn = tid / 16;
  float acc[4][4] = {};
  for (int c0 = 0; c0 < C; c0 += 16) {
    for (int e = tid; e < 16 * 64; e += 256) {
      int oo = e / 16, kk = e % 16;
      int c = c0 + kk, o = o0 + oo;
      Wt[kk][oo] = (c < C && o < O) ? W[(long)o * ldw + c] : 0.f;
    }
    for (int e = tid; e < 16 * 64; e += 256) {
      int kk = e / 64, nn = e % 64;
      int c = c0 + kk, n = n0 + nn;
      Xt[kk][nn] = (c < C && n < Np) ? X[(long)b * xStrideB + (long)c * Np + n] : 0.f;
    }
    __syncthreads();
    for (int kk = 0; kk < 16; ++kk) {
      float4 xv = *(const float4*)&Xt[kk][tn * 4];
      float4 wv = *(const float4*)&Wt[kk][to * 4];
      float xs[4] = {xv.x, xv.y, xv.z, xv.w};
      float wvs[4] = {wv.x, wv.y, wv.z, wv.w};
      #pragma unroll
      for (int i = 0; i < 4; ++i)
        #pragma unroll
        for (int j = 0; j < 4; ++j) acc[i][j] = fmaf(xs[i], wvs[j], acc[i][j]);
    }
    __syncthreads();
  }
  float vm[4];
  #pragma unroll
  for (int j = 0; j < 4; ++j) {
    int o = o0 + to * 4 + j;
    float gs = g[o] * BN_SCALE, bo = bb[o];
    float m = -INFINITY;
    #pragma unroll
    for (int i = 0; i < 4; ++i) {
      float h = acc[i][j] * gs + bo;
      h = h >= 0.f ? h : 0.2f * h;
      m = fmaxf(m, h);
    }
    vm[j] = m;
  }
  #pragma unroll
  for (int j = 0; j < 4; ++j) Xt[tn][to * 4 + j] = vm[j];
  __syncthreads();
  for (int s = 8; s > 0; s >>= 1) {
    if (tn < s)
      for (int j = 0; j < 4; ++j)
        Xt[tn][to * 4 + j] = fmaxf(Xt[tn][to * 4 + j], Xt[tn + s][to * 4 + j]);
    __syncthreads();
  }
  if (tn == 0)
    for (int j = 0; j < 4; ++j) {
      int o = o0 + to * 4 + j;
      partial[((long)b * nNT + nt) * O + o] = Xt[0][to * 4 + j];
    }
}

__global__ void gemm_colmax_kernel(const float* __restrict__ X, int xStrideB, int C, int Np,
                                   const float* __restrict__ W, int ldw, int O,
                                   const float* __restrict__ g, const float* __restrict__ bb,
                                   float* __restrict__ partial) {
  __shared__ __align__(16) char smem[8704];
  gemm_colmax_body(X, xStrideB, C, Np, W, ldw, O, g, bb, partial,
                   blockIdx.z, blockIdx.x * 64, blockIdx.y * 64, blockIdx.x, gridDim.x, smem);
}

// ---------------- xmfill body ----------------
__device__ __forceinline__ void xmfill_body(const float* __restrict__ xt1, int N,
                                            const int* __restrict__ fpsI,
                                            const int* __restrict__ idxA, int k, int M,
                                            float* __restrict__ xm, int xe) {
  long t = (long)xe * 256 + threadIdx.x;
  int i = (int)(t % M);
  int c = (int)((t / M) % 128);
  int b = (int)(t / ((long)128 * M));
  const float* xb = xt1 + (long)b * 128 * N + (long)c * N;
  float* xmB = xm + (long)b * 256 * M;
  xmB[(long)c * M + i] = xb[fpsI[(long)b * M + i]];
  const int* ip = idxA + ((long)b * M + i) * k;
  float best = -INFINITY;
  for (int kk = 0; kk < k; ++kk) best = fmaxf(best, xb[ip[kk]]);
  xmB[(long)(128 + c) * M + i] = best;
}

// ---------------- FPS body, RANGE-split (R18: SoA px/py/pz, 26.8KB vs 35KB).
// Same swizzled slot (n&7)*256+(n>>3) -> identical bank behavior; values identical ->
// fidx/node1 bit-identical. Shrink lets the fused kernels hit 32KB LDS = 5 blocks/CU.
template <int FIRST, int LAST>
__device__ __forceinline__ void fps_body_rg(const float* __restrict__ xyz, int N, int M,
                                            int it0, int it1,
                                            int* __restrict__ fpsIdx, float* __restrict__ node1,
                                            float* __restrict__ distSv, int* __restrict__ lastSv,
                                            int b, char* smem) {
  #pragma clang fp contract(off)
  float* px = (float*)smem;                    // [2048] @ 0
  float* py = (float*)(smem + 8192);           // [2048]
  float* pz = (float*)(smem + 16384);          // [2048]
  int*   fidx = (int*)(smem + 24576);          // [512]
  float4* wvc = (float4*)(smem + 26624);       // [2][4] {gmax,x,y,z}
  int*   wis  = (int*)(smem + 26752);          // [2][4]   (total 26784 B)
  int tid = threadIdx.x;
  int lane = tid & 63, w = tid >> 6;
  const float* xb = xyz + (long)b * 3 * N;
  for (int n = tid; n < N; n += 256) {
    int s = ((n & 7) << 8) | (n >> 3);
    px[s] = xb[n]; py[s] = xb[N + n]; pz[s] = xb[2 * N + n];
  }
  if (!FIRST) {
    for (int e = tid; e < it0; e += 256) fidx[e] = fpsIdx[(long)b * M + e];
  }
  __syncthreads();
  float ptx[8], pty[8], ptz[8];
  #pragma unroll
  for (int i = 0; i < 8; ++i) {
    int s = (i << 8) | tid;                    // point tid*8+i
    ptx[i] = px[s]; pty[i] = py[s]; ptz[i] = pz[s];
  }
  float dist[8];
  int last;
  float lx, ly, lz;
  if (FIRST) {
    #pragma unroll
    for (int i = 0; i < 8; ++i) dist[i] = 1e10f;
    last = 0;
    int s0 = 0;
    lx = px[s0]; ly = py[s0]; lz = pz[s0];
  } else {
    #pragma unroll
    for (int i = 0; i < 8; ++i) dist[i] = distSv[(long)b * 2048 + i * 256 + tid];
    last = lastSv[b];
    int sl = ((last & 7) << 8) | (last >> 3);
    lx = px[sl]; ly = py[sl]; lz = pz[sl];
  }
  int base = tid * 8;
  for (int it = it0; it < it1; ++it) {
    int p = it & 1;
    if (tid == 0) fidx[it] = last;
    float best = -INFINITY; int bi = N;
    #pragma unroll
    for (int i = 0; i < 8; ++i) {
      float dx = ptx[i] - lx, dy = pty[i] - ly, dz = ptz[i] - lz;
      float dx2 = dx * dx, dy2 = dy * dy, dz2 = dz * dz;
      float d = (dx2 + dy2) + dz2;
      float dn = dist[i];
      if (d < dn) dn = d;
      dist[i] = dn;
      if (dn > best) { best = dn; bi = base + i; }
    }
    float cx = ptx[0], cy = pty[0], cz = ptz[0];
    #pragma unroll
    for (int i = 1; i < 8; ++i) {
      bool c = (bi == base + i);
      cx = c ? ptx[i] : cx; cy = c ? pty[i] : cy; cz = c ? ptz[i] : cz;
    }
    float gmax = wave_fmax(best);
    int cand = (best == gmax) ? bi : 0x7FFFFFFF;
    int wbi = wave_imin(cand);
    if (bi == wbi) { wvc[p * 4 + w] = make_float4(gmax, cx, cy, cz); wis[p * 4 + w] = wbi; }
    __syncthreads();
    float4 c0 = wvc[p * 4 + 0], c1 = wvc[p * 4 + 1], c2 = wvc[p * 4 + 2], c3 = wvc[p * 4 + 3];
    int i0 = wis[p * 4 + 0], i1 = wis[p * 4 + 1], i2 = wis[p * 4 + 2], i3 = wis[p * 4 + 3];
    float bv = c0.x; int bbi = i0; lx = c0.y; ly = c0.z; lz = c0.w;
    { bool c = (c1.x > bv) || (c1.x == bv && i1 < bbi);
      bv = c ? c1.x : bv; bbi = c ? i1 : bbi; lx = c ? c1.y : lx; ly = c ? c1.z : ly; lz = c ? c1.w : lz; }
    { bool c = (c2.x > bv) || (c2.x == bv && i2 < bbi);
      bv = c ? c2.x : bv; bbi = c ? i2 : bbi; lx = c ? c2.y : lx; ly = c ? c2.z : ly; lz = c ? c2.w : lz; }
    { bool c = (c3.x > bv) || (c3.x == bv && i3 < bbi);
      bv = c ? c3.x : bv; bbi = c ? i3 : bbi; lx = c ? c3.y : lx; ly = c ? c3.z : ly; lz = c ? c3.w : lz; }
    last = bbi;
    // parity: slot p rewritten only in iter it+2, after barrier it+1 -> safe with 1 barrier
  }
  if (!LAST) {
    for (int e = tid; e < it1; e += 256) {
      if (e >= it0) fpsIdx[(long)b * M + e] = fidx[e];
    }
    #pragma unroll
    for (int i = 0; i < 8; ++i) distSv[(long)b * 2048 + i * 256 + tid] = dist[i];
    if (tid == 0) lastSv[b] = last;
  } else {
    for (int e = tid; e < M; e += 256) fpsIdx[(long)b * M + e] = fidx[e];
    for (int e = tid; e < 3 * M; e += 256) {
      int c = e / M, i = e % M;
      int src = fidx[i];
      int s = ((src & 7) << 8) | (src >> 3);
      node1[(long)b * 3 * M + e] = (c == 0) ? px[s] : (c == 1) ? py[s] : pz[s];
    }
  }
}

// ---------------- fused {fps-range + knn + gemmPS}, 1D grid, fps first ----------------
// smem = max(knn 32768, fps 26784, gemmPS 13056) = 32768 -> 5 blocks/CU (was 4).
template <int FIRST, int LAST, bool SQP>
__global__ void knnfpsgemm_kernel(const float* __restrict__ Q, int qStrideB,
                                  const float* __restrict__ Xc, int cStrideB,
                                  int C, int Mq, int N, int k, int* __restrict__ idxOut,
                                  const float* __restrict__ W, int ldw, int O,
                                  float* __restrict__ Pt, float* __restrict__ St,
                                  const float* __restrict__ xyz, int Mf, int it0, int it1,
                                  int* __restrict__ fpsIdx, float* __restrict__ node1,
                                  float* __restrict__ distSv, int* __restrict__ lastSv,
                                  const float* __restrict__ sqPre,
                                  int nQblk, int nGblk, int nB) {
  __shared__ __align__(16) char smem[32768];
  int bid = blockIdx.x;
  if (bid < nB) {
    __builtin_amdgcn_s_setprio(1);
    fps_body_rg<FIRST, LAST>(xyz, N, Mf, it0, it1, fpsIdx, node1, distSv, lastSv, bid, smem);
    __builtin_amdgcn_s_setprio(0);
  } else if (bid < nB + nB * nQblk) {
    int e = bid - nB;
    knn4_body<8, SQP>(Q, qStrideB, Xc, cStrideB, C, Mq, N, k, idxOut, sqPre,
                      e / nQblk, (e % nQblk) * 4, smem);
  } else {
    int e = bid - nB - nB * nQblk;
    gemmPS_body(Xc, cStrideB, C, N, W, ldw, O, Pt, St,
                e / nGblk, (e % nGblk) * 64, 0, smem);
  }
}

// ---------------- fused {ecfinish1 (+sq emit) + fps mid-range}, fps blocks first --------
__global__ void ecfps_kernel(const float* __restrict__ Pt, const float* __restrict__ St,
                             const int* __restrict__ idx, int k, int O, int Np,
                             const float* __restrict__ g, const float* __restrict__ bb,
                             float* __restrict__ outp, long oStrideB,
                             float* __restrict__ sqOut,
                             const float* __restrict__ xyz, int N, int Mf, int it0, int it1,
                             int* __restrict__ fpsIdx, float* __restrict__ node1,
                             float* __restrict__ distSv, int* __restrict__ lastSv,
                             int nEperB, int nB) {
  __shared__ __align__(16) char smem[26784];
  int bid = blockIdx.x;
  if (bid < nB) {
    __builtin_amdgcn_s_setprio(1);
    fps_body_rg<0, 0>(xyz, N, Mf, it0, it1, fpsIdx, node1, distSv, lastSv, bid, smem);
    __builtin_amdgcn_s_setprio(0);
  } else {
    int e = bid - nB;
    ecfinish_body64(Pt, St, idx, k, O, Np, g, bb, outp, oStrideB, sqOut,
                    e / nEperB, e % nEperB);
  }
}

// ---------------- fused {ecfinish2 + agg-knn}, striped (agg every 5th bid) ----------------
__global__ void ecfagg_kernel(const float* __restrict__ Pt, const float* __restrict__ St,
                              const int* __restrict__ idxS2, int k2, int O2, int Np2,
                              const float* __restrict__ g2, const float* __restrict__ b2,
                              float* __restrict__ out2, long oStrideB2,
                              const float* __restrict__ Qn, int qStrideB,
                              const float* __restrict__ Xc, int cStrideB,
                              int Cq, int Mq, int Nc, int kq, int* __restrict__ idxAgg,
                              int nQblk, int nEperB) {
  __shared__ __align__(16) char smem[32768];
  int bid = blockIdx.x;
  if (bid % 5 == 0) {
    int a = bid / 5;                       // [0, 1024)
    knn4_body<8, false>(Qn, qStrideB, Xc, cStrideB, Cq, Mq, Nc, kq, idxAgg, nullptr,
                        a / nQblk, (a % nQblk) * 4, smem);
  } else {
    int e = bid - bid / 5 - 1;             // [0, 4096) sequential
    ecfinish_body64(Pt, St, idxS2, k2, O2, Np2, g2, b2, out2, oStrideB2, nullptr,
                    e / nEperB, e % nEperB);
  }
}

// ---------------- fused {gemm_colmaxA + xmfill}, striped (xmfill every 3rd bid) ----------------
__global__ void colmaxxm_kernel(const float* __restrict__ X, int xStrideB, int C, int Np,
                                const float* __restrict__ W, int ldw, int O,
                                const float* __restrict__ g, const float* __restrict__ bb,
                                float* __restrict__ partial, int nNT, int nOT,
                                const float* __restrict__ xt1, int N,
                                const int* __restrict__ fpsI, const int* __restrict__ idxA,
                                int kq, int M, float* __restrict__ xm) {
  __shared__ __align__(16) char smem[8704];
  int bid = blockIdx.x;
  if (bid % 3 == 0) {
    xmfill_body(xt1, N, fpsI, idxA, kq, M, xm, bid / 3);       // [0, 2048)
  } else {
    int e = bid - bid / 3 - 1;                                  // [0, 4096)
    int per = nNT * nOT;
    int b = e / per, r = e % per;
    int nt = r % nNT, ot = r / nNT;
    gemm_colmax_body(X, xStrideB, C, Np, W, ldw, O, g, bb, partial,
                     b, nt * 64, ot * 64, nt, nNT, smem);
  }
}

// ---------------- fused {knn<2> + gemmPS} for stages 3/4 ----------------
__global__ void knngemm_kernel(const float* __restrict__ Xin, int xStrideB,
                               int C, int Mq, int N, int k, int* __restrict__ idxOut,
                               const float* __restrict__ W, int ldw, int O,
                               float* __restrict__ Pt, float* __restrict__ St,
                               int nQblk, int nGn, int nGo, int nB) {
  __shared__ __align__(16) char smem[13056];
  int bid = blockIdx.x;
  if (bid < nB * nQblk) {
    knn4_body<2, false>(Xin, xStrideB, Xin, xStrideB, C, Mq, N, k, idxOut, nullptr,
                        bid / nQblk, (bid % nQblk) * 4, smem);
  } else {
    int e = bid - nB * nQblk;
    int per = nGn * nGo;
    int b = e / per, r = e % per;
    int nt = r % nGn, ot = r / nGn;
    gemmPS_body(Xin, xStrideB, C, N, W, ldw, O, Pt, St, b, nt * 64, ot * 64, smem);
  }
}

// ---------------- head: fused colmax_finish + 3-layer MLP (wave-cooperative) ----------------
__global__ void head_kernel(const float* __restrict__ partA, int NTa,
                            const float* __restrict__ partB, int NTb,
                            const float* __restrict__ Wl1, const float* __restrict__ g6, const float* __restrict__ b6,
                            const float* __restrict__ Wl2, const float* __restrict__ bl2,
                            const float* __restrict__ g7, const float* __restrict__ b7,
                            const float* __restrict__ Wl3, const float* __restrict__ bl3,
                            float* __restrict__ logits) {
  __shared__ float v[2048];
  __shared__ float h1[512];
  __shared__ float h2[256];
  int b = blockIdx.x, tid = threadIdx.x;
  int lane = tid & 63, w = tid >> 6;
  for (int o = tid; o < 1024; o += 256) {
    float m = -INFINITY;
    for (int t = 0; t < NTa; ++t) m = fmaxf(m, partA[((long)b * NTa + t) * 1024 + o]);
    v[o] = m;
    float m2 = -INFINITY;
    for (int t = 0; t < NTb; ++t) m2 = fmaxf(m2, partB[((long)b * NTb + t) * 1024 + o]);
    v[1024 + o] = m2;
  }
  __syncthreads();
  for (int o = w; o < 512; o += 4) {
    const float4* wr = (const float4*)(Wl1 + (long)o * 2048);
    const float4* vp = (const float4*)v;
    float s = 0.f;
    #pragma unroll
    for (int j = 0; j < 8; ++j) {
      float4 w4 = wr[lane + 64 * j];
      float4 v4 = vp[lane + 64 * j];
      s = fmaf(w4.x, v4.x, s); s = fmaf(w4.y, v4.y, s);
      s = fmaf(w4.z, v4.z, s); s = fmaf(w4.w, v4.w, s);
    }
    float t = wave_fadd(s);
    if (lane == 0) {
      float h = t * (g6[o] * BN_SCALE) + b6[o];
      h1[o] = h >= 0.f ? h : 0.2f * h;
    }
  }
  __syncthreads();
  for (int o = w; o < 256; o += 4) {
    const float4* wr = (const float4*)(Wl2 + (long)o * 512);
    const float4* hp = (const float4*)h1;
    float s = 0.f;
    #pragma unroll
    for (int j = 0; j < 2; ++j) {
      float4 w4 = wr[lane + 64 * j];
      float4 v4 = hp[lane + 64 * j];
      s = fmaf(w4.x, v4.x, s); s = fmaf(w4.y, v4.y, s);
      s = fmaf(w4.z, v4.z, s); s = fmaf(w4.w, v4.w, s);
    }
    float t = wave_fadd(s);
    if (lane == 0) {
      float sb = t + bl2[o];
      float h = sb * (g7[o] * BN_SCALE) + b7[o];
      h2[o] = h >= 0.f ? h : 0.2f * h;
    }
  }
  __syncthreads();
  for (int o = w; o < 40; o += 4) {
    const float4* wr = (const float4*)(Wl3 + (long)o * 256);
    const float4* hp = (const float4*)h2;
    float4 w4 = wr[lane];
    float4 v4 = hp[lane];
    float s = fmaf(w4.x, v4.x, 0.f);
    s = fmaf(w4.y, v4.y, s); s = fmaf(w4.z, v4.z, s); s = fmaf(w4.w, v4.w, s);
    float t = wave_fadd(s);
    if (lane == 0) logits[(long)b * 40 + o] = t + bl3[o];
  }
}

extern "C" void kernel_launch(void* const* d_in, const int* in_sizes, int n_in,
                              void* d_out, int out_size, void* d_ws, size_t ws_size,
                              hipStream_t stream) {
  const float* x   = (const float*)d_in[0];
  const float* W1  = (const float*)d_in[1];
  const float* g1  = (const float*)d_in[2];
  const float* b1  = (const float*)d_in[3];
  const float* W2  = (const float*)d_in[4];
  const float* g2  = (const float*)d_in[5];
  const float* b2  = (const float*)d_in[6];
  const float* W2m = (const float*)d_in[7];
  const float* g2m = (const float*)d_in[8];
  const float* b2m = (const float*)d_in[9];
  const float* W3  = (const float*)d_in[10];
  const float* g3  = (const float*)d_in[11];
  const float* b3  = (const float*)d_in[12];
  const float* W4  = (const float*)d_in[13];
  const float* g4  = (const float*)d_in[14];
  const float* b4  = (const float*)d_in[15];
  const float* W5  = (const float*)d_in[16];
  const float* g5  = (const float*)d_in[17];
  const float* b5  = (const float*)d_in[18];
  const float* Wl1 = (const float*)d_in[19];
  const float* g6  = (const float*)d_in[20];
  const float* b6  = (const float*)d_in[21];
  const float* Wl2 = (const float*)d_in[22];
  const float* bl2 = (const float*)d_in[23];
  const float* g7  = (const float*)d_in[24];
  const float* b7  = (const float*)d_in[25];
  const float* Wl3 = (const float*)d_in[26];
  const float* bl3 = (const float*)d_in[27];
  float* outF = (float*)d_out;

  const int B = 8, N = 2048, K = 20, M = 512, K2 = 10;

  float* ws    = (float*)d_ws;
  float* xt1   = ws;                               // (B,128,N)
  float* xm    = xt1 + (size_t)B * 128 * N;        // (B,256,M)
  float* xc    = xm  + (size_t)B * 256 * M;        // (B,512,M)
  float* Pt    = xc  + (size_t)B * 512 * M;        // max(B*N*64, B*M*256)
  float* St    = Pt  + (size_t)B * N * 64;
  float* partA = St  + (size_t)B * N * 64;         // (B,32,1024)
  float* partB = partA + (size_t)B * 32 * 1024;    // (B,8,1024)
  int*   idxK  = (int*)(partB + (size_t)B * 8 * 1024);  // (B,N,K)
  int*   fpsI  = idxK + (size_t)B * N * K;         // (B,M)
  float* fpsDist = (float*)(fpsI + (size_t)B * M); // (B,2048) fps checkpoint dists
  int*   fpsLast = (int*)(fpsDist + (size_t)B * 2048);  // (B)
  int*   idxAgg  = fpsLast + 64;                   // (B,M,K) aggregate-knn indices
  float* sqS2    = (float*)(idxAgg + (size_t)B * M * K); // (B,N) stage-2 candidate norms

  float* logits = outF;        // (B,40)
  float* node1  = outF + 320;  // (B,3,M)

  dim3 t256(256);
  const int nQblk = N / 4;     // 512 knn query-blocks per batch (N-point knn)
  const int nGblk = N / 64;    // 32 gemmPS n-tiles per batch (stage 1/2)
  const int nFused = B + B * nQblk + B * nGblk;
  const int nQa = M / 4;       // 128 agg/stage3/4 knn query-blocks per batch
  const int IT1 = 208, IT2 = 304;   // fps phase boundaries

  // ---- stage 1 FUSED: fps [0,208) + knn(xyz) + gemmPS1 (all depend only on x)
  knnfpsgemm_kernel<1, 0, false><<<dim3(nFused), t256, 0, stream>>>(
      x, 3 * N, x, 3 * N, 3, N, N, K, idxK,
      W1, 6, 64, Pt, St,
      x, M, 0, IT1, fpsI, node1, fpsDist, fpsLast, nullptr, nQblk, nGblk, B);

  // ---- ecfinish1 (+sq emit for stage-2 knn) FUSED with fps [208,304)
  ecfps_kernel<<<dim3(B + B * (N / 4)), t256, 0, stream>>>(
      Pt, St, idxK, K, 64, N, g1, b1, xt1, (long)128 * N, sqS2,
      x, N, M, IT1, IT2, fpsI, node1, fpsDist, fpsLast, N / 4, B);

  // ---- stage 2 FUSED: fps [304,512) + knn(x1, precomputed sq) + gemmPS2
  knnfpsgemm_kernel<0, 1, true><<<dim3(nFused), t256, 0, stream>>>(
      xt1, 128 * N, xt1, 128 * N, 64, N, N, K, idxK,
      W2, 128, 64, Pt, St,
      x, M, IT2, M, fpsI, node1, fpsDist, fpsLast, sqS2, nQblk, nGblk, B);

  // ---- FUSED: ecfinish2 (gather-bound) + aggregate-knn (VALU-latency-bound), striped
  ecfagg_kernel<<<dim3(B * nQa + B * (N / 4)), t256, 0, stream>>>(
      Pt, St, idxK, K, 64, N, g2, b2, xt1 + (size_t)64 * N, (long)128 * N,
      node1, 3 * M, x, 3 * N, 3, M, N, K, idxAgg, nQa, N / 4);

  // ---- FUSED: gemm_colmaxA + xmfill, striped every-3rd
  colmaxxm_kernel<<<dim3((B * 128 * M) / 256 + B * 32 * 16), t256, 0, stream>>>(
      xt1, 128 * N, 128, N, W2m, 128, 1024, g2m, b2m, partA, 32, 16,
      xt1, N, fpsI, idxAgg, K, M, xm);

  // ---- stage 3 FUSED: knn(xm) + gemmPS3
  knngemm_kernel<<<dim3(B * nQa + B * (M / 64) * (256 / 64)), t256, 0, stream>>>(
      xm, 256 * M, 256, M, M, K2, idxK, W3, 512, 256, Pt, St, nQa, M / 64, 256 / 64, B);
  ecfinish_kernel<<<dim3(M, B), dim3(256, 1), 0, stream>>>(Pt, St, idxK, K2, 256, M, g3, b3, xc, (long)512 * M);

  // ---- stage 4 FUSED: knn(x3) + gemmPS4
  knngemm_kernel<<<dim3(B * nQa + B * (M / 64) * (256 / 64)), t256, 0, stream>>>(
      xc, 512 * M, 256, M, M, K2, idxK, W4, 512, 256, Pt, St, nQa, M / 64, 256 / 64, B);
  ecfinish_kernel<<<dim3(M, B), dim3(256, 1), 0, stream>>>(Pt, St, idxK, K2, 256, M, g4, b4,
                                                           xc + (size_t)256 * M, (long)512 * M);

  // ---- vs partials
  gemm_colmax_kernel<<<dim3(M / 64, 1024 / 64, B), t256, 0, stream>>>(xc, 512 * M, 512, M, W5, 512, 1024,
                                                                      g5, b5, partB);

  // ---- head (fused colmax_finish + MLP; NTa=32, NTb=8)
  head_kernel<<<dim3(B), t256, 0, stream>>>(partA, N / 64, partB, M / 64,
                                            Wl1, g6, b6, Wl2, bl2, g7, b7, Wl3, bl3, logits);
}

// Round 19
// 984.447 us; speedup vs baseline: 1.3104x; 1.0738x over previous
//
#include <hip/hip_runtime.h>

#define BN_SCALE 0.9999950000374997f  // 1/sqrt(1+1e-5)

// ---- DPP full-wave reductions (validated in fps/knn since R2/R4) ----
template <int CTRL>
__device__ __forceinline__ float dpp_fmax_step(float v) {
  int xi = __builtin_bit_cast(int, v);
  int ti = __builtin_amdgcn_update_dpp(xi, xi, CTRL, 0xf, 0xf, false);  // invalid lanes -> old(=v)
  return fmaxf(v, __builtin_bit_cast(float, ti));
}
template <int CTRL>
__device__ __forceinline__ int dpp_imin_step(int v) {
  int t = __builtin_amdgcn_update_dpp(v, v, CTRL, 0xf, 0xf, false);    // invalid lanes -> old(=v)
  return (t < v) ? t : v;
}
template <int CTRL>
__device__ __forceinline__ float dpp_fadd_step(float v) {
  // bound_ctrl=true: invalid lanes contribute 0 (required for sums)
  int ti = __builtin_amdgcn_update_dpp(0, __builtin_bit_cast(int, v), CTRL, 0xf, 0xf, true);
  return v + __builtin_bit_cast(float, ti);
}
__device__ __forceinline__ float wave_fmax(float v) {
  v = dpp_fmax_step<0x111>(v);
  v = dpp_fmax_step<0x112>(v);
  v = dpp_fmax_step<0x114>(v);
  v = dpp_fmax_step<0x118>(v);
  v = dpp_fmax_step<0x142>(v);
  v = dpp_fmax_step<0x143>(v);
  return __builtin_bit_cast(float, __builtin_amdgcn_readlane(__builtin_bit_cast(int, v), 63));
}
__device__ __forceinline__ int wave_imin(int v) {
  v = dpp_imin_step<0x111>(v);
  v = dpp_imin_step<0x112>(v);
  v = dpp_imin_step<0x114>(v);
  v = dpp_imin_step<0x118>(v);
  v = dpp_imin_step<0x142>(v);
  v = dpp_imin_step<0x143>(v);
  return __builtin_amdgcn_readlane(v, 63);
}
__device__ __forceinline__ float wave_fadd(float v) {
  v = dpp_fadd_step<0x111>(v);
  v = dpp_fadd_step<0x112>(v);
  v = dpp_fadd_step<0x114>(v);
  v = dpp_fadd_step<0x118>(v);
  v = dpp_fadd_step<0x142>(v);
  v = dpp_fadd_step<0x143>(v);
  return __builtin_bit_cast(float, __builtin_amdgcn_readlane(__builtin_bit_cast(int, v), 63));
}

// ---------------- knn4 body (R18: persistent group bests) ----------------
template <int R, bool SQPRE>
__device__ __forceinline__ void knn4_body(const float* __restrict__ Q, int qStrideB,
                                          const float* __restrict__ Xc, int cStrideB,
                                          int C, int M, int N, int k, int* __restrict__ idxOut,
                                          const float* __restrict__ sqPre,
                                          int b, int q0, char* smem) {
  constexpr int NR = 4 * R;
  float (*negd)[R * 256] = (float (*)[R * 256])smem;
  int tid = threadIdx.x;
  const float* qb = Q + (long)b * qStrideB + q0;
  const float* cb = Xc + (long)b * cStrideB;
  if constexpr (R % 4 == 0) {
    constexpr int H = R / 4;
    float d0[R], d1[R], d2[R], d3[R], sq[R];
    #pragma unroll
    for (int i = 0; i < R; ++i) { d0[i] = d1[i] = d2[i] = d3[i] = sq[i] = 0.f; }
    for (int c = 0; c < C; ++c) {
      float4 q4 = *(const float4*)(qb + (long)c * M);  // uniform -> scalar load
      const float4* pc4 = (const float4*)(cb + (long)c * N);
      #pragma unroll
      for (int h = 0; h < H; ++h) {
        float4 xv = pc4[tid + 256 * h];                // 16B/lane coalesced
        if (!SQPRE) {
          sq[4 * h + 0] = fmaf(xv.x, xv.x, sq[4 * h + 0]);
          sq[4 * h + 1] = fmaf(xv.y, xv.y, sq[4 * h + 1]);
          sq[4 * h + 2] = fmaf(xv.z, xv.z, sq[4 * h + 2]);
          sq[4 * h + 3] = fmaf(xv.w, xv.w, sq[4 * h + 3]);
        }
        d0[4 * h + 0] = fmaf(q4.x, xv.x, d0[4 * h + 0]);
        d0[4 * h + 1] = fmaf(q4.x, xv.y, d0[4 * h + 1]);
        d0[4 * h + 2] = fmaf(q4.x, xv.z, d0[4 * h + 2]);
        d0[4 * h + 3] = fmaf(q4.x, xv.w, d0[4 * h + 3]);
        d1[4 * h + 0] = fmaf(q4.y, xv.x, d1[4 * h + 0]);
        d1[4 * h + 1] = fmaf(q4.y, xv.y, d1[4 * h + 1]);
        d1[4 * h + 2] = fmaf(q4.y, xv.z, d1[4 * h + 2]);
        d1[4 * h + 3] = fmaf(q4.y, xv.w, d1[4 * h + 3]);
        d2[4 * h + 0] = fmaf(q4.z, xv.x, d2[4 * h + 0]);
        d2[4 * h + 1] = fmaf(q4.z, xv.y, d2[4 * h + 1]);
        d2[4 * h + 2] = fmaf(q4.z, xv.z, d2[4 * h + 2]);
        d2[4 * h + 3] = fmaf(q4.z, xv.w, d2[4 * h + 3]);
        d3[4 * h + 0] = fmaf(q4.w, xv.x, d3[4 * h + 0]);
        d3[4 * h + 1] = fmaf(q4.w, xv.y, d3[4 * h + 1]);
        d3[4 * h + 2] = fmaf(q4.w, xv.z, d3[4 * h + 2]);
        d3[4 * h + 3] = fmaf(q4.w, xv.w, d3[4 * h + 3]);
      }
    }
    #pragma unroll
    for (int h = 0; h < H; ++h) {
      float4 s4;
      if (SQPRE) {
        s4 = ((const float4*)(sqPre + (long)b * N))[tid + 256 * h];
      } else {
        s4 = make_float4(sq[4 * h], sq[4 * h + 1], sq[4 * h + 2], sq[4 * h + 3]);
      }
      ((float4*)negd[0])[tid + 256 * h] =
          make_float4(2.f * d0[4 * h] - s4.x, 2.f * d0[4 * h + 1] - s4.y,
                      2.f * d0[4 * h + 2] - s4.z, 2.f * d0[4 * h + 3] - s4.w);
      ((float4*)negd[1])[tid + 256 * h] =
          make_float4(2.f * d1[4 * h] - s4.x, 2.f * d1[4 * h + 1] - s4.y,
                      2.f * d1[4 * h + 2] - s4.z, 2.f * d1[4 * h + 3] - s4.w);
      ((float4*)negd[2])[tid + 256 * h] =
          make_float4(2.f * d2[4 * h] - s4.x, 2.f * d2[4 * h + 1] - s4.y,
                      2.f * d2[4 * h + 2] - s4.z, 2.f * d2[4 * h + 3] - s4.w);
      ((float4*)negd[3])[tid + 256 * h] =
          make_float4(2.f * d3[4 * h] - s4.x, 2.f * d3[4 * h + 1] - s4.y,
                      2.f * d3[4 * h + 2] - s4.z, 2.f * d3[4 * h + 3] - s4.w);
    }
  } else {
    float d0[R], d1[R], d2[R], d3[R], sq[R];
    #pragma unroll
    for (int i = 0; i < R; ++i) { d0[i] = d1[i] = d2[i] = d3[i] = sq[i] = 0.f; }
    for (int c = 0; c < C; ++c) {
      float4 q4 = *(const float4*)(qb + (long)c * M);
      const float* pc = cb + (long)c * N;
      #pragma unroll
      for (int i = 0; i < R; ++i) {
        float xv = pc[tid + 256 * i];
        sq[i] = fmaf(xv, xv, sq[i]);
        d0[i] = fmaf(q4.x, xv, d0[i]);
        d1[i] = fmaf(q4.y, xv, d1[i]);
        d2[i] = fmaf(q4.z, xv, d2[i]);
        d3[i] = fmaf(q4.w, xv, d3[i]);
      }
    }
    #pragma unroll
    for (int i = 0; i < R; ++i) {
      int m = tid + 256 * i;
      negd[0][m] = 2.f * d0[i] - sq[i];
      negd[1][m] = 2.f * d1[i] - sq[i];
      negd[2][m] = 2.f * d2[i] - sq[i];
      negd[3][m] = 2.f * d3[i] - sq[i];
    }
  }
  __syncthreads();
  int lane = tid & 63, w = tid >> 6;
  const float* row = negd[w];
  int* outp = idxOut + ((long)b * M + (q0 + w)) * k;
  float v[NR];
  #pragma unroll
  for (int i = 0; i < NR; ++i) v[i] = row[lane + 64 * i];
  constexpr int G = NR / 4;
  float bv[G]; int br[G];
  #pragma unroll
  for (int g = 0; g < G; ++g) {
    float v0 = v[4 * g]; int r0 = 4 * g;
    #pragma unroll
    for (int j = 1; j < 4; ++j) {
      bool c = v[4 * g + j] > v0;
      v0 = c ? v[4 * g + j] : v0;
      r0 = c ? (4 * g + j) : r0;
    }
    bv[g] = v0; br[g] = r0;
  }
  for (int kk = 0; kk < k; ++kk) {
    float mv[G]; int mi[G];
    #pragma unroll
    for (int g = 0; g < G; ++g) { mv[g] = bv[g]; mi[g] = br[g]; }
    #pragma unroll
    for (int s = G >> 1; s >= 1; s >>= 1) {
      #pragma unroll
      for (int i = 0; i < s; ++i) {
        bool c = mv[2 * i] >= mv[2 * i + 1];
        mv[i] = c ? mv[2 * i] : mv[2 * i + 1];
        mi[i] = c ? mi[2 * i] : mi[2 * i + 1];
      }
    }
    float best = mv[0]; int ib = mi[0];
    int bi = (best > -INFINITY) ? (lane + (ib << 6)) : N;
    float gmax = wave_fmax(best);
    int cand = (best == gmax) ? bi : 0x7FFFFFFF;
    int big = wave_imin(cand);
    if (lane == 0) outp[kk] = big;
    int ri = big >> 6;                      // uniform
    bool mine = (lane == (big & 63));
    #pragma unroll
    for (int i = 0; i < NR; ++i)
      if (i == ri) v[i] = mine ? -INFINITY : v[i];
    int gi = ri >> 2;
    #pragma unroll
    for (int g = 0; g < G; ++g) {
      if (g == gi) {
        float v0 = v[4 * g]; int r0 = 4 * g;
        #pragma unroll
        for (int j = 1; j < 4; ++j) {
          bool c = v[4 * g + j] > v0;
          v0 = c ? v[4 * g + j] : v0;
          r0 = c ? (4 * g + j) : r0;
        }
        bv[g] = v0; br[g] = r0;
      }
    }
  }
}

template <int R>
__global__ void knn4_kernel(const float* __restrict__ Q, int qStrideB,
                            const float* __restrict__ Xc, int cStrideB,
                            int C, int M, int N, int k, int* __restrict__ idxOut) {
  __shared__ __align__(16) char smem[R * 256 * 4 * 4];
  knn4_body<R, false>(Q, qStrideB, Xc, cStrideB, C, M, N, k, idxOut, nullptr,
                      blockIdx.y, blockIdx.x * 4, smem);
}

// ---------------- gemmPS body (R17: contiguous sub-tiles, float4 LDS reads) ----------------
__device__ __forceinline__ void gemmPS_body(const float* __restrict__ X, int xStrideB, int C, int Np,
                                            const float* __restrict__ W, int ldw, int O,
                                            float* __restrict__ PtT, float* __restrict__ StT,
                                            int b, int n0, int o0, char* smem) {
  float (*Wp)[68] = (float (*)[68])smem;             // 4352 B
  float (*Ws)[68] = (float (*)[68])(smem + 4352);    // 4352 B
  float (*Xt)[68] = (float (*)[68])(smem + 8704);    // 4352 B (13056 total)
  int tid = threadIdx.x;
  int to = tid % 16, tn = tid / 16;
  float accP[4][4] = {}, accS[4][4] = {};
  for (int c0 = 0; c0 < C; c0 += 16) {
    for (int e = tid; e < 16 * 64; e += 256) {
      int oo = e / 16, kk = e % 16;
      int c = c0 + kk, o = o0 + oo;
      bool ok = (c < C && o < O);
      Wp[kk][oo] = ok ? W[(long)o * ldw + c] : 0.f;
      Ws[kk][oo] = ok ? W[(long)o * ldw + C + c] : 0.f;
    }
    for (int e = tid; e < 16 * 64; e += 256) {
      int kk = e / 64, nn = e % 64;
      int c = c0 + kk, n = n0 + nn;
      Xt[kk][nn] = (c < C && n < Np) ? X[(long)b * xStrideB + (long)c * Np + n] : 0.f;
    }
    __syncthreads();
    for (int kk = 0; kk < 16; ++kk) {
      float4 xv = *(const float4*)&Xt[kk][tn * 4];
      float4 wp = *(const float4*)&Wp[kk][to * 4];
      float4 ws = *(const float4*)&Ws[kk][to * 4];
      float xs[4] = {xv.x, xv.y, xv.z, xv.w};
      float wps[4] = {wp.x, wp.y, wp.z, wp.w};
      float wss[4] = {ws.x, ws.y, ws.z, ws.w};
      #pragma unroll
      for (int i = 0; i < 4; ++i)
        #pragma unroll
        for (int j = 0; j < 4; ++j) {
          accP[i][j] = fmaf(xs[i], wps[j], accP[i][j]);
          accS[i][j] = fmaf(xs[i], wss[j], accS[i][j]);
        }
    }
    __syncthreads();
  }
  #pragma unroll
  for (int i = 0; i < 4; ++i) {
    int n = n0 + tn * 4 + i;
    if (n >= Np) continue;
    int o = o0 + to * 4;
    if (o + 3 < O) {
      long off = ((long)b * Np + n) * O + o;
      *(float4*)&PtT[off] = make_float4(accP[i][0], accP[i][1], accP[i][2], accP[i][3]);
      *(float4*)&StT[off] = make_float4(accS[i][0], accS[i][1], accS[i][2], accS[i][3]);
    } else {
      for (int j = 0; j < 4; ++j) {
        int oo = o + j;
        if (oo < O) {
          long off = ((long)b * Np + n) * O + oo;
          PtT[off] = accP[i][j];
          StT[off] = accS[i][j];
        }
      }
    }
  }
}

// ---------------- ecfinish body (O=64 flat-256 variant) ----------------
__device__ __forceinline__ void ecfinish_body64(const float* __restrict__ Pt, const float* __restrict__ St,
                                                const int* __restrict__ idx, int k, int O, int Np,
                                                const float* __restrict__ g, const float* __restrict__ bb,
                                                float* __restrict__ outp, long oStrideB,
                                                float* __restrict__ sqOut,
                                                int b, int blk) {
  int tid = threadIdx.x;
  int o = tid & 63;
  int n = blk * 4 + (tid >> 6);
  const float* PtB = Pt + (long)b * Np * O;
  const float* StB = St + (long)b * Np * O;
  const int* ip = idx + ((long)b * Np + n) * k;
  float mx = -INFINITY, mn = INFINITY;
  for (int kk = 0; kk < k; ++kk) {
    float v = PtB[(long)ip[kk] * O + o];
    mx = fmaxf(mx, v); mn = fminf(mn, v);
  }
  float ctrP = PtB[(long)n * O + o];
  float ctrS = StB[(long)n * O + o];
  float gs = g[o] * BN_SCALE;
  float m = (gs >= 0.f) ? mx : mn;
  float h = (ctrS - ctrP + m) * gs + bb[o];
  float out = h >= 0.f ? h : 0.2f * h;
  outp[(long)b * oStrideB + (long)o * Np + n] = out;
  if (sqOut) {
    int obits = __builtin_bit_cast(int, out);
    float acc = 0.f;
    #pragma unroll
    for (int c = 0; c < 64; ++c) {
      float hv = __builtin_bit_cast(float, __builtin_amdgcn_readlane(obits, c));
      acc = fmaf(hv, hv, acc);
    }
    if (o == 0) sqOut[(long)b * Np + n] = acc;
  }
}

__global__ void ecfinish_kernel(const float* __restrict__ Pt, const float* __restrict__ St,
                                const int* __restrict__ idx, int k, int O, int Np,
                                const float* __restrict__ g, const float* __restrict__ bb,
                                float* __restrict__ outp, long oStrideB) {
  int b = blockIdx.y;
  int n = blockIdx.x * blockDim.y + threadIdx.y;
  int o = threadIdx.x;
  const float* PtB = Pt + (long)b * Np * O;
  const float* StB = St + (long)b * Np * O;
  const int* ip = idx + ((long)b * Np + n) * k;
  float mx = -INFINITY, mn = INFINITY;
  for (int kk = 0; kk < k; ++kk) {
    float v = PtB[(long)ip[kk] * O + o];
    mx = fmaxf(mx, v); mn = fminf(mn, v);
  }
  float ctrP = PtB[(long)n * O + o];
  float ctrS = StB[(long)n * O + o];
  float gs = g[o] * BN_SCALE;
  float m = (gs >= 0.f) ? mx : mn;
  float h = (ctrS - ctrP + m) * gs + bb[o];
  outp[(long)b * oStrideB + (long)o * Np + n] = h >= 0.f ? h : 0.2f * h;
}

// ---------------- gemm_colmax body (R17: contiguous sub-tiles, float4 LDS reads) --------
__device__ __forceinline__ void gemm_colmax_body(const float* __restrict__ X, int xStrideB, int C, int Np,
                                                 const float* __restrict__ W, int ldw, int O,
                                                 const float* __restrict__ g, const float* __restrict__ bb,
                                                 float* __restrict__ partial,
                                                 int b, int n0, int o0, int nt, int nNT, char* smem) {
  float (*Wt)[68] = (float (*)[68])smem;            // 4352 B
  float (*Xt)[68] = (float (*)[68])(smem + 4352);   // 4352 B (8704 total)
  int tid = threadIdx.x;
  int to = tid % 16, tn = tid / 16;
  float acc[4][4] = {};
  for (int c0 = 0; c0 < C; c0 += 16) {
    for (int e = tid; e < 16 * 64; e += 256) {
      int oo = e / 16, kk = e % 16;
      int c = c0 + kk, o = o0 + oo;
      Wt[kk][oo] = (c < C && o < O) ? W[(long)o * ldw + c] : 0.f;
    }
    for (int e = tid; e < 16 * 64; e += 256) {
      int kk = e / 64, nn = e % 64;
      int c = c0 + kk, n = n0 + nn;
      Xt[kk][nn] = (c < C && n < Np) ? X[(long)b * xStrideB + (long)c * Np + n] : 0.f;
    }
    __syncthreads();
    for (int kk = 0; kk < 16; ++kk) {
      float4 xv = *(const float4*)&Xt[kk][tn * 4];
      float4 wv = *(const float4*)&Wt[kk][to * 4];
      float xs[4] = {xv.x, xv.y, xv.z, xv.w};
      float wvs[4] = {wv.x, wv.y, wv.z, wv.w};
      #pragma unroll
      for (int i = 0; i < 4; ++i)
        #pragma unroll
        for (int j = 0; j < 4; ++j) acc[i][j] = fmaf(xs[i], wvs[j], acc[i][j]);
    }
    __syncthreads();
  }
  float vm[4];
  #pragma unroll
  for (int j = 0; j < 4; ++j) {
    int o = o0 + to * 4 + j;
    float gs = g[o] * BN_SCALE, bo = bb[o];
    float m = -INFINITY;
    #pragma unroll
    for (int i = 0; i < 4; ++i) {
      float h = acc[i][j] * gs + bo;
      h = h >= 0.f ? h : 0.2f * h;
      m = fmaxf(m, h);
    }
    vm[j] = m;
  }
  #pragma unroll
  for (int j = 0; j < 4; ++j) Xt[tn][to * 4 + j] = vm[j];
  __syncthreads();
  for (int s = 8; s > 0; s >>= 1) {
    if (tn < s)
      for (int j = 0; j < 4; ++j)
        Xt[tn][to * 4 + j] = fmaxf(Xt[tn][to * 4 + j], Xt[tn + s][to * 4 + j]);
    __syncthreads();
  }
  if (tn == 0)
    for (int j = 0; j < 4; ++j) {
      int o = o0 + to * 4 + j;
      partial[((long)b * nNT + nt) * O + o] = Xt[0][to * 4 + j];
    }
}

__global__ void gemm_colmax_kernel(const float* __restrict__ X, int xStrideB, int C, int Np,
                                   const float* __restrict__ W, int ldw, int O,
                                   const float* __restrict__ g, const float* __restrict__ bb,
                                   float* __restrict__ partial) {
  __shared__ __align__(16) char smem[8704];
  gemm_colmax_body(X, xStrideB, C, Np, W, ldw, O, g, bb, partial,
                   blockIdx.z, blockIdx.x * 64, blockIdx.y * 64, blockIdx.x, gridDim.x, smem);
}

// ---------------- xmfill body ----------------
__device__ __forceinline__ void xmfill_body(const float* __restrict__ xt1, int N,
                                            const int* __restrict__ fpsI,
                                            const int* __restrict__ idxA, int k, int M,
                                            float* __restrict__ xm, int xe) {
  long t = (long)xe * 256 + threadIdx.x;
  int i = (int)(t % M);
  int c = (int)((t / M) % 128);
  int b = (int)(t / ((long)128 * M));
  const float* xb = xt1 + (long)b * 128 * N + (long)c * N;
  float* xmB = xm + (long)b * 256 * M;
  xmB[(long)c * M + i] = xb[fpsI[(long)b * M + i]];
  const int* ip = idxA + ((long)b * M + i) * k;
  float best = -INFINITY;
  for (int kk = 0; kk < k; ++kk) best = fmaxf(best, xb[ip[kk]]);
  xmB[(long)(128 + c) * M + i] = best;
}

// ---------------- FPS body, RANGE-split (R18: SoA px/py/pz, 26.8KB) ----------------
template <int FIRST, int LAST>
__device__ __forceinline__ void fps_body_rg(const float* __restrict__ xyz, int N, int M,
                                            int it0, int it1,
                                            int* __restrict__ fpsIdx, float* __restrict__ node1,
                                            float* __restrict__ distSv, int* __restrict__ lastSv,
                                            int b, char* smem) {
  #pragma clang fp contract(off)
  float* px = (float*)smem;                    // [2048] @ 0
  float* py = (float*)(smem + 8192);           // [2048]
  float* pz = (float*)(smem + 16384);          // [2048]
  int*   fidx = (int*)(smem + 24576);          // [512]
  float4* wvc = (float4*)(smem + 26624);       // [2][4] {gmax,x,y,z}
  int*   wis  = (int*)(smem + 26752);          // [2][4]   (total 26784 B)
  int tid = threadIdx.x;
  int lane = tid & 63, w = tid >> 6;
  const float* xb = xyz + (long)b * 3 * N;
  for (int n = tid; n < N; n += 256) {
    int s = ((n & 7) << 8) | (n >> 3);
    px[s] = xb[n]; py[s] = xb[N + n]; pz[s] = xb[2 * N + n];
  }
  if (!FIRST) {
    for (int e = tid; e < it0; e += 256) fidx[e] = fpsIdx[(long)b * M + e];
  }
  __syncthreads();
  float ptx[8], pty[8], ptz[8];
  #pragma unroll
  for (int i = 0; i < 8; ++i) {
    int s = (i << 8) | tid;                    // point tid*8+i
    ptx[i] = px[s]; pty[i] = py[s]; ptz[i] = pz[s];
  }
  float dist[8];
  int last;
  float lx, ly, lz;
  if (FIRST) {
    #pragma unroll
    for (int i = 0; i < 8; ++i) dist[i] = 1e10f;
    last = 0;
    int s0 = 0;
    lx = px[s0]; ly = py[s0]; lz = pz[s0];
  } else {
    #pragma unroll
    for (int i = 0; i < 8; ++i) dist[i] = distSv[(long)b * 2048 + i * 256 + tid];
    last = lastSv[b];
    int sl = ((last & 7) << 8) | (last >> 3);
    lx = px[sl]; ly = py[sl]; lz = pz[sl];
  }
  int base = tid * 8;
  for (int it = it0; it < it1; ++it) {
    int p = it & 1;
    if (tid == 0) fidx[it] = last;
    float best = -INFINITY; int bi = N;
    #pragma unroll
    for (int i = 0; i < 8; ++i) {
      float dx = ptx[i] - lx, dy = pty[i] - ly, dz = ptz[i] - lz;
      float dx2 = dx * dx, dy2 = dy * dy, dz2 = dz * dz;
      float d = (dx2 + dy2) + dz2;
      float dn = dist[i];
      if (d < dn) dn = d;
      dist[i] = dn;
      if (dn > best) { best = dn; bi = base + i; }
    }
    float cx = ptx[0], cy = pty[0], cz = ptz[0];
    #pragma unroll
    for (int i = 1; i < 8; ++i) {
      bool c = (bi == base + i);
      cx = c ? ptx[i] : cx; cy = c ? pty[i] : cy; cz = c ? ptz[i] : cz;
    }
    float gmax = wave_fmax(best);
    int cand = (best == gmax) ? bi : 0x7FFFFFFF;
    int wbi = wave_imin(cand);
    if (bi == wbi) { wvc[p * 4 + w] = make_float4(gmax, cx, cy, cz); wis[p * 4 + w] = wbi; }
    __syncthreads();
    float4 c0 = wvc[p * 4 + 0], c1 = wvc[p * 4 + 1], c2 = wvc[p * 4 + 2], c3 = wvc[p * 4 + 3];
    int i0 = wis[p * 4 + 0], i1 = wis[p * 4 + 1], i2 = wis[p * 4 + 2], i3 = wis[p * 4 + 3];
    float bv = c0.x; int bbi = i0; lx = c0.y; ly = c0.z; lz = c0.w;
    { bool c = (c1.x > bv) || (c1.x == bv && i1 < bbi);
      bv = c ? c1.x : bv; bbi = c ? i1 : bbi; lx = c ? c1.y : lx; ly = c ? c1.z : ly; lz = c ? c1.w : lz; }
    { bool c = (c2.x > bv) || (c2.x == bv && i2 < bbi);
      bv = c ? c2.x : bv; bbi = c ? i2 : bbi; lx = c ? c2.y : lx; ly = c ? c2.z : ly; lz = c ? c2.w : lz; }
    { bool c = (c3.x > bv) || (c3.x == bv && i3 < bbi);
      bv = c ? c3.x : bv; bbi = c ? i3 : bbi; lx = c ? c3.y : lx; ly = c ? c3.z : ly; lz = c ? c3.w : lz; }
    last = bbi;
    // parity: slot p rewritten only in iter it+2, after barrier it+1 -> safe with 1 barrier
  }
  if (!LAST) {
    for (int e = tid; e < it1; e += 256) {
      if (e >= it0) fpsIdx[(long)b * M + e] = fidx[e];
    }
    #pragma unroll
    for (int i = 0; i < 8; ++i) distSv[(long)b * 2048 + i * 256 + tid] = dist[i];
    if (tid == 0) lastSv[b] = last;
  } else {
    for (int e = tid; e < M; e += 256) fpsIdx[(long)b * M + e] = fidx[e];
    for (int e = tid; e < 3 * M; e += 256) {
      int c = e / M, i = e % M;
      int src = fidx[i];
      int s = ((src & 7) << 8) | (src >> 3);
      node1[(long)b * 3 * M + e] = (c == 0) ? px[s] : (c == 1) ? py[s] : pz[s];
    }
  }
}

// ---------------- fused {fps-range + knn + gemmPS}, 1D grid, fps first ----------------
template <int FIRST, int LAST, bool SQP>
__global__ void knnfpsgemm_kernel(const float* __restrict__ Q, int qStrideB,
                                  const float* __restrict__ Xc, int cStrideB,
                                  int C, int Mq, int N, int k, int* __restrict__ idxOut,
                                  const float* __restrict__ W, int ldw, int O,
                                  float* __restrict__ Pt, float* __restrict__ St,
                                  const float* __restrict__ xyz, int Mf, int it0, int it1,
                                  int* __restrict__ fpsIdx, float* __restrict__ node1,
                                  float* __restrict__ distSv, int* __restrict__ lastSv,
                                  const float* __restrict__ sqPre,
                                  int nQblk, int nGblk, int nB) {
  __shared__ __align__(16) char smem[32768];
  int bid = blockIdx.x;
  if (bid < nB) {
    __builtin_amdgcn_s_setprio(1);
    fps_body_rg<FIRST, LAST>(xyz, N, Mf, it0, it1, fpsIdx, node1, distSv, lastSv, bid, smem);
    __builtin_amdgcn_s_setprio(0);
  } else if (bid < nB + nB * nQblk) {
    int e = bid - nB;
    knn4_body<8, SQP>(Q, qStrideB, Xc, cStrideB, C, Mq, N, k, idxOut, sqPre,
                      e / nQblk, (e % nQblk) * 4, smem);
  } else {
    int e = bid - nB - nB * nQblk;
    gemmPS_body(Xc, cStrideB, C, N, W, ldw, O, Pt, St,
                e / nGblk, (e % nGblk) * 64, 0, smem);
  }
}

// ---------------- fused {ecfinish1 (+sq emit) + fps mid-range}, fps blocks first --------
__global__ void ecfps_kernel(const float* __restrict__ Pt, const float* __restrict__ St,
                             const int* __restrict__ idx, int k, int O, int Np,
                             const float* __restrict__ g, const float* __restrict__ bb,
                             float* __restrict__ outp, long oStrideB,
                             float* __restrict__ sqOut,
                             const float* __restrict__ xyz, int N, int Mf, int it0, int it1,
                             int* __restrict__ fpsIdx, float* __restrict__ node1,
                             float* __restrict__ distSv, int* __restrict__ lastSv,
                             int nEperB, int nB) {
  __shared__ __align__(16) char smem[26784];
  int bid = blockIdx.x;
  if (bid < nB) {
    __builtin_amdgcn_s_setprio(1);
    fps_body_rg<0, 0>(xyz, N, Mf, it0, it1, fpsIdx, node1, distSv, lastSv, bid, smem);
    __builtin_amdgcn_s_setprio(0);
  } else {
    int e = bid - nB;
    ecfinish_body64(Pt, St, idx, k, O, Np, g, bb, outp, oStrideB, sqOut,
                    e / nEperB, e % nEperB);
  }
}

// ---------------- fused {ecfinish2 + agg-knn}, striped (agg every 5th bid) ----------------
__global__ void ecfagg_kernel(const float* __restrict__ Pt, const float* __restrict__ St,
                              const int* __restrict__ idxS2, int k2, int O2, int Np2,
                              const float* __restrict__ g2, const float* __restrict__ b2,
                              float* __restrict__ out2, long oStrideB2,
                              const float* __restrict__ Qn, int qStrideB,
                              const float* __restrict__ Xc, int cStrideB,
                              int Cq, int Mq, int Nc, int kq, int* __restrict__ idxAgg,
                              int nQblk, int nEperB) {
  __shared__ __align__(16) char smem[32768];
  int bid = blockIdx.x;
  if (bid % 5 == 0) {
    int a = bid / 5;                       // [0, 1024)
    knn4_body<8, false>(Qn, qStrideB, Xc, cStrideB, Cq, Mq, Nc, kq, idxAgg, nullptr,
                        a / nQblk, (a % nQblk) * 4, smem);
  } else {
    int e = bid - bid / 5 - 1;             // [0, 4096) sequential
    ecfinish_body64(Pt, St, idxS2, k2, O2, Np2, g2, b2, out2, oStrideB2, nullptr,
                    e / nEperB, e % nEperB);
  }
}

// ---------------- fused {gemm_colmaxA + xmfill}, striped (xmfill every 3rd bid) ----------------
__global__ void colmaxxm_kernel(const float* __restrict__ X, int xStrideB, int C, int Np,
                                const float* __restrict__ W, int ldw, int O,
                                const float* __restrict__ g, const float* __restrict__ bb,
                                float* __restrict__ partial, int nNT, int nOT,
                                const float* __restrict__ xt1, int N,
                                const int* __restrict__ fpsI, const int* __restrict__ idxA,
                                int kq, int M, float* __restrict__ xm) {
  __shared__ __align__(16) char smem[8704];
  int bid = blockIdx.x;
  if (bid % 3 == 0) {
    xmfill_body(xt1, N, fpsI, idxA, kq, M, xm, bid / 3);       // [0, 2048)
  } else {
    int e = bid - bid / 3 - 1;                                  // [0, 4096)
    int per = nNT * nOT;
    int b = e / per, r = e % per;
    int nt = r % nNT, ot = r / nNT;
    gemm_colmax_body(X, xStrideB, C, Np, W, ldw, O, g, bb, partial,
                     b, nt * 64, ot * 64, nt, nNT, smem);
  }
}

// ---------------- fused {knn<2> + gemmPS} for stages 3/4 ----------------
__global__ void knngemm_kernel(const float* __restrict__ Xin, int xStrideB,
                               int C, int Mq, int N, int k, int* __restrict__ idxOut,
                               const float* __restrict__ W, int ldw, int O,
                               float* __restrict__ Pt, float* __restrict__ St,
                               int nQblk, int nGn, int nGo, int nB) {
  __shared__ __align__(16) char smem[13056];
  int bid = blockIdx.x;
  if (bid < nB * nQblk) {
    knn4_body<2, false>(Xin, xStrideB, Xin, xStrideB, C, Mq, N, k, idxOut, nullptr,
                        bid / nQblk, (bid % nQblk) * 4, smem);
  } else {
    int e = bid - nB * nQblk;
    int per = nGn * nGo;
    int b = e / per, r = e % per;
    int nt = r % nGn, ot = r / nGn;
    gemmPS_body(Xin, xStrideB, C, N, W, ldw, O, Pt, St, b, nt * 64, ot * 64, smem);
  }
}

// ---------------- head, R18->R19: batched over b to kill cross-XCD weight re-fetch.
// R18's per-batch blocks each streamed the full 4MB Wl1 -> 19.3MB HBM, latency-bound
// at 8 blocks. Now: headv computes v[b] to ws; headl1 (64 blks x 8 outs) loads each
// Wl1 row ONCE into registers and loops the 8 batches (vws L2-hot); headl2 same for
// Wl2; headl3 finishes. Per-(b,o) fmaf chain + wave_fadd tree identical -> logits
// bit-identical (absmax stays 0.0).
__global__ void headv_kernel(const float* __restrict__ partA, int NTa,
                             const float* __restrict__ partB, int NTb,
                             float* __restrict__ vws) {
  int b = blockIdx.x, tid = threadIdx.x;
  for (int o = tid; o < 1024; o += 256) {
    float m = -INFINITY;
    for (int t = 0; t < NTa; ++t) m = fmaxf(m, partA[((long)b * NTa + t) * 1024 + o]);
    vws[(long)b * 2048 + o] = m;
    float m2 = -INFINITY;
    for (int t = 0; t < NTb; ++t) m2 = fmaxf(m2, partB[((long)b * NTb + t) * 1024 + o]);
    vws[(long)b * 2048 + 1024 + o] = m2;
  }
}

__global__ void headl1_kernel(const float* __restrict__ vws,
                              const float* __restrict__ Wl1, const float* __restrict__ g6,
                              const float* __restrict__ b6, float* __restrict__ h1ws) {
  int tid = threadIdx.x;
  int lane = tid & 63, w = tid >> 6;
  int o0 = blockIdx.x * 8;
  for (int oo = w; oo < 8; oo += 4) {
    int o = o0 + oo;
    const float4* wr = (const float4*)(Wl1 + (long)o * 2048);
    float4 w4[8];
    #pragma unroll
    for (int j = 0; j < 8; ++j) w4[j] = wr[lane + 64 * j];
    float gs = g6[o] * BN_SCALE, bo = b6[o];
    for (int b = 0; b < 8; ++b) {
      const float4* vp = (const float4*)(vws + (long)b * 2048);
      float s = 0.f;
      #pragma unroll
      for (int j = 0; j < 8; ++j) {
        float4 v4 = vp[lane + 64 * j];
        s = fmaf(w4[j].x, v4.x, s); s = fmaf(w4[j].y, v4.y, s);
        s = fmaf(w4[j].z, v4.z, s); s = fmaf(w4[j].w, v4.w, s);
      }
      float t = wave_fadd(s);
      if (lane == 0) {
        float h = t * gs + bo;
        h1ws[(long)b * 512 + o] = h >= 0.f ? h : 0.2f * h;
      }
    }
  }
}

__global__ void headl2_kernel(const float* __restrict__ h1ws,
                              const float* __restrict__ Wl2, const float* __restrict__ bl2,
                              const float* __restrict__ g7, const float* __restrict__ b7,
                              float* __restrict__ h2ws) {
  int tid = threadIdx.x;
  int lane = tid & 63, w = tid >> 6;
  int o0 = blockIdx.x * 8;
  for (int oo = w; oo < 8; oo += 4) {
    int o = o0 + oo;
    const float4* wr = (const float4*)(Wl2 + (long)o * 512);
    float4 w4[2];
    #pragma unroll
    for (int j = 0; j < 2; ++j) w4[j] = wr[lane + 64 * j];
    float bl = bl2[o], gs = g7[o] * BN_SCALE, bo = b7[o];
    for (int b = 0; b < 8; ++b) {
      const float4* hp = (const float4*)(h1ws + (long)b * 512);
      float s = 0.f;
      #pragma unroll
      for (int j = 0; j < 2; ++j) {
        float4 v4 = hp[lane + 64 * j];
        s = fmaf(w4[j].x, v4.x, s); s = fmaf(w4[j].y, v4.y, s);
        s = fmaf(w4[j].z, v4.z, s); s = fmaf(w4[j].w, v4.w, s);
      }
      float t = wave_fadd(s);
      if (lane == 0) {
        float sb = t + bl;
        float h = sb * gs + bo;
        h2ws[(long)b * 256 + o] = h >= 0.f ? h : 0.2f * h;
      }
    }
  }
}

__global__ void headl3_kernel(const float* __restrict__ h2ws,
                              const float* __restrict__ Wl3, const float* __restrict__ bl3,
                              float* __restrict__ logits) {
  int b = blockIdx.x, tid = threadIdx.x;
  int lane = tid & 63, w = tid >> 6;
  const float4* hp = (const float4*)(h2ws + (long)b * 256);
  float4 v4 = hp[lane];
  for (int o = w; o < 40; o += 4) {
    const float4* wr = (const float4*)(Wl3 + (long)o * 256);
    float4 w4 = wr[lane];
    float s = fmaf(w4.x, v4.x, 0.f);
    s = fmaf(w4.y, v4.y, s); s = fmaf(w4.z, v4.z, s); s = fmaf(w4.w, v4.w, s);
    float t = wave_fadd(s);
    if (lane == 0) logits[(long)b * 40 + o] = t + bl3[o];
  }
}

extern "C" void kernel_launch(void* const* d_in, const int* in_sizes, int n_in,
                              void* d_out, int out_size, void* d_ws, size_t ws_size,
                              hipStream_t stream) {
  const float* x   = (const float*)d_in[0];
  const float* W1  = (const float*)d_in[1];
  const float* g1  = (const float*)d_in[2];
  const float* b1  = (const float*)d_in[3];
  const float* W2  = (const float*)d_in[4];
  const float* g2  = (const float*)d_in[5];
  const float* b2  = (const float*)d_in[6];
  const float* W2m = (const float*)d_in[7];
  const float* g2m = (const float*)d_in[8];
  const float* b2m = (const float*)d_in[9];
  const float* W3  = (const float*)d_in[10];
  const float* g3  = (const float*)d_in[11];
  const float* b3  = (const float*)d_in[12];
  const float* W4  = (const float*)d_in[13];
  const float* g4  = (const float*)d_in[14];
  const float* b4  = (const float*)d_in[15];
  const float* W5  = (const float*)d_in[16];
  const float* g5  = (const float*)d_in[17];
  const float* b5  = (const float*)d_in[18];
  const float* Wl1 = (const float*)d_in[19];
  const float* g6  = (const float*)d_in[20];
  const float* b6  = (const float*)d_in[21];
  const float* Wl2 = (const float*)d_in[22];
  const float* bl2 = (const float*)d_in[23];
  const float* g7  = (const float*)d_in[24];
  const float* b7  = (const float*)d_in[25];
  const float* Wl3 = (const float*)d_in[26];
  const float* bl3 = (const float*)d_in[27];
  float* outF = (float*)d_out;

  const int B = 8, N = 2048, K = 20, M = 512, K2 = 10;

  float* ws    = (float*)d_ws;
  float* xt1   = ws;                               // (B,128,N)
  float* xm    = xt1 + (size_t)B * 128 * N;        // (B,256,M)
  float* xc    = xm  + (size_t)B * 256 * M;        // (B,512,M)
  float* Pt    = xc  + (size_t)B * 512 * M;        // max(B*N*64, B*M*256)
  float* St    = Pt  + (size_t)B * N * 64;
  float* partA = St  + (size_t)B * N * 64;         // (B,32,1024)
  float* partB = partA + (size_t)B * 32 * 1024;    // (B,8,1024)
  int*   idxK  = (int*)(partB + (size_t)B * 8 * 1024);  // (B,N,K)
  int*   fpsI  = idxK + (size_t)B * N * K;         // (B,M)
  float* fpsDist = (float*)(fpsI + (size_t)B * M); // (B,2048) fps checkpoint dists
  int*   fpsLast = (int*)(fpsDist + (size_t)B * 2048);  // (B)
  int*   idxAgg  = fpsLast + 64;                   // (B,M,K) aggregate-knn indices
  float* sqS2    = (float*)(idxAgg + (size_t)B * M * K); // (B,N) stage-2 candidate norms
  float* vws     = sqS2 + (size_t)B * N;           // (B,2048) head v
  float* h1ws    = vws + (size_t)B * 2048;         // (B,512)
  float* h2ws    = h1ws + (size_t)B * 512;         // (B,256)

  float* logits = outF;        // (B,40)
  float* node1  = outF + 320;  // (B,3,M)

  dim3 t256(256);
  const int nQblk = N / 4;     // 512 knn query-blocks per batch (N-point knn)
  const int nGblk = N / 64;    // 32 gemmPS n-tiles per batch (stage 1/2)
  const int nFused = B + B * nQblk + B * nGblk;
  const int nQa = M / 4;       // 128 agg/stage3/4 knn query-blocks per batch
  const int IT1 = 208, IT2 = 304;   // fps phase boundaries

  // ---- stage 1 FUSED: fps [0,208) + knn(xyz) + gemmPS1 (all depend only on x)
  knnfpsgemm_kernel<1, 0, false><<<dim3(nFused), t256, 0, stream>>>(
      x, 3 * N, x, 3 * N, 3, N, N, K, idxK,
      W1, 6, 64, Pt, St,
      x, M, 0, IT1, fpsI, node1, fpsDist, fpsLast, nullptr, nQblk, nGblk, B);

  // ---- ecfinish1 (+sq emit for stage-2 knn) FUSED with fps [208,304)
  ecfps_kernel<<<dim3(B + B * (N / 4)), t256, 0, stream>>>(
      Pt, St, idxK, K, 64, N, g1, b1, xt1, (long)128 * N, sqS2,
      x, N, M, IT1, IT2, fpsI, node1, fpsDist, fpsLast, N / 4, B);

  // ---- stage 2 FUSED: fps [304,512) + knn(x1, precomputed sq) + gemmPS2
  knnfpsgemm_kernel<0, 1, true><<<dim3(nFused), t256, 0, stream>>>(
      xt1, 128 * N, xt1, 128 * N, 64, N, N, K, idxK,
      W2, 128, 64, Pt, St,
      x, M, IT2, M, fpsI, node1, fpsDist, fpsLast, sqS2, nQblk, nGblk, B);

  // ---- FUSED: ecfinish2 (gather-bound) + aggregate-knn (VALU-latency-bound), striped
  ecfagg_kernel<<<dim3(B * nQa + B * (N / 4)), t256, 0, stream>>>(
      Pt, St, idxK, K, 64, N, g2, b2, xt1 + (size_t)64 * N, (long)128 * N,
      node1, 3 * M, x, 3 * N, 3, M, N, K, idxAgg, nQa, N / 4);

  // ---- FUSED: gemm_colmaxA + xmfill, striped every-3rd
  colmaxxm_kernel<<<dim3((B * 128 * M) / 256 + B * 32 * 16), t256, 0, stream>>>(
      xt1, 128 * N, 128, N, W2m, 128, 1024, g2m, b2m, partA, 32, 16,
      xt1, N, fpsI, idxAgg, K, M, xm);

  // ---- stage 3 FUSED: knn(xm) + gemmPS3
  knngemm_kernel<<<dim3(B * nQa + B * (M / 64) * (256 / 64)), t256, 0, stream>>>(
      xm, 256 * M, 256, M, M, K2, idxK, W3, 512, 256, Pt, St, nQa, M / 64, 256 / 64, B);
  ecfinish_kernel<<<dim3(M, B), dim3(256, 1), 0, stream>>>(Pt, St, idxK, K2, 256, M, g3, b3, xc, (long)512 * M);

  // ---- stage 4 FUSED: knn(x3) + gemmPS4
  knngemm_kernel<<<dim3(B * nQa + B * (M / 64) * (256 / 64)), t256, 0, stream>>>(
      xc, 512 * M, 256, M, M, K2, idxK, W4, 512, 256, Pt, St, nQa, M / 64, 256 / 64, B);
  ecfinish_kernel<<<dim3(M, B), dim3(256, 1), 0, stream>>>(Pt, St, idxK, K2, 256, M, g4, b4,
                                                           xc + (size_t)256 * M, (long)512 * M);

  // ---- vs partials
  gemm_colmax_kernel<<<dim3(M / 64, 1024 / 64, B), t256, 0, stream>>>(xc, 512 * M, 512, M, W5, 512, 1024,
                                                                      g5, b5, partB);

  // ---- head, batched over b (weights fetched once)
  headv_kernel<<<dim3(B), t256, 0, stream>>>(partA, N / 64, partB, M / 64, vws);
  headl1_kernel<<<dim3(64), t256, 0, stream>>>(vws, Wl1, g6, b6, h1ws);
  headl2_kernel<<<dim3(32), t256, 0, stream>>>(h1ws, Wl2, bl2, g7, b7, h2ws);
  headl3_kernel<<<dim3(B), t256, 0, stream>>>(h2ws, Wl3, bl3, logits);
}

// Round 20
// 970.231 us; speedup vs baseline: 1.3296x; 1.0147x over previous
//
#include <hip/hip_runtime.h>

#define BN_SCALE 0.9999950000374997f  // 1/sqrt(1+1e-5)

// ---- DPP full-wave reductions (validated in fps/knn since R2/R4) ----
template <int CTRL>
__device__ __forceinline__ float dpp_fmax_step(float v) {
  int xi = __builtin_bit_cast(int, v);
  int ti = __builtin_amdgcn_update_dpp(xi, xi, CTRL, 0xf, 0xf, false);  // invalid lanes -> old(=v)
  return fmaxf(v, __builtin_bit_cast(float, ti));
}
template <int CTRL>
__device__ __forceinline__ int dpp_imin_step(int v) {
  int t = __builtin_amdgcn_update_dpp(v, v, CTRL, 0xf, 0xf, false);    // invalid lanes -> old(=v)
  return (t < v) ? t : v;
}
template <int CTRL>
__device__ __forceinline__ float dpp_fadd_step(float v) {
  // bound_ctrl=true: invalid lanes contribute 0 (required for sums)
  int ti = __builtin_amdgcn_update_dpp(0, __builtin_bit_cast(int, v), CTRL, 0xf, 0xf, true);
  return v + __builtin_bit_cast(float, ti);
}
__device__ __forceinline__ float wave_fmax(float v) {
  v = dpp_fmax_step<0x111>(v);
  v = dpp_fmax_step<0x112>(v);
  v = dpp_fmax_step<0x114>(v);
  v = dpp_fmax_step<0x118>(v);
  v = dpp_fmax_step<0x142>(v);
  v = dpp_fmax_step<0x143>(v);
  return __builtin_bit_cast(float, __builtin_amdgcn_readlane(__builtin_bit_cast(int, v), 63));
}
__device__ __forceinline__ int wave_imin(int v) {
  v = dpp_imin_step<0x111>(v);
  v = dpp_imin_step<0x112>(v);
  v = dpp_imin_step<0x114>(v);
  v = dpp_imin_step<0x118>(v);
  v = dpp_imin_step<0x142>(v);
  v = dpp_imin_step<0x143>(v);
  return __builtin_amdgcn_readlane(v, 63);
}
__device__ __forceinline__ float wave_fadd(float v) {
  v = dpp_fadd_step<0x111>(v);
  v = dpp_fadd_step<0x112>(v);
  v = dpp_fadd_step<0x114>(v);
  v = dpp_fadd_step<0x118>(v);
  v = dpp_fadd_step<0x142>(v);
  v = dpp_fadd_step<0x143>(v);
  return __builtin_bit_cast(float, __builtin_amdgcn_readlane(__builtin_bit_cast(int, v), 63));
}

// ---------------- knn4 body (R18: persistent group bests) ----------------
template <int R, bool SQPRE>
__device__ __forceinline__ void knn4_body(const float* __restrict__ Q, int qStrideB,
                                          const float* __restrict__ Xc, int cStrideB,
                                          int C, int M, int N, int k, int* __restrict__ idxOut,
                                          const float* __restrict__ sqPre,
                                          int b, int q0, char* smem) {
  constexpr int NR = 4 * R;
  float (*negd)[R * 256] = (float (*)[R * 256])smem;
  int tid = threadIdx.x;
  const float* qb = Q + (long)b * qStrideB + q0;
  const float* cb = Xc + (long)b * cStrideB;
  if constexpr (R % 4 == 0) {
    constexpr int H = R / 4;
    float d0[R], d1[R], d2[R], d3[R], sq[R];
    #pragma unroll
    for (int i = 0; i < R; ++i) { d0[i] = d1[i] = d2[i] = d3[i] = sq[i] = 0.f; }
    for (int c = 0; c < C; ++c) {
      float4 q4 = *(const float4*)(qb + (long)c * M);  // uniform -> scalar load
      const float4* pc4 = (const float4*)(cb + (long)c * N);
      #pragma unroll
      for (int h = 0; h < H; ++h) {
        float4 xv = pc4[tid + 256 * h];                // 16B/lane coalesced
        if (!SQPRE) {
          sq[4 * h + 0] = fmaf(xv.x, xv.x, sq[4 * h + 0]);
          sq[4 * h + 1] = fmaf(xv.y, xv.y, sq[4 * h + 1]);
          sq[4 * h + 2] = fmaf(xv.z, xv.z, sq[4 * h + 2]);
          sq[4 * h + 3] = fmaf(xv.w, xv.w, sq[4 * h + 3]);
        }
        d0[4 * h + 0] = fmaf(q4.x, xv.x, d0[4 * h + 0]);
        d0[4 * h + 1] = fmaf(q4.x, xv.y, d0[4 * h + 1]);
        d0[4 * h + 2] = fmaf(q4.x, xv.z, d0[4 * h + 2]);
        d0[4 * h + 3] = fmaf(q4.x, xv.w, d0[4 * h + 3]);
        d1[4 * h + 0] = fmaf(q4.y, xv.x, d1[4 * h + 0]);
        d1[4 * h + 1] = fmaf(q4.y, xv.y, d1[4 * h + 1]);
        d1[4 * h + 2] = fmaf(q4.y, xv.z, d1[4 * h + 2]);
        d1[4 * h + 3] = fmaf(q4.y, xv.w, d1[4 * h + 3]);
        d2[4 * h + 0] = fmaf(q4.z, xv.x, d2[4 * h + 0]);
        d2[4 * h + 1] = fmaf(q4.z, xv.y, d2[4 * h + 1]);
        d2[4 * h + 2] = fmaf(q4.z, xv.z, d2[4 * h + 2]);
        d2[4 * h + 3] = fmaf(q4.z, xv.w, d2[4 * h + 3]);
        d3[4 * h + 0] = fmaf(q4.w, xv.x, d3[4 * h + 0]);
        d3[4 * h + 1] = fmaf(q4.w, xv.y, d3[4 * h + 1]);
        d3[4 * h + 2] = fmaf(q4.w, xv.z, d3[4 * h + 2]);
        d3[4 * h + 3] = fmaf(q4.w, xv.w, d3[4 * h + 3]);
      }
    }
    #pragma unroll
    for (int h = 0; h < H; ++h) {
      float4 s4;
      if (SQPRE) {
        s4 = ((const float4*)(sqPre + (long)b * N))[tid + 256 * h];
      } else {
        s4 = make_float4(sq[4 * h], sq[4 * h + 1], sq[4 * h + 2], sq[4 * h + 3]);
      }
      ((float4*)negd[0])[tid + 256 * h] =
          make_float4(2.f * d0[4 * h] - s4.x, 2.f * d0[4 * h + 1] - s4.y,
                      2.f * d0[4 * h + 2] - s4.z, 2.f * d0[4 * h + 3] - s4.w);
      ((float4*)negd[1])[tid + 256 * h] =
          make_float4(2.f * d1[4 * h] - s4.x, 2.f * d1[4 * h + 1] - s4.y,
                      2.f * d1[4 * h + 2] - s4.z, 2.f * d1[4 * h + 3] - s4.w);
      ((float4*)negd[2])[tid + 256 * h] =
          make_float4(2.f * d2[4 * h] - s4.x, 2.f * d2[4 * h + 1] - s4.y,
                      2.f * d2[4 * h + 2] - s4.z, 2.f * d2[4 * h + 3] - s4.w);
      ((float4*)negd[3])[tid + 256 * h] =
          make_float4(2.f * d3[4 * h] - s4.x, 2.f * d3[4 * h + 1] - s4.y,
                      2.f * d3[4 * h + 2] - s4.z, 2.f * d3[4 * h + 3] - s4.w);
    }
  } else {
    float d0[R], d1[R], d2[R], d3[R], sq[R];
    #pragma unroll
    for (int i = 0; i < R; ++i) { d0[i] = d1[i] = d2[i] = d3[i] = sq[i] = 0.f; }
    for (int c = 0; c < C; ++c) {
      float4 q4 = *(const float4*)(qb + (long)c * M);
      const float* pc = cb + (long)c * N;
      #pragma unroll
      for (int i = 0; i < R; ++i) {
        float xv = pc[tid + 256 * i];
        sq[i] = fmaf(xv, xv, sq[i]);
        d0[i] = fmaf(q4.x, xv, d0[i]);
        d1[i] = fmaf(q4.y, xv, d1[i]);
        d2[i] = fmaf(q4.z, xv, d2[i]);
        d3[i] = fmaf(q4.w, xv, d3[i]);
      }
    }
    #pragma unroll
    for (int i = 0; i < R; ++i) {
      int m = tid + 256 * i;
      negd[0][m] = 2.f * d0[i] - sq[i];
      negd[1][m] = 2.f * d1[i] - sq[i];
      negd[2][m] = 2.f * d2[i] - sq[i];
      negd[3][m] = 2.f * d3[i] - sq[i];
    }
  }
  __syncthreads();
  int lane = tid & 63, w = tid >> 6;
  const float* row = negd[w];
  int* outp = idxOut + ((long)b * M + (q0 + w)) * k;
  float v[NR];
  #pragma unroll
  for (int i = 0; i < NR; ++i) v[i] = row[lane + 64 * i];
  constexpr int G = NR / 4;
  float bv[G]; int br[G];
  #pragma unroll
  for (int g = 0; g < G; ++g) {
    float v0 = v[4 * g]; int r0 = 4 * g;
    #pragma unroll
    for (int j = 1; j < 4; ++j) {
      bool c = v[4 * g + j] > v0;
      v0 = c ? v[4 * g + j] : v0;
      r0 = c ? (4 * g + j) : r0;
    }
    bv[g] = v0; br[g] = r0;
  }
  for (int kk = 0; kk < k; ++kk) {
    float mv[G]; int mi[G];
    #pragma unroll
    for (int g = 0; g < G; ++g) { mv[g] = bv[g]; mi[g] = br[g]; }
    #pragma unroll
    for (int s = G >> 1; s >= 1; s >>= 1) {
      #pragma unroll
      for (int i = 0; i < s; ++i) {
        bool c = mv[2 * i] >= mv[2 * i + 1];
        mv[i] = c ? mv[2 * i] : mv[2 * i + 1];
        mi[i] = c ? mi[2 * i] : mi[2 * i + 1];
      }
    }
    float best = mv[0]; int ib = mi[0];
    int bi = (best > -INFINITY) ? (lane + (ib << 6)) : N;
    float gmax = wave_fmax(best);
    int cand = (best == gmax) ? bi : 0x7FFFFFFF;
    int big = wave_imin(cand);
    if (lane == 0) outp[kk] = big;
    int ri = big >> 6;                      // uniform
    bool mine = (lane == (big & 63));
    #pragma unroll
    for (int i = 0; i < NR; ++i)
      if (i == ri) v[i] = mine ? -INFINITY : v[i];
    int gi = ri >> 2;
    #pragma unroll
    for (int g = 0; g < G; ++g) {
      if (g == gi) {
        float v0 = v[4 * g]; int r0 = 4 * g;
        #pragma unroll
        for (int j = 1; j < 4; ++j) {
          bool c = v[4 * g + j] > v0;
          v0 = c ? v[4 * g + j] : v0;
          r0 = c ? (4 * g + j) : r0;
        }
        bv[g] = v0; br[g] = r0;
      }
    }
  }
}

template <int R>
__global__ void knn4_kernel(const float* __restrict__ Q, int qStrideB,
                            const float* __restrict__ Xc, int cStrideB,
                            int C, int M, int N, int k, int* __restrict__ idxOut) {
  __shared__ __align__(16) char smem[R * 256 * 4 * 4];
  knn4_body<R, false>(Q, qStrideB, Xc, cStrideB, C, M, N, k, idxOut, nullptr,
                      blockIdx.y, blockIdx.x * 4, smem);
}

// ---------------- gemmPS body (R17: contiguous sub-tiles, float4 LDS reads) ----------------
__device__ __forceinline__ void gemmPS_body(const float* __restrict__ X, int xStrideB, int C, int Np,
                                            const float* __restrict__ W, int ldw, int O,
                                            float* __restrict__ PtT, float* __restrict__ StT,
                                            int b, int n0, int o0, char* smem) {
  float (*Wp)[68] = (float (*)[68])smem;             // 4352 B
  float (*Ws)[68] = (float (*)[68])(smem + 4352);    // 4352 B
  float (*Xt)[68] = (float (*)[68])(smem + 8704);    // 4352 B (13056 total)
  int tid = threadIdx.x;
  int to = tid % 16, tn = tid / 16;
  float accP[4][4] = {}, accS[4][4] = {};
  for (int c0 = 0; c0 < C; c0 += 16) {
    for (int e = tid; e < 16 * 64; e += 256) {
      int oo = e / 16, kk = e % 16;
      int c = c0 + kk, o = o0 + oo;
      bool ok = (c < C && o < O);
      Wp[kk][oo] = ok ? W[(long)o * ldw + c] : 0.f;
      Ws[kk][oo] = ok ? W[(long)o * ldw + C + c] : 0.f;
    }
    for (int e = tid; e < 16 * 64; e += 256) {
      int kk = e / 64, nn = e % 64;
      int c = c0 + kk, n = n0 + nn;
      Xt[kk][nn] = (c < C && n < Np) ? X[(long)b * xStrideB + (long)c * Np + n] : 0.f;
    }
    __syncthreads();
    for (int kk = 0; kk < 16; ++kk) {
      float4 xv = *(const float4*)&Xt[kk][tn * 4];
      float4 wp = *(const float4*)&Wp[kk][to * 4];
      float4 ws = *(const float4*)&Ws[kk][to * 4];
      float xs[4] = {xv.x, xv.y, xv.z, xv.w};
      float wps[4] = {wp.x, wp.y, wp.z, wp.w};
      float wss[4] = {ws.x, ws.y, ws.z, ws.w};
      #pragma unroll
      for (int i = 0; i < 4; ++i)
        #pragma unroll
        for (int j = 0; j < 4; ++j) {
          accP[i][j] = fmaf(xs[i], wps[j], accP[i][j]);
          accS[i][j] = fmaf(xs[i], wss[j], accS[i][j]);
        }
    }
    __syncthreads();
  }
  #pragma unroll
  for (int i = 0; i < 4; ++i) {
    int n = n0 + tn * 4 + i;
    if (n >= Np) continue;
    int o = o0 + to * 4;
    if (o + 3 < O) {
      long off = ((long)b * Np + n) * O + o;
      *(float4*)&PtT[off] = make_float4(accP[i][0], accP[i][1], accP[i][2], accP[i][3]);
      *(float4*)&StT[off] = make_float4(accS[i][0], accS[i][1], accS[i][2], accS[i][3]);
    } else {
      for (int j = 0; j < 4; ++j) {
        int oo = o + j;
        if (oo < O) {
          long off = ((long)b * Np + n) * O + oo;
          PtT[off] = accP[i][j];
          StT[off] = accS[i][j];
        }
      }
    }
  }
}

// ---------------- ecfinish body (O=64 flat-256 variant) ----------------
__device__ __forceinline__ void ecfinish_body64(const float* __restrict__ Pt, const float* __restrict__ St,
                                                const int* __restrict__ idx, int k, int O, int Np,
                                                const float* __restrict__ g, const float* __restrict__ bb,
                                                float* __restrict__ outp, long oStrideB,
                                                float* __restrict__ sqOut,
                                                int b, int blk) {
  int tid = threadIdx.x;
  int o = tid & 63;
  int n = blk * 4 + (tid >> 6);
  const float* PtB = Pt + (long)b * Np * O;
  const float* StB = St + (long)b * Np * O;
  const int* ip = idx + ((long)b * Np + n) * k;
  float mx = -INFINITY, mn = INFINITY;
  for (int kk = 0; kk < k; ++kk) {
    float v = PtB[(long)ip[kk] * O + o];
    mx = fmaxf(mx, v); mn = fminf(mn, v);
  }
  float ctrP = PtB[(long)n * O + o];
  float ctrS = StB[(long)n * O + o];
  float gs = g[o] * BN_SCALE;
  float m = (gs >= 0.f) ? mx : mn;
  float h = (ctrS - ctrP + m) * gs + bb[o];
  float out = h >= 0.f ? h : 0.2f * h;
  outp[(long)b * oStrideB + (long)o * Np + n] = out;
  if (sqOut) {
    int obits = __builtin_bit_cast(int, out);
    float acc = 0.f;
    #pragma unroll
    for (int c = 0; c < 64; ++c) {
      float hv = __builtin_bit_cast(float, __builtin_amdgcn_readlane(obits, c));
      acc = fmaf(hv, hv, acc);
    }
    if (o == 0) sqOut[(long)b * Np + n] = acc;
  }
}

__global__ void ecfinish_kernel(const float* __restrict__ Pt, const float* __restrict__ St,
                                const int* __restrict__ idx, int k, int O, int Np,
                                const float* __restrict__ g, const float* __restrict__ bb,
                                float* __restrict__ outp, long oStrideB) {
  int b = blockIdx.y;
  int n = blockIdx.x * blockDim.y + threadIdx.y;
  int o = threadIdx.x;
  const float* PtB = Pt + (long)b * Np * O;
  const float* StB = St + (long)b * Np * O;
  const int* ip = idx + ((long)b * Np + n) * k;
  float mx = -INFINITY, mn = INFINITY;
  for (int kk = 0; kk < k; ++kk) {
    float v = PtB[(long)ip[kk] * O + o];
    mx = fmaxf(mx, v); mn = fminf(mn, v);
  }
  float ctrP = PtB[(long)n * O + o];
  float ctrS = StB[(long)n * O + o];
  float gs = g[o] * BN_SCALE;
  float m = (gs >= 0.f) ? mx : mn;
  float h = (ctrS - ctrP + m) * gs + bb[o];
  outp[(long)b * oStrideB + (long)o * Np + n] = h >= 0.f ? h : 0.2f * h;
}

// ---------------- gemm_colmax body (R17: contiguous sub-tiles, float4 LDS reads) --------
__device__ __forceinline__ void gemm_colmax_body(const float* __restrict__ X, int xStrideB, int C, int Np,
                                                 const float* __restrict__ W, int ldw, int O,
                                                 const float* __restrict__ g, const float* __restrict__ bb,
                                                 float* __restrict__ partial,
                                                 int b, int n0, int o0, int nt, int nNT, char* smem) {
  float (*Wt)[68] = (float (*)[68])smem;            // 4352 B
  float (*Xt)[68] = (float (*)[68])(smem + 4352);   // 4352 B (8704 total)
  int tid = threadIdx.x;
  int to = tid % 16, tn = tid / 16;
  float acc[4][4] = {};
  for (int c0 = 0; c0 < C; c0 += 16) {
    for (int e = tid; e < 16 * 64; e += 256) {
      int oo = e / 16, kk = e % 16;
      int c = c0 + kk, o = o0 + oo;
      Wt[kk][oo] = (c < C && o < O) ? W[(long)o * ldw + c] : 0.f;
    }
    for (int e = tid; e < 16 * 64; e += 256) {
      int kk = e / 64, nn = e % 64;
      int c = c0 + kk, n = n0 + nn;
      Xt[kk][nn] = (c < C && n < Np) ? X[(long)b * xStrideB + (long)c * Np + n] : 0.f;
    }
    __syncthreads();
    for (int kk = 0; kk < 16; ++kk) {
      float4 xv = *(const float4*)&Xt[kk][tn * 4];
      float4 wv = *(const float4*)&Wt[kk][to * 4];
      float xs[4] = {xv.x, xv.y, xv.z, xv.w};
      float wvs[4] = {wv.x, wv.y, wv.z, wv.w};
      #pragma unroll
      for (int i = 0; i < 4; ++i)
        #pragma unroll
        for (int j = 0; j < 4; ++j) acc[i][j] = fmaf(xs[i], wvs[j], acc[i][j]);
    }
    __syncthreads();
  }
  float vm[4];
  #pragma unroll
  for (int j = 0; j < 4; ++j) {
    int o = o0 + to * 4 + j;
    float gs = g[o] * BN_SCALE, bo = bb[o];
    float m = -INFINITY;
    #pragma unroll
    for (int i = 0; i < 4; ++i) {
      float h = acc[i][j] * gs + bo;
      h = h >= 0.f ? h : 0.2f * h;
      m = fmaxf(m, h);
    }
    vm[j] = m;
  }
  #pragma unroll
  for (int j = 0; j < 4; ++j) Xt[tn][to * 4 + j] = vm[j];
  __syncthreads();
  for (int s = 8; s > 0; s >>= 1) {
    if (tn < s)
      for (int j = 0; j < 4; ++j)
        Xt[tn][to * 4 + j] = fmaxf(Xt[tn][to * 4 + j], Xt[tn + s][to * 4 + j]);
    __syncthreads();
  }
  if (tn == 0)
    for (int j = 0; j < 4; ++j) {
      int o = o0 + to * 4 + j;
      partial[((long)b * nNT + nt) * O + o] = Xt[0][to * 4 + j];
    }
}

__global__ void gemm_colmax_kernel(const float* __restrict__ X, int xStrideB, int C, int Np,
                                   const float* __restrict__ W, int ldw, int O,
                                   const float* __restrict__ g, const float* __restrict__ bb,
                                   float* __restrict__ partial) {
  __shared__ __align__(16) char smem[8704];
  gemm_colmax_body(X, xStrideB, C, Np, W, ldw, O, g, bb, partial,
                   blockIdx.z, blockIdx.x * 64, blockIdx.y * 64, blockIdx.x, gridDim.x, smem);
}

// ---------------- xmfill body ----------------
__device__ __forceinline__ void xmfill_body(const float* __restrict__ xt1, int N,
                                            const int* __restrict__ fpsI,
                                            const int* __restrict__ idxA, int k, int M,
                                            float* __restrict__ xm, int xe) {
  long t = (long)xe * 256 + threadIdx.x;
  int i = (int)(t % M);
  int c = (int)((t / M) % 128);
  int b = (int)(t / ((long)128 * M));
  const float* xb = xt1 + (long)b * 128 * N + (long)c * N;
  float* xmB = xm + (long)b * 256 * M;
  xmB[(long)c * M + i] = xb[fpsI[(long)b * M + i]];
  const int* ip = idxA + ((long)b * M + i) * k;
  float best = -INFINITY;
  for (int kk = 0; kk < k; ++kk) best = fmaxf(best, xb[ip[kk]]);
  xmB[(long)(128 + c) * M + i] = best;
}

// ---------------- FPS body, RANGE-split (R19->R20: ballot winner-select).
// wave_imin chain (6 dependent DPP + readlane) replaced by v_cmp ballot + s_ff1 +
// lane==srcLane write — R2's validated pattern. Exact because fps lanes own contiguous
// ascending index ranges [8l, 8l+8): the smallest lane among maxima holds the smallest
// index (within-lane fold already keeps the first/smallest). fidx/node1 bit-identical.
template <int FIRST, int LAST>
__device__ __forceinline__ void fps_body_rg(const float* __restrict__ xyz, int N, int M,
                                            int it0, int it1,
                                            int* __restrict__ fpsIdx, float* __restrict__ node1,
                                            float* __restrict__ distSv, int* __restrict__ lastSv,
                                            int b, char* smem) {
  #pragma clang fp contract(off)
  float* px = (float*)smem;                    // [2048] @ 0
  float* py = (float*)(smem + 8192);           // [2048]
  float* pz = (float*)(smem + 16384);          // [2048]
  int*   fidx = (int*)(smem + 24576);          // [512]
  float4* wvc = (float4*)(smem + 26624);       // [2][4] {gmax,x,y,z}
  int*   wis  = (int*)(smem + 26752);          // [2][4]   (total 26784 B)
  int tid = threadIdx.x;
  int lane = tid & 63, w = tid >> 6;
  const float* xb = xyz + (long)b * 3 * N;
  for (int n = tid; n < N; n += 256) {
    int s = ((n & 7) << 8) | (n >> 3);
    px[s] = xb[n]; py[s] = xb[N + n]; pz[s] = xb[2 * N + n];
  }
  if (!FIRST) {
    for (int e = tid; e < it0; e += 256) fidx[e] = fpsIdx[(long)b * M + e];
  }
  __syncthreads();
  float ptx[8], pty[8], ptz[8];
  #pragma unroll
  for (int i = 0; i < 8; ++i) {
    int s = (i << 8) | tid;                    // point tid*8+i
    ptx[i] = px[s]; pty[i] = py[s]; ptz[i] = pz[s];
  }
  float dist[8];
  int last;
  float lx, ly, lz;
  if (FIRST) {
    #pragma unroll
    for (int i = 0; i < 8; ++i) dist[i] = 1e10f;
    last = 0;
    int s0 = 0;
    lx = px[s0]; ly = py[s0]; lz = pz[s0];
  } else {
    #pragma unroll
    for (int i = 0; i < 8; ++i) dist[i] = distSv[(long)b * 2048 + i * 256 + tid];
    last = lastSv[b];
    int sl = ((last & 7) << 8) | (last >> 3);
    lx = px[sl]; ly = py[sl]; lz = pz[sl];
  }
  int base = tid * 8;
  for (int it = it0; it < it1; ++it) {
    int p = it & 1;
    if (tid == 0) fidx[it] = last;
    float best = -INFINITY; int bi = N;
    #pragma unroll
    for (int i = 0; i < 8; ++i) {
      float dx = ptx[i] - lx, dy = pty[i] - ly, dz = ptz[i] - lz;
      float dx2 = dx * dx, dy2 = dy * dy, dz2 = dz * dz;
      float d = (dx2 + dy2) + dz2;
      float dn = dist[i];
      if (d < dn) dn = d;
      dist[i] = dn;
      if (dn > best) { best = dn; bi = base + i; }  // ascending -> first max in lane kept
    }
    float cx = ptx[0], cy = pty[0], cz = ptz[0];
    #pragma unroll
    for (int i = 1; i < 8; ++i) {
      bool c = (bi == base + i);
      cx = c ? ptx[i] : cx; cy = c ? pty[i] : cy; cz = c ? ptz[i] : cz;
    }
    float gmax = wave_fmax(best);
    unsigned long long mm = __ballot(best == gmax);
    int srcLane = (int)(__ffsll((long long)mm) - 1);   // min lane = min index (contiguous ranges)
    if (lane == srcLane) { wvc[p * 4 + w] = make_float4(gmax, cx, cy, cz); wis[p * 4 + w] = bi; }
    __syncthreads();
    float4 c0 = wvc[p * 4 + 0], c1 = wvc[p * 4 + 1], c2 = wvc[p * 4 + 2], c3 = wvc[p * 4 + 3];
    int i0 = wis[p * 4 + 0], i1 = wis[p * 4 + 1], i2 = wis[p * 4 + 2], i3 = wis[p * 4 + 3];
    float bv = c0.x; int bbi = i0; lx = c0.y; ly = c0.z; lz = c0.w;
    { bool c = (c1.x > bv) || (c1.x == bv && i1 < bbi);
      bv = c ? c1.x : bv; bbi = c ? i1 : bbi; lx = c ? c1.y : lx; ly = c ? c1.z : ly; lz = c ? c1.w : lz; }
    { bool c = (c2.x > bv) || (c2.x == bv && i2 < bbi);
      bv = c ? c2.x : bv; bbi = c ? i2 : bbi; lx = c ? c2.y : lx; ly = c ? c2.z : ly; lz = c ? c2.w : lz; }
    { bool c = (c3.x > bv) || (c3.x == bv && i3 < bbi);
      bv = c ? c3.x : bv; bbi = c ? i3 : bbi; lx = c ? c3.y : lx; ly = c ? c3.z : ly; lz = c ? c3.w : lz; }
    last = bbi;
    // parity: slot p rewritten only in iter it+2, after barrier it+1 -> safe with 1 barrier
  }
  if (!LAST) {
    for (int e = tid; e < it1; e += 256) {
      if (e >= it0) fpsIdx[(long)b * M + e] = fidx[e];
    }
    #pragma unroll
    for (int i = 0; i < 8; ++i) distSv[(long)b * 2048 + i * 256 + tid] = dist[i];
    if (tid == 0) lastSv[b] = last;
  } else {
    for (int e = tid; e < M; e += 256) fpsIdx[(long)b * M + e] = fidx[e];
    for (int e = tid; e < 3 * M; e += 256) {
      int c = e / M, i = e % M;
      int src = fidx[i];
      int s = ((src & 7) << 8) | (src >> 3);
      node1[(long)b * 3 * M + e] = (c == 0) ? px[s] : (c == 1) ? py[s] : pz[s];
    }
  }
}

// ---------------- fused {fps-range + knn + gemmPS}, 1D grid, fps first ----------------
template <int FIRST, int LAST, bool SQP>
__global__ void knnfpsgemm_kernel(const float* __restrict__ Q, int qStrideB,
                                  const float* __restrict__ Xc, int cStrideB,
                                  int C, int Mq, int N, int k, int* __restrict__ idxOut,
                                  const float* __restrict__ W, int ldw, int O,
                                  float* __restrict__ Pt, float* __restrict__ St,
                                  const float* __restrict__ xyz, int Mf, int it0, int it1,
                                  int* __restrict__ fpsIdx, float* __restrict__ node1,
                                  float* __restrict__ distSv, int* __restrict__ lastSv,
                                  const float* __restrict__ sqPre,
                                  int nQblk, int nGblk, int nB) {
  __shared__ __align__(16) char smem[32768];
  int bid = blockIdx.x;
  if (bid < nB) {
    __builtin_amdgcn_s_setprio(3);   // R20: max priority — fps is the binding chain
    fps_body_rg<FIRST, LAST>(xyz, N, Mf, it0, it1, fpsIdx, node1, distSv, lastSv, bid, smem);
    __builtin_amdgcn_s_setprio(0);
  } else if (bid < nB + nB * nQblk) {
    int e = bid - nB;
    knn4_body<8, SQP>(Q, qStrideB, Xc, cStrideB, C, Mq, N, k, idxOut, sqPre,
                      e / nQblk, (e % nQblk) * 4, smem);
  } else {
    int e = bid - nB - nB * nQblk;
    gemmPS_body(Xc, cStrideB, C, N, W, ldw, O, Pt, St,
                e / nGblk, (e % nGblk) * 64, 0, smem);
  }
}

// ---------------- fused {ecfinish1 (+sq emit) + fps mid-range}, fps blocks first --------
__global__ void ecfps_kernel(const float* __restrict__ Pt, const float* __restrict__ St,
                             const int* __restrict__ idx, int k, int O, int Np,
                             const float* __restrict__ g, const float* __restrict__ bb,
                             float* __restrict__ outp, long oStrideB,
                             float* __restrict__ sqOut,
                             const float* __restrict__ xyz, int N, int Mf, int it0, int it1,
                             int* __restrict__ fpsIdx, float* __restrict__ node1,
                             float* __restrict__ distSv, int* __restrict__ lastSv,
                             int nEperB, int nB) {
  __shared__ __align__(16) char smem[26784];
  int bid = blockIdx.x;
  if (bid < nB) {
    __builtin_amdgcn_s_setprio(3);
    fps_body_rg<0, 0>(xyz, N, Mf, it0, it1, fpsIdx, node1, distSv, lastSv, bid, smem);
    __builtin_amdgcn_s_setprio(0);
  } else {
    int e = bid - nB;
    ecfinish_body64(Pt, St, idx, k, O, Np, g, bb, outp, oStrideB, sqOut,
                    e / nEperB, e % nEperB);
  }
}

// ---------------- fused {ecfinish2 + agg-knn}, striped (agg every 5th bid) ----------------
__global__ void ecfagg_kernel(const float* __restrict__ Pt, const float* __restrict__ St,
                              const int* __restrict__ idxS2, int k2, int O2, int Np2,
                              const float* __restrict__ g2, const float* __restrict__ b2,
                              float* __restrict__ out2, long oStrideB2,
                              const float* __restrict__ Qn, int qStrideB,
                              const float* __restrict__ Xc, int cStrideB,
                              int Cq, int Mq, int Nc, int kq, int* __restrict__ idxAgg,
                              int nQblk, int nEperB) {
  __shared__ __align__(16) char smem[32768];
  int bid = blockIdx.x;
  if (bid % 5 == 0) {
    int a = bid / 5;                       // [0, 1024)
    knn4_body<8, false>(Qn, qStrideB, Xc, cStrideB, Cq, Mq, Nc, kq, idxAgg, nullptr,
                        a / nQblk, (a % nQblk) * 4, smem);
  } else {
    int e = bid - bid / 5 - 1;             // [0, 4096) sequential
    ecfinish_body64(Pt, St, idxS2, k2, O2, Np2, g2, b2, out2, oStrideB2, nullptr,
                    e / nEperB, e % nEperB);
  }
}

// ---------------- fused {gemm_colmaxA + xmfill}, striped (xmfill every 3rd bid) ----------------
__global__ void colmaxxm_kernel(const float* __restrict__ X, int xStrideB, int C, int Np,
                                const float* __restrict__ W, int ldw, int O,
                                const float* __restrict__ g, const float* __restrict__ bb,
                                float* __restrict__ partial, int nNT, int nOT,
                                const float* __restrict__ xt1, int N,
                                const int* __restrict__ fpsI, const int* __restrict__ idxA,
                                int kq, int M, float* __restrict__ xm) {
  __shared__ __align__(16) char smem[8704];
  int bid = blockIdx.x;
  if (bid % 3 == 0) {
    xmfill_body(xt1, N, fpsI, idxA, kq, M, xm, bid / 3);       // [0, 2048)
  } else {
    int e = bid - bid / 3 - 1;                                  // [0, 4096)
    int per = nNT * nOT;
    int b = e / per, r = e % per;
    int nt = r % nNT, ot = r / nNT;
    gemm_colmax_body(X, xStrideB, C, Np, W, ldw, O, g, bb, partial,
                     b, nt * 64, ot * 64, nt, nNT, smem);
  }
}

// ---------------- fused {knn<2> + gemmPS} for stages 3/4 ----------------
__global__ void knngemm_kernel(const float* __restrict__ Xin, int xStrideB,
                               int C, int Mq, int N, int k, int* __restrict__ idxOut,
                               const float* __restrict__ W, int ldw, int O,
                               float* __restrict__ Pt, float* __restrict__ St,
                               int nQblk, int nGn, int nGo, int nB) {
  __shared__ __align__(16) char smem[13056];
  int bid = blockIdx.x;
  if (bid < nB * nQblk) {
    knn4_body<2, false>(Xin, xStrideB, Xin, xStrideB, C, Mq, N, k, idxOut, nullptr,
                        bid / nQblk, (bid % nQblk) * 4, smem);
  } else {
    int e = bid - nB * nQblk;
    int per = nGn * nGo;
    int b = e / per, r = e % per;
    int nt = r % nGn, ot = r / nGn;
    gemmPS_body(Xin, xStrideB, C, N, W, ldw, O, Pt, St, b, nt * 64, ot * 64, smem);
  }
}

// ---------------- head, batched over b (R19) ----------------
__global__ void headv_kernel(const float* __restrict__ partA, int NTa,
                             const float* __restrict__ partB, int NTb,
                             float* __restrict__ vws) {
  int b = blockIdx.x, tid = threadIdx.x;
  for (int o = tid; o < 1024; o += 256) {
    float m = -INFINITY;
    for (int t = 0; t < NTa; ++t) m = fmaxf(m, partA[((long)b * NTa + t) * 1024 + o]);
    vws[(long)b * 2048 + o] = m;
    float m2 = -INFINITY;
    for (int t = 0; t < NTb; ++t) m2 = fmaxf(m2, partB[((long)b * NTb + t) * 1024 + o]);
    vws[(long)b * 2048 + 1024 + o] = m2;
  }
}

__global__ void headl1_kernel(const float* __restrict__ vws,
                              const float* __restrict__ Wl1, const float* __restrict__ g6,
                              const float* __restrict__ b6, float* __restrict__ h1ws) {
  int tid = threadIdx.x;
  int lane = tid & 63, w = tid >> 6;
  int o0 = blockIdx.x * 8;
  for (int oo = w; oo < 8; oo += 4) {
    int o = o0 + oo;
    const float4* wr = (const float4*)(Wl1 + (long)o * 2048);
    float4 w4[8];
    #pragma unroll
    for (int j = 0; j < 8; ++j) w4[j] = wr[lane + 64 * j];
    float gs = g6[o] * BN_SCALE, bo = b6[o];
    for (int b = 0; b < 8; ++b) {
      const float4* vp = (const float4*)(vws + (long)b * 2048);
      float s = 0.f;
      #pragma unroll
      for (int j = 0; j < 8; ++j) {
        float4 v4 = vp[lane + 64 * j];
        s = fmaf(w4[j].x, v4.x, s); s = fmaf(w4[j].y, v4.y, s);
        s = fmaf(w4[j].z, v4.z, s); s = fmaf(w4[j].w, v4.w, s);
      }
      float t = wave_fadd(s);
      if (lane == 0) {
        float h = t * gs + bo;
        h1ws[(long)b * 512 + o] = h >= 0.f ? h : 0.2f * h;
      }
    }
  }
}

__global__ void headl2_kernel(const float* __restrict__ h1ws,
                              const float* __restrict__ Wl2, const float* __restrict__ bl2,
                              const float* __restrict__ g7, const float* __restrict__ b7,
                              float* __restrict__ h2ws) {
  int tid = threadIdx.x;
  int lane = tid & 63, w = tid >> 6;
  int o0 = blockIdx.x * 8;
  for (int oo = w; oo < 8; oo += 4) {
    int o = o0 + oo;
    const float4* wr = (const float4*)(Wl2 + (long)o * 512);
    float4 w4[2];
    #pragma unroll
    for (int j = 0; j < 2; ++j) w4[j] = wr[lane + 64 * j];
    float bl = bl2[o], gs = g7[o] * BN_SCALE, bo = b7[o];
    for (int b = 0; b < 8; ++b) {
      const float4* hp = (const float4*)(h1ws + (long)b * 512);
      float s = 0.f;
      #pragma unroll
      for (int j = 0; j < 2; ++j) {
        float4 v4 = hp[lane + 64 * j];
        s = fmaf(w4[j].x, v4.x, s); s = fmaf(w4[j].y, v4.y, s);
        s = fmaf(w4[j].z, v4.z, s); s = fmaf(w4[j].w, v4.w, s);
      }
      float t = wave_fadd(s);
      if (lane == 0) {
        float sb = t + bl;
        float h = sb * gs + bo;
        h2ws[(long)b * 256 + o] = h >= 0.f ? h : 0.2f * h;
      }
    }
  }
}

__global__ void headl3_kernel(const float* __restrict__ h2ws,
                              const float* __restrict__ Wl3, const float* __restrict__ bl3,
                              float* __restrict__ logits) {
  int b = blockIdx.x, tid = threadIdx.x;
  int lane = tid & 63, w = tid >> 6;
  const float4* hp = (const float4*)(h2ws + (long)b * 256);
  float4 v4 = hp[lane];
  for (int o = w; o < 40; o += 4) {
    const float4* wr = (const float4*)(Wl3 + (long)o * 256);
    float4 w4 = wr[lane];
    float s = fmaf(w4.x, v4.x, 0.f);
    s = fmaf(w4.y, v4.y, s); s = fmaf(w4.z, v4.z, s); s = fmaf(w4.w, v4.w, s);
    float t = wave_fadd(s);
    if (lane == 0) logits[(long)b * 40 + o] = t + bl3[o];
  }
}

extern "C" void kernel_launch(void* const* d_in, const int* in_sizes, int n_in,
                              void* d_out, int out_size, void* d_ws, size_t ws_size,
                              hipStream_t stream) {
  const float* x   = (const float*)d_in[0];
  const float* W1  = (const float*)d_in[1];
  const float* g1  = (const float*)d_in[2];
  const float* b1  = (const float*)d_in[3];
  const float* W2  = (const float*)d_in[4];
  const float* g2  = (const float*)d_in[5];
  const float* b2  = (const float*)d_in[6];
  const float* W2m = (const float*)d_in[7];
  const float* g2m = (const float*)d_in[8];
  const float* b2m = (const float*)d_in[9];
  const float* W3  = (const float*)d_in[10];
  const float* g3  = (const float*)d_in[11];
  const float* b3  = (const float*)d_in[12];
  const float* W4  = (const float*)d_in[13];
  const float* g4  = (const float*)d_in[14];
  const float* b4  = (const float*)d_in[15];
  const float* W5  = (const float*)d_in[16];
  const float* g5  = (const float*)d_in[17];
  const float* b5  = (const float*)d_in[18];
  const float* Wl1 = (const float*)d_in[19];
  const float* g6  = (const float*)d_in[20];
  const float* b6  = (const float*)d_in[21];
  const float* Wl2 = (const float*)d_in[22];
  const float* bl2 = (const float*)d_in[23];
  const float* g7  = (const float*)d_in[24];
  const float* b7  = (const float*)d_in[25];
  const float* Wl3 = (const float*)d_in[26];
  const float* bl3 = (const float*)d_in[27];
  float* outF = (float*)d_out;

  const int B = 8, N = 2048, K = 20, M = 512, K2 = 10;

  float* ws    = (float*)d_ws;
  float* xt1   = ws;                               // (B,128,N)
  float* xm    = xt1 + (size_t)B * 128 * N;        // (B,256,M)
  float* xc    = xm  + (size_t)B * 256 * M;        // (B,512,M)
  float* Pt    = xc  + (size_t)B * 512 * M;        // max(B*N*64, B*M*256)
  float* St    = Pt  + (size_t)B * N * 64;
  float* partA = St  + (size_t)B * N * 64;         // (B,32,1024)
  float* partB = partA + (size_t)B * 32 * 1024;    // (B,8,1024)
  int*   idxK  = (int*)(partB + (size_t)B * 8 * 1024);  // (B,N,K)
  int*   fpsI  = idxK + (size_t)B * N * K;         // (B,M)
  float* fpsDist = (float*)(fpsI + (size_t)B * M); // (B,2048) fps checkpoint dists
  int*   fpsLast = (int*)(fpsDist + (size_t)B * 2048);  // (B)
  int*   idxAgg  = fpsLast + 64;                   // (B,M,K) aggregate-knn indices
  float* sqS2    = (float*)(idxAgg + (size_t)B * M * K); // (B,N) stage-2 candidate norms
  float* vws     = sqS2 + (size_t)B * N;           // (B,2048) head v
  float* h1ws    = vws + (size_t)B * 2048;         // (B,512)
  float* h2ws    = h1ws + (size_t)B * 512;         // (B,256)

  float* logits = outF;        // (B,40)
  float* node1  = outF + 320;  // (B,3,M)

  dim3 t256(256);
  const int nQblk = N / 4;     // 512 knn query-blocks per batch (N-point knn)
  const int nGblk = N / 64;    // 32 gemmPS n-tiles per batch (stage 1/2)
  const int nFused = B + B * nQblk + B * nGblk;
  const int nQa = M / 4;       // 128 agg/stage3/4 knn query-blocks per batch
  const int IT1 = 208, IT2 = 304;   // fps phase boundaries

  // ---- stage 1 FUSED: fps [0,208) + knn(xyz) + gemmPS1 (all depend only on x)
  knnfpsgemm_kernel<1, 0, false><<<dim3(nFused), t256, 0, stream>>>(
      x, 3 * N, x, 3 * N, 3, N, N, K, idxK,
      W1, 6, 64, Pt, St,
      x, M, 0, IT1, fpsI, node1, fpsDist, fpsLast, nullptr, nQblk, nGblk, B);

  // ---- ecfinish1 (+sq emit for stage-2 knn) FUSED with fps [208,304)
  ecfps_kernel<<<dim3(B + B * (N / 4)), t256, 0, stream>>>(
      Pt, St, idxK, K, 64, N, g1, b1, xt1, (long)128 * N, sqS2,
      x, N, M, IT1, IT2, fpsI, node1, fpsDist, fpsLast, N / 4, B);

  // ---- stage 2 FUSED: fps [304,512) + knn(x1, precomputed sq) + gemmPS2
  knnfpsgemm_kernel<0, 1, true><<<dim3(nFused), t256, 0, stream>>>(
      xt1, 128 * N, xt1, 128 * N, 64, N, N, K, idxK,
      W2, 128, 64, Pt, St,
      x, M, IT2, M, fpsI, node1, fpsDist, fpsLast, sqS2, nQblk, nGblk, B);

  // ---- FUSED: ecfinish2 (gather-bound) + aggregate-knn (VALU-latency-bound), striped
  ecfagg_kernel<<<dim3(B * nQa + B * (N / 4)), t256, 0, stream>>>(
      Pt, St, idxK, K, 64, N, g2, b2, xt1 + (size_t)64 * N, (long)128 * N,
      node1, 3 * M, x, 3 * N, 3, M, N, K, idxAgg, nQa, N / 4);

  // ---- FUSED: gemm_colmaxA + xmfill, striped every-3rd
  colmaxxm_kernel<<<dim3((B * 128 * M) / 256 + B * 32 * 16), t256, 0, stream>>>(
      xt1, 128 * N, 128, N, W2m, 128, 1024, g2m, b2m, partA, 32, 16,
      xt1, N, fpsI, idxAgg, K, M, xm);

  // ---- stage 3 FUSED: knn(xm) + gemmPS3
  knngemm_kernel<<<dim3(B * nQa + B * (M / 64) * (256 / 64)), t256, 0, stream>>>(
      xm, 256 * M, 256, M, M, K2, idxK, W3, 512, 256, Pt, St, nQa, M / 64, 256 / 64, B);
  ecfinish_kernel<<<dim3(M, B), dim3(256, 1), 0, stream>>>(Pt, St, idxK, K2, 256, M, g3, b3, xc, (long)512 * M);

  // ---- stage 4 FUSED: knn(x3) + gemmPS4
  knngemm_kernel<<<dim3(B * nQa + B * (M / 64) * (256 / 64)), t256, 0, stream>>>(
      xc, 512 * M, 256, M, M, K2, idxK, W4, 512, 256, Pt, St, nQa, M / 64, 256 / 64, B);
  ecfinish_kernel<<<dim3(M, B), dim3(256, 1), 0, stream>>>(Pt, St, idxK, K2, 256, M, g4, b4,
                                                           xc + (size_t)256 * M, (long)512 * M);

  // ---- vs partials
  gemm_colmax_kernel<<<dim3(M / 64, 1024 / 64, B), t256, 0, stream>>>(xc, 512 * M, 512, M, W5, 512, 1024,
                                                                      g5, b5, partB);

  // ---- head, batched over b (weights fetched once)
  headv_kernel<<<dim3(B), t256, 0, stream>>>(partA, N / 64, partB, M / 64, vws);
  headl1_kernel<<<dim3(64), t256, 0, stream>>>(vws, Wl1, g6, b6, h1ws);
  headl2_kernel<<<dim3(32), t256, 0, stream>>>(h1ws, Wl2, bl2, g7, b7, h2ws);
  headl3_kernel<<<dim3(B), t256, 0, stream>>>(h2ws, Wl3, bl3, logits);
}